// Round 4
// baseline (883.084 us; speedup 1.0000x reference)
//
#include <hip/hip_runtime.h>
#include <stdint.h>

// Problem constants
#define B_   16
#define N_   4096
#define S_   1024
#define K_   32
#define CIN_ 64
#define C0IN 67          // 3 + CIN
#define P_   524288      // B*S*K points through the MLP
#define PQ_  16384       // B*S queries
#define EPS_ 1e-5f

// Workspace layout (bytes)
#define SZ_IDX    ((size_t)P_ * 4)            // knn indices, int32
#define SZ_Y      ((size_t)P_ * 64 * 2)       // 64ch x P bf16
#define SZ_MX     ((size_t)PQ_ * 128 * 4)     // per-(q,ch) f32
#define OFF_IDX   ((size_t)0)
#define OFF_Y0    (OFF_IDX + SZ_IDX)
#define OFF_Y1    (OFF_Y0 + SZ_Y)
#define OFF_MX    (OFF_Y1 + SZ_Y)
#define OFF_MN    (OFF_MX + SZ_MX)
#define OFF_STATS (OFF_MN + SZ_MX)            // 512 f32 raw sums (zeroed per launch)
#define OFF_FIN   (OFF_STATS + 2048)          // 512 f32 finalized scale/shift
#define OFF_FPSC  (OFF_FIN + 2048)            // canonical fps, 16384 int32
#define WS_NEEDED (OFF_FPSC + (size_t)PQ_ * 4)

typedef unsigned short u16;

__device__ __forceinline__ float b2f(unsigned v) {
  return __uint_as_float((v & 0xffffu) << 16);
}
__device__ __forceinline__ u16 f2b(float f) {
  unsigned u = __float_as_uint(f);
  unsigned r = (u + 0x7fffu + ((u >> 16) & 1u)) >> 16;  // RNE
  return (u16)r;
}

// ---------------------------------------------------------------------------
// fps canonicalization: detect int64 vs int32 storage, emit int32.
// Single indexed load (no speculative OOB read of the int32 buffer).
// ---------------------------------------------------------------------------
__global__ __launch_bounds__(256) void fps_canon_kernel(
    const int* __restrict__ fpsraw, int* __restrict__ fpsc)
{
  __shared__ int is64;
  const int tid = threadIdx.x;
  if (tid == 0) is64 = 1;
  __syncthreads();
  if (tid < 64) {
    if (fpsraw[2 * tid + 1] != 0) atomicAnd(&is64, 0);
  }
  __syncthreads();
  int i = blockIdx.x * 256 + tid;
  if (i < PQ_) {
    int src = is64 ? (2 * i) : i;   // single load, index chosen first
    int v = fpsraw[src];
    fpsc[i] = (v & 0xFFF);          // clamp into [0,4095] (no-op for valid data)
  }
}

// ---------------------------------------------------------------------------
// KNN: per query, exact 32 smallest (d, idx) via histogram radix-select.
// Distance arithmetic mirrors the reference bit-for-bit:
// (|c|^2 + |x|^2) - 2*dot, f32, no FMA contraction.
// new_xyz output is a bit-exact f32 copy of the gathered input coords.
// ---------------------------------------------------------------------------
#define CAND_CAP 1024

__global__ __launch_bounds__(256) void knn_kernel(
    const float* __restrict__ xyz, const int* __restrict__ fps,
    int* __restrict__ idxout, float* __restrict__ out_xyz)
{
  __shared__ float dar[N_];
  __shared__ unsigned hist[1024];
  __shared__ float cd[CAND_CAP];
  __shared__ int   ci_[CAND_CAP];
  __shared__ int   sel[K_];
  __shared__ int   wtot[4];
  __shared__ float bwd[4];
  __shared__ int   bwi[4];
  __shared__ int   sCnt, sCand, sT, sWin;

  const int q   = blockIdx.x;
  const int b   = q >> 10;                 // q / S_
  const int tid = threadIdx.x;
  const float* xb = xyz + (size_t)b * N_ * 3;
  const int ctr = fps[q];
  const float cx = xb[ctr*3+0], cy = xb[ctr*3+1], cz = xb[ctr*3+2];

  if (tid == 0) {
    out_xyz[(size_t)q*3+0] = cx;
    out_xyz[(size_t)q*3+1] = cy;
    out_xyz[(size_t)q*3+2] = cz;
    sCnt = 0; sCand = 0;
  }
  for (int i = tid; i < 1024; i += 256) hist[i] = 0u;
  const float s1 = __fadd_rn(__fadd_rn(__fmul_rn(cx,cx), __fmul_rn(cy,cy)), __fmul_rn(cz,cz));
  __syncthreads();

  for (int n = tid; n < N_; n += 256) {
    float x0 = xb[n*3+0], x1 = xb[n*3+1], x2 = xb[n*3+2];
    float s2 = __fadd_rn(__fadd_rn(__fmul_rn(x0,x0), __fmul_rn(x1,x1)), __fmul_rn(x2,x2));
    float dt = __fadd_rn(__fadd_rn(__fmul_rn(cx,x0), __fmul_rn(cy,x1)), __fmul_rn(cz,x2));
    float d  = __fsub_rn(__fadd_rn(s1, s2), __fmul_rn(2.0f, dt));
    dar[n] = d;
    float dc = fmaxf(d, 0.0f);
    int bin = (int)(dc * 16.0f); bin = bin > 1023 ? 1023 : bin;
    atomicAdd(&hist[bin], 1u);
  }
  __syncthreads();

  // Block-wide scan over 1024 bins; find crossing bin T (cumulative reaches K).
  const int base = tid * 4;
  int h0 = (int)hist[base], h1 = (int)hist[base+1], h2 = (int)hist[base+2], h3 = (int)hist[base+3];
  int lsum = h0 + h1 + h2 + h3;
  const int lane = tid & 63, wid = tid >> 6;
  int scv = lsum;
  #pragma unroll
  for (int off = 1; off < 64; off <<= 1) {
    int v = __shfl_up(scv, off, 64);
    if (lane >= off) scv += v;
  }
  if (lane == 63) wtot[wid] = scv;
  __syncthreads();
  int woff = 0;
  for (int w = 0; w < wid; ++w) woff += wtot[w];
  int run = woff + scv - lsum;
  int hh[4] = {h0, h1, h2, h3};
  #pragma unroll
  for (int j = 0; j < 4; ++j) {
    int c = hh[j];
    if (run < K_ && run + c >= K_) { sT = base + j; }
    run += c;
  }
  __syncthreads();
  const int T = sT;

  // Everything strictly below bin T is selected; bin T members are candidates.
  for (int n = tid; n < N_; n += 256) {
    float d  = dar[n];
    float dc = fmaxf(d, 0.0f);
    int bin = (int)(dc * 16.0f); bin = bin > 1023 ? 1023 : bin;
    if (bin < T) {
      int s = atomicAdd(&sCnt, 1);
      if (s < K_) sel[s] = n;
    } else if (bin == T) {
      int s = atomicAdd(&sCand, 1);
      if (s < CAND_CAP) { cd[s] = d; ci_[s] = n; }
    }
  }
  __syncthreads();

  int m = sCnt; m = m > K_ ? K_ : m;
  int cc = sCand; cc = cc > CAND_CAP ? CAND_CAP : cc;
  const int r = K_ - m;
  for (int it = 0; it < r; ++it) {
    float bd = 3.0e38f; int bi = 0x7fffffff;
    for (int j = tid; j < cc; j += 256) {
      float dv = cd[j]; int iv = ci_[j];
      if (dv < bd || (dv == bd && iv < bi)) { bd = dv; bi = iv; }
    }
    #pragma unroll
    for (int off = 32; off > 0; off >>= 1) {
      float od = __shfl_down(bd, off, 64);
      int   oi = __shfl_down(bi, off, 64);
      if (od < bd || (od == bd && oi < bi)) { bd = od; bi = oi; }
    }
    if (lane == 0) { bwd[wid] = bd; bwi[wid] = bi; }
    __syncthreads();
    if (tid == 0) {
      float fd = bwd[0]; int fi = bwi[0];
      for (int w = 1; w < 4; ++w) {
        float od = bwd[w]; int oi = bwi[w];
        if (od < fd || (od == fd && oi < fi)) { fd = od; fi = oi; }
      }
      sel[m + it] = fi & 0xFFF;  // clamp: valid indices unchanged
      sWin = fi;
    }
    __syncthreads();
    for (int j = tid; j < cc; j += 256) if (ci_[j] == sWin) cd[j] = 3.0e38f;
    __syncthreads();
  }
  if (tid < K_) idxout[(size_t)q * K_ + tid] = sel[tid] & 0xFFF;
}

// ---------------------------------------------------------------------------
// Layer 0: gather grouped (3 rel-xyz + 64 feat) -> y0 = W0*x + b0 (raw, bf16)
// + per-channel global sum / sumsq via atomics. Block: 128 thr, 64o x 128p tile.
// ---------------------------------------------------------------------------
__global__ __launch_bounds__(128) void l0_kernel(
    const float* __restrict__ xyz, const float* __restrict__ feat,
    const int* __restrict__ fps, const int* __restrict__ idxin,
    const float* __restrict__ W0, const float* __restrict__ b0,
    u16* __restrict__ Y0,
    float* __restrict__ sumg, float* __restrict__ sqg)
{
  __shared__ float X[C0IN][128];
  __shared__ float Wl[C0IN][64];
  __shared__ float ssum[64], ssq[64];
  const int tid = threadIdx.x;
  const int q0 = blockIdx.x * 4;
  const int b = q0 >> 10;
  const int pbase = blockIdx.x * 128;

  for (int i = tid; i < C0IN * 64; i += 128) {
    int o = i & 63, c = i >> 6;
    Wl[c][o] = W0[o * C0IN + c];
  }
  {
    const int p = tid;
    const int n = idxin[pbase + p] & 0xFFF;
    const int qq = q0 + (p >> 5);
    const int ct = fps[qq] & 0xFFF;
    const float* xb = xyz + (size_t)b * N_ * 3;
    X[0][p] = xb[n*3+0] - xb[ct*3+0];
    X[1][p] = xb[n*3+1] - xb[ct*3+1];
    X[2][p] = xb[n*3+2] - xb[ct*3+2];
    const float4* fr = (const float4*)(feat + ((size_t)b * N_ + n) * CIN_);
    #pragma unroll
    for (int c4 = 0; c4 < CIN_ / 4; ++c4) {
      float4 f = fr[c4];
      X[3+c4*4+0][p] = f.x; X[3+c4*4+1][p] = f.y;
      X[3+c4*4+2][p] = f.z; X[3+c4*4+3][p] = f.w;
    }
  }
  if (tid < 64) { ssum[tid] = 0.f; ssq[tid] = 0.f; }
  __syncthreads();

  const int og = tid >> 4;   // 0..7  -> o = og*8
  const int pg = tid & 15;   // 0..15 -> p = pg*8
  float acc[8][8];
  #pragma unroll
  for (int oi = 0; oi < 8; ++oi) {
    float bb = b0 ? b0[og*8 + oi] : 0.0f;
    #pragma unroll
    for (int pi = 0; pi < 8; ++pi) acc[oi][pi] = bb;
  }
  for (int c = 0; c < C0IN; ++c) {
    float4 wa = *(const float4*)&Wl[c][og*8];
    float4 wb = *(const float4*)&Wl[c][og*8+4];
    float4 xa = *(const float4*)&X[c][pg*8];
    float4 xc = *(const float4*)&X[c][pg*8+4];
    float wv[8] = {wa.x,wa.y,wa.z,wa.w,wb.x,wb.y,wb.z,wb.w};
    float xv[8] = {xa.x,xa.y,xa.z,xa.w,xc.x,xc.y,xc.z,xc.w};
    #pragma unroll
    for (int oi = 0; oi < 8; ++oi)
      #pragma unroll
      for (int pi = 0; pi < 8; ++pi)
        acc[oi][pi] = fmaf(wv[oi], xv[pi], acc[oi][pi]);
  }
  #pragma unroll
  for (int oi = 0; oi < 8; ++oi) {
    int o = og*8 + oi;
    uint4 pk; unsigned* pu = (unsigned*)&pk;
    float s = 0.f, s2 = 0.f;
    #pragma unroll
    for (int h = 0; h < 4; ++h) {
      float v0 = acc[oi][h*2], v1 = acc[oi][h*2+1];
      pu[h] = (unsigned)f2b(v0) | ((unsigned)f2b(v1) << 16);
    }
    #pragma unroll
    for (int pi = 0; pi < 8; ++pi) { float v = acc[oi][pi]; s += v; s2 += v*v; }
    *(uint4*)(Y0 + (size_t)o * P_ + pbase + pg*8) = pk;
    atomicAdd(&ssum[o], s);
    atomicAdd(&ssq[o], s2);
  }
  __syncthreads();
  if (tid < 64) { atomicAdd(&sumg[tid], ssum[tid]); atomicAdd(&sqg[tid], ssq[tid]); }
}

// ---------------------------------------------------------------------------
// Layer 1: x = relu(sc0*y0 + sh0); y1 = W1*x + b1 (raw bf16) + stats.
// ---------------------------------------------------------------------------
__global__ __launch_bounds__(128) void l1_kernel(
    const u16* __restrict__ Y0,
    const float* __restrict__ W1, const float* __restrict__ b1,
    const float* __restrict__ sc0, const float* __restrict__ sh0,
    u16* __restrict__ Y1,
    float* __restrict__ sumg, float* __restrict__ sqg)
{
  __shared__ float X[64][128];
  __shared__ float Wl[64][64];
  __shared__ float ssum[64], ssq[64];
  const int tid = threadIdx.x;
  const int pbase = blockIdx.x * 128;

  for (int i = tid; i < 64 * 64; i += 128) {
    int o = i & 63, c = i >> 6;
    Wl[c][o] = W1[o * 64 + c];
  }
  for (int i = tid; i < 64 * 16; i += 128) {
    int c = i >> 4, j = i & 15;
    uint4 pk = *(const uint4*)(Y0 + (size_t)c * P_ + pbase + j*8);
    const unsigned* pu = (const unsigned*)&pk;
    float sc = sc0[c], sh = sh0[c];
    float4 lo, hi;
    lo.x = fmaxf(fmaf(sc, b2f(pu[0]),       sh), 0.f);
    lo.y = fmaxf(fmaf(sc, b2f(pu[0] >> 16), sh), 0.f);
    lo.z = fmaxf(fmaf(sc, b2f(pu[1]),       sh), 0.f);
    lo.w = fmaxf(fmaf(sc, b2f(pu[1] >> 16), sh), 0.f);
    hi.x = fmaxf(fmaf(sc, b2f(pu[2]),       sh), 0.f);
    hi.y = fmaxf(fmaf(sc, b2f(pu[2] >> 16), sh), 0.f);
    hi.z = fmaxf(fmaf(sc, b2f(pu[3]),       sh), 0.f);
    hi.w = fmaxf(fmaf(sc, b2f(pu[3] >> 16), sh), 0.f);
    *(float4*)&X[c][j*8]   = lo;
    *(float4*)&X[c][j*8+4] = hi;
  }
  if (tid < 64) { ssum[tid] = 0.f; ssq[tid] = 0.f; }
  __syncthreads();

  const int og = tid >> 4;
  const int pg = tid & 15;
  float acc[8][8];
  #pragma unroll
  for (int oi = 0; oi < 8; ++oi) {
    float bb = b1 ? b1[og*8 + oi] : 0.0f;
    #pragma unroll
    for (int pi = 0; pi < 8; ++pi) acc[oi][pi] = bb;
  }
  for (int c = 0; c < 64; ++c) {
    float4 wa = *(const float4*)&Wl[c][og*8];
    float4 wb = *(const float4*)&Wl[c][og*8+4];
    float4 xa = *(const float4*)&X[c][pg*8];
    float4 xc = *(const float4*)&X[c][pg*8+4];
    float wv[8] = {wa.x,wa.y,wa.z,wa.w,wb.x,wb.y,wb.z,wb.w};
    float xv[8] = {xa.x,xa.y,xa.z,xa.w,xc.x,xc.y,xc.z,xc.w};
    #pragma unroll
    for (int oi = 0; oi < 8; ++oi)
      #pragma unroll
      for (int pi = 0; pi < 8; ++pi)
        acc[oi][pi] = fmaf(wv[oi], xv[pi], acc[oi][pi]);
  }
  #pragma unroll
  for (int oi = 0; oi < 8; ++oi) {
    int o = og*8 + oi;
    uint4 pk; unsigned* pu = (unsigned*)&pk;
    float s = 0.f, s2 = 0.f;
    #pragma unroll
    for (int h = 0; h < 4; ++h) {
      float v0 = acc[oi][h*2], v1 = acc[oi][h*2+1];
      pu[h] = (unsigned)f2b(v0) | ((unsigned)f2b(v1) << 16);
    }
    #pragma unroll
    for (int pi = 0; pi < 8; ++pi) { float v = acc[oi][pi]; s += v; s2 += v*v; }
    *(uint4*)(Y1 + (size_t)o * P_ + pbase + pg*8) = pk;
    atomicAdd(&ssum[o], s);
    atomicAdd(&ssq[o], s2);
  }
  __syncthreads();
  if (tid < 64) { atomicAdd(&sumg[tid], ssum[tid]); atomicAdd(&sqg[tid], ssq[tid]); }
}

// ---------------------------------------------------------------------------
// Layer 2: x = relu(sc1*y1 + sh1); y2 = W2*x + b2; per-(q,ch) max & min over K
// plus global stats. Block: 128 thr, 128o x 64p (2 queries).
// ---------------------------------------------------------------------------
__global__ __launch_bounds__(128) void l2_kernel(
    const u16* __restrict__ Y1,
    const float* __restrict__ W2, const float* __restrict__ b2,
    const float* __restrict__ sc1, const float* __restrict__ sh1,
    float* __restrict__ mxg, float* __restrict__ mng,
    float* __restrict__ sumg, float* __restrict__ sqg)
{
  __shared__ float X[64][64];
  __shared__ float Wl[64][128];
  __shared__ float rmx[128][8], rmn[128][8];
  __shared__ float ssum[128], ssq[128];
  const int tid = threadIdx.x;
  const int pbase = blockIdx.x * 64;

  for (int i = tid; i < 128 * 64; i += 128) {
    int o = i & 127, c = i >> 7;
    Wl[c][o] = W2[o * 64 + c];
  }
  for (int i = tid; i < 64 * 8; i += 128) {
    int c = i >> 3, j = i & 7;
    uint4 pk = *(const uint4*)(Y1 + (size_t)c * P_ + pbase + j*8);
    const unsigned* pu = (const unsigned*)&pk;
    float sc = sc1[c], sh = sh1[c];
    float4 lo, hi;
    lo.x = fmaxf(fmaf(sc, b2f(pu[0]),       sh), 0.f);
    lo.y = fmaxf(fmaf(sc, b2f(pu[0] >> 16), sh), 0.f);
    lo.z = fmaxf(fmaf(sc, b2f(pu[1]),       sh), 0.f);
    lo.w = fmaxf(fmaf(sc, b2f(pu[1] >> 16), sh), 0.f);
    hi.x = fmaxf(fmaf(sc, b2f(pu[2]),       sh), 0.f);
    hi.y = fmaxf(fmaf(sc, b2f(pu[2] >> 16), sh), 0.f);
    hi.z = fmaxf(fmaf(sc, b2f(pu[3]),       sh), 0.f);
    hi.w = fmaxf(fmaf(sc, b2f(pu[3] >> 16), sh), 0.f);
    *(float4*)&X[c][j*8]   = lo;
    *(float4*)&X[c][j*8+4] = hi;
  }
  if (tid < 128) { ssum[tid] = 0.f; ssq[tid] = 0.f; }
  __syncthreads();

  const int og = tid >> 3;  // 0..15 -> o = og*8 (128 out ch)
  const int pg = tid & 7;   // 0..7  -> p = pg*8 (64 pts)
  float acc[8][8];
  #pragma unroll
  for (int oi = 0; oi < 8; ++oi) {
    float bb = b2 ? b2[og*8 + oi] : 0.0f;
    #pragma unroll
    for (int pi = 0; pi < 8; ++pi) acc[oi][pi] = bb;
  }
  for (int c = 0; c < 64; ++c) {
    float4 wa = *(const float4*)&Wl[c][og*8];
    float4 wb = *(const float4*)&Wl[c][og*8+4];
    float4 xa = *(const float4*)&X[c][pg*8];
    float4 xc = *(const float4*)&X[c][pg*8+4];
    float wv[8] = {wa.x,wa.y,wa.z,wa.w,wb.x,wb.y,wb.z,wb.w};
    float xv[8] = {xa.x,xa.y,xa.z,xa.w,xc.x,xc.y,xc.z,xc.w};
    #pragma unroll
    for (int oi = 0; oi < 8; ++oi)
      #pragma unroll
      for (int pi = 0; pi < 8; ++pi)
        acc[oi][pi] = fmaf(wv[oi], xv[pi], acc[oi][pi]);
  }
  #pragma unroll
  for (int oi = 0; oi < 8; ++oi) {
    int o = og*8 + oi;
    float s = 0.f, s2 = 0.f;
    float lmx = -3.0e38f, lmn = 3.0e38f;
    #pragma unroll
    for (int pi = 0; pi < 8; ++pi) {
      float v = acc[oi][pi];
      s += v; s2 += v*v;
      lmx = fmaxf(lmx, v); lmn = fminf(lmn, v);
    }
    atomicAdd(&ssum[o], s);
    atomicAdd(&ssq[o], s2);
    rmx[o][pg] = lmx;
    rmn[o][pg] = lmn;
  }
  __syncthreads();
  if (tid < 128) {
    const int o = tid;
    const size_t q0 = (size_t)blockIdx.x * 2;
    float m0 = rmx[o][0], n0 = rmn[o][0];
    float m1 = rmx[o][4], n1 = rmn[o][4];
    #pragma unroll
    for (int j = 1; j < 4; ++j) {
      m0 = fmaxf(m0, rmx[o][j]);   n0 = fminf(n0, rmn[o][j]);
      m1 = fmaxf(m1, rmx[o][4+j]); n1 = fminf(n1, rmn[o][4+j]);
    }
    mxg[q0*128 + o] = m0;      mng[q0*128 + o] = n0;
    mxg[(q0+1)*128 + o] = m1;  mng[(q0+1)*128 + o] = n1;
    atomicAdd(&sumg[o], ssum[o]);
    atomicAdd(&sqg[o],  ssq[o]);
  }
}

// ---------------------------------------------------------------------------
// BN finalize: raw (sum, sumsq) -> (scale, shift) per channel.
// ---------------------------------------------------------------------------
__global__ void finalize_kernel(
    const float* __restrict__ sum, const float* __restrict__ sq,
    const float* __restrict__ g, const float* __restrict__ bt,
    float* __restrict__ sc, float* __restrict__ sh, int C)
{
  int c = threadIdx.x;
  if (c < C) {
    const float inv = 1.0f / (float)P_;
    float mu = sum[c] * inv;
    float var = sq[c] * inv - mu * mu;
    var = fmaxf(var, 0.f);
    float r = 1.0f / sqrtf(var + EPS_);
    float gg = g ? g[c] : 1.0f;
    float bb = bt ? bt[c] : 0.0f;
    float s = gg * r;
    sc[c] = s;
    sh[c] = bb - mu * s;
  }
}

// ---------------------------------------------------------------------------
// Epilogue: BN2 + ReLU + maxpool (monotone affine commutes with max; min
// handles a negative scale), write f32 features.
// ---------------------------------------------------------------------------
__global__ __launch_bounds__(256) void out_kernel(
    const float* __restrict__ mxg, const float* __restrict__ mng,
    const float* __restrict__ sc2, const float* __restrict__ sh2,
    float* __restrict__ out)
{
  int i = blockIdx.x * 256 + threadIdx.x;  // i = q*128 + o, 2M total
  int o = i & 127;
  float a = sc2[o];
  float v = (a >= 0.f) ? mxg[i] : mng[i];
  float z = fmaxf(fmaf(a, v, sh2[o]), 0.f);
  out[(size_t)PQ_ * 3 + i] = z;
}

// ---------------------------------------------------------------------------
extern "C" void kernel_launch(void* const* d_in, const int* in_sizes, int n_in,
                              void* d_out, int out_size, void* d_ws, size_t ws_size,
                              hipStream_t stream)
{
  // Size-keyed input identification (robust to any input permutation).
  int i_xyz=-1, i_feat=-1, i_fps=-1, i_w0=-1, i_w1=-1, i_w2=-1;
  for (int i = 0; i < n_in; ++i) {
    switch (in_sizes[i]) {
      case 196608:  i_xyz = i; break;   // B*N*3
      case 4194304: i_feat = i; break;  // B*N*CIN
      case 16384:   i_fps = i; break;   // B*S
      case 4288:    i_w0 = i; break;    // 64*67
      case 4096:    i_w1 = i; break;    // 64*64
      case 8192:    i_w2 = i; break;    // 128*64
      default: break;
    }
  }
  if (i_xyz < 0 || i_feat < 0 || i_fps < 0 || i_w0 < 0 || i_w1 < 0 || i_w2 < 0) return;

  const float* xyz  = (const float*)d_in[i_xyz];
  const float* feat = (const float*)d_in[i_feat];
  const int*   fpsr = (const int*)d_in[i_fps];
  const float* W0 = (const float*)d_in[i_w0];
  const float* W1 = (const float*)d_in[i_w1];
  const float* W2 = (const float*)d_in[i_w2];

  // b/g/bt only if the full documented layout holds; otherwise use their
  // setup-time constants (b=0, g=1, bt=0).
  bool canon = (n_in >= 15 && i_xyz==0 && i_feat==1 && i_fps==2 && i_w0==3 &&
                i_w1==7 && i_w2==11 &&
                in_sizes[4]==64 && in_sizes[5]==64 && in_sizes[6]==64 &&
                in_sizes[8]==64 && in_sizes[9]==64 && in_sizes[10]==64 &&
                in_sizes[12]==128 && in_sizes[13]==128 && in_sizes[14]==128);
  const float* b0 = canon ? (const float*)d_in[4]  : nullptr;
  const float* g0 = canon ? (const float*)d_in[5]  : nullptr;
  const float* bt0= canon ? (const float*)d_in[6]  : nullptr;
  const float* b1 = canon ? (const float*)d_in[8]  : nullptr;
  const float* g1 = canon ? (const float*)d_in[9]  : nullptr;
  const float* bt1= canon ? (const float*)d_in[10] : nullptr;
  const float* b2 = canon ? (const float*)d_in[12] : nullptr;
  const float* g2 = canon ? (const float*)d_in[13] : nullptr;
  const float* bt2= canon ? (const float*)d_in[14] : nullptr;

  float* out = (float*)d_out;
  char* ws = (char*)d_ws;
  if (ws_size < WS_NEEDED) return;

  int* idxw = (int*)(ws + OFF_IDX);
  u16* Y0 = (u16*)(ws + OFF_Y0);
  u16* Y1 = (u16*)(ws + OFF_Y1);
  float* mxg = (float*)(ws + OFF_MX);
  float* mng = (float*)(ws + OFF_MN);
  float* st  = (float*)(ws + OFF_STATS);
  float* fin = (float*)(ws + OFF_FIN);
  int* fpsc  = (int*)(ws + OFF_FPSC);

  hipMemsetAsync(st, 0, 2048, stream);

  fps_canon_kernel<<<(PQ_+255)/256, 256, 0, stream>>>(fpsr, fpsc);

  knn_kernel<<<PQ_, 256, 0, stream>>>(xyz, fpsc, idxw, out);

  l0_kernel<<<P_/128, 128, 0, stream>>>(xyz, feat, fpsc, idxw, W0, b0, Y0, st + 0, st + 64);
  finalize_kernel<<<1, 64, 0, stream>>>(st + 0, st + 64, g0, bt0, fin + 0, fin + 64, 64);

  l1_kernel<<<P_/128, 128, 0, stream>>>(Y0, W1, b1, fin + 0, fin + 64, Y1, st + 128, st + 192);
  finalize_kernel<<<1, 64, 0, stream>>>(st + 128, st + 192, g1, bt1, fin + 128, fin + 192, 64);

  l2_kernel<<<P_/64, 128, 0, stream>>>(Y1, W2, b2, fin + 128, fin + 192, mxg, mng, st + 256, st + 384);
  finalize_kernel<<<1, 128, 0, stream>>>(st + 256, st + 384, g2, bt2, fin + 256, fin + 384, 128);

  out_kernel<<<(PQ_*128)/256, 256, 0, stream>>>(mxg, mng, fin + 256, fin + 384, out);
}

// Round 5
// 638.113 us; speedup vs baseline: 1.3839x; 1.3839x over previous
//
#include <hip/hip_runtime.h>
#include <stdint.h>

// Problem constants
#define B_   16
#define N_   4096
#define S_   1024
#define K_   32
#define CIN_ 64
#define P_   524288      // B*S*K points through the MLP
#define PQ_  16384       // B*S queries
#define EPS_ 1e-5f

// Workspace layout (bytes)
#define SZ_IDX    ((size_t)P_ * 4)            // knn indices, int32
#define SZ_Y      ((size_t)P_ * 64 * 2)       // 64ch x P bf16 (subtiled units)
#define SZ_MX     ((size_t)PQ_ * 128 * 4)     // per-(q,ch) f32
#define OFF_IDX   ((size_t)0)
#define OFF_Y0    (OFF_IDX + SZ_IDX)
#define OFF_Y1    (OFF_Y0 + SZ_Y)
#define OFF_MX    (OFF_Y1 + SZ_Y)
#define OFF_MN    (OFF_MX + SZ_MX)
#define OFF_STATS (OFF_MN + SZ_MX)            // 512 f32 raw sums (zeroed per launch)
#define OFF_FIN   (OFF_STATS + 2048)          // 512 f32 finalized scale/shift
#define OFF_FPSC  (OFF_FIN + 2048)            // canonical fps, 16384 int32
#define WS_NEEDED (OFF_FPSC + (size_t)PQ_ * 4)

typedef unsigned short u16;
typedef short bfrag __attribute__((ext_vector_type(8)));   // 8 bf16 (4 VGPRs)
typedef float f32x4 __attribute__((ext_vector_type(4)));

__device__ __forceinline__ float b2f(unsigned v) {
  return __uint_as_float((v & 0xffffu) << 16);
}
__device__ __forceinline__ u16 f2b(float f) {
  unsigned u = __float_as_uint(f);
  unsigned r = (u + 0x7fffu + ((u >> 16) & 1u)) >> 16;  // RNE
  return (u16)r;
}
__device__ __forceinline__ unsigned pk2(float a, float b) {
  return (unsigned)f2b(a) | ((unsigned)f2b(b) << 16);
}

// ---------------------------------------------------------------------------
// fps canonicalization (int64 vs int32 storage) -> int32, clamped.
// ---------------------------------------------------------------------------
__global__ __launch_bounds__(256) void fps_canon_kernel(
    const int* __restrict__ fpsraw, int* __restrict__ fpsc)
{
  __shared__ int is64;
  const int tid = threadIdx.x;
  if (tid == 0) is64 = 1;
  __syncthreads();
  if (tid < 64) {
    if (fpsraw[2 * tid + 1] != 0) atomicAnd(&is64, 0);
  }
  __syncthreads();
  int i = blockIdx.x * 256 + tid;
  if (i < PQ_) {
    int src = is64 ? (2 * i) : i;
    int v = fpsraw[src];
    fpsc[i] = (v & 0xFFF);
  }
}

// ---------------------------------------------------------------------------
// KNN: exact 32 smallest (d, idx) via histogram radix-select (unchanged,
// passing & not the bottleneck). Distance arithmetic mirrors the reference.
// ---------------------------------------------------------------------------
#define CAND_CAP 1024

__global__ __launch_bounds__(256) void knn_kernel(
    const float* __restrict__ xyz, const int* __restrict__ fps,
    int* __restrict__ idxout, float* __restrict__ out_xyz)
{
  __shared__ float dar[N_];
  __shared__ unsigned hist[1024];
  __shared__ float cd[CAND_CAP];
  __shared__ int   ci_[CAND_CAP];
  __shared__ int   sel[K_];
  __shared__ int   wtot[4];
  __shared__ float bwd[4];
  __shared__ int   bwi[4];
  __shared__ int   sCnt, sCand, sT, sWin;

  const int q   = blockIdx.x;
  const int b   = q >> 10;
  const int tid = threadIdx.x;
  const float* xb = xyz + (size_t)b * N_ * 3;
  const int ctr = fps[q];
  const float cx = xb[ctr*3+0], cy = xb[ctr*3+1], cz = xb[ctr*3+2];

  if (tid == 0) {
    out_xyz[(size_t)q*3+0] = cx;
    out_xyz[(size_t)q*3+1] = cy;
    out_xyz[(size_t)q*3+2] = cz;
    sCnt = 0; sCand = 0;
  }
  for (int i = tid; i < 1024; i += 256) hist[i] = 0u;
  const float s1 = __fadd_rn(__fadd_rn(__fmul_rn(cx,cx), __fmul_rn(cy,cy)), __fmul_rn(cz,cz));
  __syncthreads();

  for (int n = tid; n < N_; n += 256) {
    float x0 = xb[n*3+0], x1 = xb[n*3+1], x2 = xb[n*3+2];
    float s2 = __fadd_rn(__fadd_rn(__fmul_rn(x0,x0), __fmul_rn(x1,x1)), __fmul_rn(x2,x2));
    float dt = __fadd_rn(__fadd_rn(__fmul_rn(cx,x0), __fmul_rn(cy,x1)), __fmul_rn(cz,x2));
    float d  = __fsub_rn(__fadd_rn(s1, s2), __fmul_rn(2.0f, dt));
    dar[n] = d;
    float dc = fmaxf(d, 0.0f);
    int bin = (int)(dc * 16.0f); bin = bin > 1023 ? 1023 : bin;
    atomicAdd(&hist[bin], 1u);
  }
  __syncthreads();

  const int base = tid * 4;
  int h0 = (int)hist[base], h1 = (int)hist[base+1], h2 = (int)hist[base+2], h3 = (int)hist[base+3];
  int lsum = h0 + h1 + h2 + h3;
  const int lane = tid & 63, wid = tid >> 6;
  int scv = lsum;
  #pragma unroll
  for (int off = 1; off < 64; off <<= 1) {
    int v = __shfl_up(scv, off, 64);
    if (lane >= off) scv += v;
  }
  if (lane == 63) wtot[wid] = scv;
  __syncthreads();
  int woff = 0;
  for (int w = 0; w < wid; ++w) woff += wtot[w];
  int run = woff + scv - lsum;
  int hh[4] = {h0, h1, h2, h3};
  #pragma unroll
  for (int j = 0; j < 4; ++j) {
    int c = hh[j];
    if (run < K_ && run + c >= K_) { sT = base + j; }
    run += c;
  }
  __syncthreads();
  const int T = sT;

  for (int n = tid; n < N_; n += 256) {
    float d  = dar[n];
    float dc = fmaxf(d, 0.0f);
    int bin = (int)(dc * 16.0f); bin = bin > 1023 ? 1023 : bin;
    if (bin < T) {
      int s = atomicAdd(&sCnt, 1);
      if (s < K_) sel[s] = n;
    } else if (bin == T) {
      int s = atomicAdd(&sCand, 1);
      if (s < CAND_CAP) { cd[s] = d; ci_[s] = n; }
    }
  }
  __syncthreads();

  int m = sCnt; m = m > K_ ? K_ : m;
  int cc = sCand; cc = cc > CAND_CAP ? CAND_CAP : cc;
  const int r = K_ - m;
  for (int it = 0; it < r; ++it) {
    float bd = 3.0e38f; int bi = 0x7fffffff;
    for (int j = tid; j < cc; j += 256) {
      float dv = cd[j]; int iv = ci_[j];
      if (dv < bd || (dv == bd && iv < bi)) { bd = dv; bi = iv; }
    }
    #pragma unroll
    for (int off = 32; off > 0; off >>= 1) {
      float od = __shfl_down(bd, off, 64);
      int   oi = __shfl_down(bi, off, 64);
      if (od < bd || (od == bd && oi < bi)) { bd = od; bi = oi; }
    }
    if (lane == 0) { bwd[wid] = bd; bwi[wid] = bi; }
    __syncthreads();
    if (tid == 0) {
      float fd = bwd[0]; int fi = bwi[0];
      for (int w = 1; w < 4; ++w) {
        float od = bwd[w]; int oi = bwi[w];
        if (od < fd || (od == fd && oi < fi)) { fd = od; fi = oi; }
      }
      sel[m + it] = fi & 0xFFF;
      sWin = fi;
    }
    __syncthreads();
    for (int j = tid; j < cc; j += 256) if (ci_[j] == sWin) cd[j] = 3.0e38f;
    __syncthreads();
  }
  if (tid < K_) idxout[(size_t)q * K_ + tid] = sel[tid] & 0xFFF;
}

// ===========================================================================
// MFMA MLP layers. Fragment mapping (verified m89/m91, gfx950 16x16x32 bf16):
//   A(M=16,K=32): lane holds A[row=lane&15][k=(lane>>4)*8+i]
//   B(K=32,N=16): lane holds B[k=(lane>>4)*8+i][col=lane&15]
//   D(M=16,N=16): lane holds D[row=(lane>>4)*4+j][col=lane&15]
// Global Y layout: 16B units, unit(kc,p) at index kc*P_+p holding channels
// kc*8..kc*8+7 for point p -> conflict-free ds_read_b128 B-frags.
// ===========================================================================

// ---------------------------------------------------------------------------
// l0: gather (feat c0..63, rel-xyz c64..66, pad->96) -> y0 = W0p*x + b0.
// Block: 256 thr (4 waves), 64o x 128p tile; wave w: p in [w*32, w*32+32).
// ---------------------------------------------------------------------------
__global__ __launch_bounds__(256) void l0_mfma(
    const float* __restrict__ xyz, const float* __restrict__ feat,
    const int* __restrict__ fps, const int* __restrict__ idxin,
    const float* __restrict__ W0, const float* __restrict__ b0,
    uint4* __restrict__ Y0g, float* __restrict__ sumg, float* __restrict__ sqg)
{
  __shared__ uint4 Xl[12*128];     // 24 KB
  __shared__ uint4 Wl[12*64];      // 12 KB
  __shared__ int   idxl[128];
  __shared__ float bl[64];
  __shared__ float ssum[64], ssq[64];

  const int tid = threadIdx.x;
  const int bid = blockIdx.x;
  const int pbase = bid * 128;
  const int q0 = bid * 4;
  const int b = bid >> 8;

  // ---- phase A: weights (channel-permuted), bias, idx, zero-pad chunks
  if (tid < 64) { bl[tid] = b0 ? b0[tid] : 0.f; ssum[tid] = 0.f; ssq[tid] = 0.f; }
  if (tid < 128) idxl[tid] = idxin[pbase + tid] & 0xFFF;
  for (int u = tid; u < 12*64; u += 256) {
    int kc = u >> 6, o = u & 63;
    unsigned pk[4];
    #pragma unroll
    for (int h = 0; h < 4; ++h) {
      int c0 = kc*8 + h*2, c1 = c0 + 1;
      float v0 = (c0 < 64) ? W0[o*67 + 3 + c0] : (c0 < 67 ? W0[o*67 + (c0-64)] : 0.f);
      float v1 = (c1 < 64) ? W0[o*67 + 3 + c1] : (c1 < 67 ? W0[o*67 + (c1-64)] : 0.f);
      pk[h] = pk2(v0, v1);
    }
    Wl[u] = make_uint4(pk[0], pk[1], pk[2], pk[3]);
  }
  for (int u = tid; u < 3*128; u += 256) Xl[9*128 + u] = make_uint4(0,0,0,0);
  __syncthreads();

  // ---- phase B: gather feat chunks 0..7 and xyz chunk 8
  for (int u = tid; u < 1024; u += 256) {
    int kc = u >> 7, p = u & 127;
    int n = idxl[p];
    const float* fp = feat + ((size_t)b * N_ + n) * 64 + kc*8;
    float4 fa = *(const float4*)fp;
    float4 fb = *(const float4*)(fp + 4);
    Xl[u] = make_uint4(pk2(fa.x, fa.y), pk2(fa.z, fa.w), pk2(fb.x, fb.y), pk2(fb.z, fb.w));
  }
  if (tid < 128) {
    int p = tid;
    int n = idxl[p];
    int ct = fps[q0 + (p >> 5)] & 0xFFF;
    const float* xb = xyz + (size_t)b * N_ * 3;
    float dx = xb[n*3+0] - xb[ct*3+0];
    float dy = xb[n*3+1] - xb[ct*3+1];
    float dz = xb[n*3+2] - xb[ct*3+2];
    Xl[8*128 + p] = make_uint4(pk2(dx, dy), (unsigned)f2b(dz), 0, 0);
  }
  __syncthreads();

  // ---- compute
  const int lane = tid & 63, w = tid >> 6, g = lane >> 4, fr = lane & 15;
  f32x4 acc[4][2];
  #pragma unroll
  for (int m = 0; m < 4; ++m)
    #pragma unroll
    for (int j = 0; j < 4; ++j) {
      float v = bl[m*16 + g*4 + j];
      acc[m][0][j] = v; acc[m][1][j] = v;
    }
  #pragma unroll
  for (int kk = 0; kk < 3; ++kk) {
    const int kc = kk*4 + g;
    bfrag a[4], xv[2];
    #pragma unroll
    for (int m = 0; m < 4; ++m) { uint4 u = Wl[kc*64 + m*16 + fr]; a[m] = *(bfrag*)&u; }
    #pragma unroll
    for (int n = 0; n < 2; ++n) { uint4 u = Xl[kc*128 + w*32 + n*16 + fr]; xv[n] = *(bfrag*)&u; }
    #pragma unroll
    for (int m = 0; m < 4; ++m)
      #pragma unroll
      for (int n = 0; n < 2; ++n)
        acc[m][n] = __builtin_amdgcn_mfma_f32_16x16x32_bf16(a[m], xv[n], acc[m][n], 0, 0, 0);
  }

  // ---- stats + subtiled store
  #pragma unroll
  for (int m = 0; m < 4; ++m) {
    #pragma unroll
    for (int j = 0; j < 4; ++j) {
      float v0 = acc[m][0][j], v1 = acc[m][1][j];
      float s = v0 + v1, s2 = v0*v0 + v1*v1;
      #pragma unroll
      for (int d = 1; d < 16; d <<= 1) { s += __shfl_xor(s, d); s2 += __shfl_xor(s2, d); }
      if (fr == 0) {
        atomicAdd(&ssum[m*16 + g*4 + j], s);
        atomicAdd(&ssq[m*16 + g*4 + j], s2);
      }
    }
    #pragma unroll
    for (int n = 0; n < 2; ++n) {
      uint2 vv;
      vv.x = pk2(acc[m][n][0], acc[m][n][1]);
      vv.y = pk2(acc[m][n][2], acc[m][n][3]);
      size_t unit = (size_t)(m*2 + (g>>1)) * P_ + pbase + w*32 + n*16 + fr;
      *(uint2*)((char*)Y0g + unit*16 + (g&1)*8) = vv;
    }
  }
  __syncthreads();
  if (tid < 64) { atomicAdd(&sumg[tid], ssum[tid]); atomicAdd(&sqg[tid], ssq[tid]); }
}

// ---------------------------------------------------------------------------
// l1: x = relu(sc0*y0+sh0) (bf16); y1 = W1*x + b1. 64o x 128p tile.
// ---------------------------------------------------------------------------
__global__ __launch_bounds__(256) void l1_mfma(
    const uint4* __restrict__ Y0g,
    const float* __restrict__ W1, const float* __restrict__ b1,
    const float* __restrict__ sc0, const float* __restrict__ sh0,
    uint4* __restrict__ Y1g, float* __restrict__ sumg, float* __restrict__ sqg)
{
  __shared__ uint4 Xl[8*128];      // 16 KB
  __shared__ uint4 Wl[8*64];       // 8 KB
  __shared__ float scl[64], shl[64], bl[64];
  __shared__ float ssum[64], ssq[64];

  const int tid = threadIdx.x;
  const int pbase = blockIdx.x * 128;

  if (tid < 64) {
    scl[tid] = sc0[tid]; shl[tid] = sh0[tid];
    bl[tid] = b1 ? b1[tid] : 0.f;
    ssum[tid] = 0.f; ssq[tid] = 0.f;
  }
  for (int u = tid; u < 8*64; u += 256) {
    int kc = u >> 6, o = u & 63;
    const float* wp = W1 + o*64 + kc*8;
    float4 wa = *(const float4*)wp;
    float4 wb = *(const float4*)(wp + 4);
    Wl[u] = make_uint4(pk2(wa.x, wa.y), pk2(wa.z, wa.w), pk2(wb.x, wb.y), pk2(wb.z, wb.w));
  }
  __syncthreads();

  for (int u = tid; u < 1024; u += 256) {
    int kc = u >> 7, p = u & 127;
    uint4 yv = Y0g[(size_t)kc * P_ + pbase + p];
    float4 sa = *(const float4*)&scl[kc*8];
    float4 sb = *(const float4*)&scl[kc*8 + 4];
    float4 ha = *(const float4*)&shl[kc*8];
    float4 hb = *(const float4*)&shl[kc*8 + 4];
    float x0 = fmaxf(fmaf(sa.x, b2f(yv.x),       ha.x), 0.f);
    float x1 = fmaxf(fmaf(sa.y, b2f(yv.x >> 16), ha.y), 0.f);
    float x2 = fmaxf(fmaf(sa.z, b2f(yv.y),       ha.z), 0.f);
    float x3 = fmaxf(fmaf(sa.w, b2f(yv.y >> 16), ha.w), 0.f);
    float x4 = fmaxf(fmaf(sb.x, b2f(yv.z),       hb.x), 0.f);
    float x5 = fmaxf(fmaf(sb.y, b2f(yv.z >> 16), hb.y), 0.f);
    float x6 = fmaxf(fmaf(sb.z, b2f(yv.w),       hb.z), 0.f);
    float x7 = fmaxf(fmaf(sb.w, b2f(yv.w >> 16), hb.w), 0.f);
    Xl[u] = make_uint4(pk2(x0, x1), pk2(x2, x3), pk2(x4, x5), pk2(x6, x7));
  }
  __syncthreads();

  const int lane = tid & 63, w = tid >> 6, g = lane >> 4, fr = lane & 15;
  f32x4 acc[4][2];
  #pragma unroll
  for (int m = 0; m < 4; ++m)
    #pragma unroll
    for (int j = 0; j < 4; ++j) {
      float v = bl[m*16 + g*4 + j];
      acc[m][0][j] = v; acc[m][1][j] = v;
    }
  #pragma unroll
  for (int kk = 0; kk < 2; ++kk) {
    const int kc = kk*4 + g;
    bfrag a[4], xv[2];
    #pragma unroll
    for (int m = 0; m < 4; ++m) { uint4 u = Wl[kc*64 + m*16 + fr]; a[m] = *(bfrag*)&u; }
    #pragma unroll
    for (int n = 0; n < 2; ++n) { uint4 u = Xl[kc*128 + w*32 + n*16 + fr]; xv[n] = *(bfrag*)&u; }
    #pragma unroll
    for (int m = 0; m < 4; ++m)
      #pragma unroll
      for (int n = 0; n < 2; ++n)
        acc[m][n] = __builtin_amdgcn_mfma_f32_16x16x32_bf16(a[m], xv[n], acc[m][n], 0, 0, 0);
  }

  #pragma unroll
  for (int m = 0; m < 4; ++m) {
    #pragma unroll
    for (int j = 0; j < 4; ++j) {
      float v0 = acc[m][0][j], v1 = acc[m][1][j];
      float s = v0 + v1, s2 = v0*v0 + v1*v1;
      #pragma unroll
      for (int d = 1; d < 16; d <<= 1) { s += __shfl_xor(s, d); s2 += __shfl_xor(s2, d); }
      if (fr == 0) {
        atomicAdd(&ssum[m*16 + g*4 + j], s);
        atomicAdd(&ssq[m*16 + g*4 + j], s2);
      }
    }
    #pragma unroll
    for (int n = 0; n < 2; ++n) {
      uint2 vv;
      vv.x = pk2(acc[m][n][0], acc[m][n][1]);
      vv.y = pk2(acc[m][n][2], acc[m][n][3]);
      size_t unit = (size_t)(m*2 + (g>>1)) * P_ + pbase + w*32 + n*16 + fr;
      *(uint2*)((char*)Y1g + unit*16 + (g&1)*8) = vv;
    }
  }
  __syncthreads();
  if (tid < 64) { atomicAdd(&sumg[tid], ssum[tid]); atomicAdd(&sqg[tid], ssq[tid]); }
}

// ---------------------------------------------------------------------------
// l2: x = relu(sc1*y1+sh1); y2 = W2*x + b2; per-(q,o) max/min over K=32 via
// shuffle tree (wave == query), + global stats. 128o x 128p tile.
// ---------------------------------------------------------------------------
__global__ __launch_bounds__(256) void l2_mfma(
    const uint4* __restrict__ Y1g,
    const float* __restrict__ W2, const float* __restrict__ b2,
    const float* __restrict__ sc1, const float* __restrict__ sh1,
    float* __restrict__ mxg, float* __restrict__ mng,
    float* __restrict__ sumg, float* __restrict__ sqg)
{
  __shared__ uint4 Xl[8*128];      // 16 KB
  __shared__ uint4 Wl[8*128];      // 16 KB
  __shared__ float scl[64], shl[64], bl[128];
  __shared__ float ssum[128], ssq[128];

  const int tid = threadIdx.x;
  const int pbase = blockIdx.x * 128;
  const int q0 = blockIdx.x * 4;

  if (tid < 64) { scl[tid] = sc1[tid]; shl[tid] = sh1[tid]; }
  if (tid < 128) { bl[tid] = b2 ? b2[tid] : 0.f; ssum[tid] = 0.f; ssq[tid] = 0.f; }
  for (int u = tid; u < 8*128; u += 256) {
    int kc = u >> 7, o = u & 127;
    const float* wp = W2 + o*64 + kc*8;
    float4 wa = *(const float4*)wp;
    float4 wb = *(const float4*)(wp + 4);
    Wl[u] = make_uint4(pk2(wa.x, wa.y), pk2(wa.z, wa.w), pk2(wb.x, wb.y), pk2(wb.z, wb.w));
  }
  __syncthreads();

  for (int u = tid; u < 1024; u += 256) {
    int kc = u >> 7, p = u & 127;
    uint4 yv = Y1g[(size_t)kc * P_ + pbase + p];
    float4 sa = *(const float4*)&scl[kc*8];
    float4 sb = *(const float4*)&scl[kc*8 + 4];
    float4 ha = *(const float4*)&shl[kc*8];
    float4 hb = *(const float4*)&shl[kc*8 + 4];
    float x0 = fmaxf(fmaf(sa.x, b2f(yv.x),       ha.x), 0.f);
    float x1 = fmaxf(fmaf(sa.y, b2f(yv.x >> 16), ha.y), 0.f);
    float x2 = fmaxf(fmaf(sa.z, b2f(yv.y),       ha.z), 0.f);
    float x3 = fmaxf(fmaf(sa.w, b2f(yv.y >> 16), ha.w), 0.f);
    float x4 = fmaxf(fmaf(sb.x, b2f(yv.z),       hb.x), 0.f);
    float x5 = fmaxf(fmaf(sb.y, b2f(yv.z >> 16), hb.y), 0.f);
    float x6 = fmaxf(fmaf(sb.z, b2f(yv.w),       hb.z), 0.f);
    float x7 = fmaxf(fmaf(sb.w, b2f(yv.w >> 16), hb.w), 0.f);
    Xl[u] = make_uint4(pk2(x0, x1), pk2(x2, x3), pk2(x4, x5), pk2(x6, x7));
  }
  __syncthreads();

  const int lane = tid & 63, w = tid >> 6, g = lane >> 4, fr = lane & 15;
  f32x4 acc[8][2];
  #pragma unroll
  for (int m = 0; m < 8; ++m)
    #pragma unroll
    for (int j = 0; j < 4; ++j) {
      float v = bl[m*16 + g*4 + j];
      acc[m][0][j] = v; acc[m][1][j] = v;
    }
  #pragma unroll
  for (int kk = 0; kk < 2; ++kk) {
    const int kc = kk*4 + g;
    bfrag a[8], xv[2];
    #pragma unroll
    for (int m = 0; m < 8; ++m) { uint4 u = Wl[kc*128 + m*16 + fr]; a[m] = *(bfrag*)&u; }
    #pragma unroll
    for (int n = 0; n < 2; ++n) { uint4 u = Xl[kc*128 + w*32 + n*16 + fr]; xv[n] = *(bfrag*)&u; }
    #pragma unroll
    for (int m = 0; m < 8; ++m)
      #pragma unroll
      for (int n = 0; n < 2; ++n)
        acc[m][n] = __builtin_amdgcn_mfma_f32_16x16x32_bf16(a[m], xv[n], acc[m][n], 0, 0, 0);
  }

  // wave w holds exactly query q0+w (its 32 points): fold pool into shuffles
  #pragma unroll
  for (int m = 0; m < 8; ++m) {
    #pragma unroll
    for (int j = 0; j < 4; ++j) {
      float v0 = acc[m][0][j], v1 = acc[m][1][j];
      float mx = fmaxf(v0, v1), mn = fminf(v0, v1);
      float s = v0 + v1, s2 = v0*v0 + v1*v1;
      #pragma unroll
      for (int d = 1; d < 16; d <<= 1) {
        mx = fmaxf(mx, __shfl_xor(mx, d));
        mn = fminf(mn, __shfl_xor(mn, d));
        s += __shfl_xor(s, d);
        s2 += __shfl_xor(s2, d);
      }
      if (fr == 0) {
        int o = m*16 + g*4 + j;
        size_t q = q0 + w;
        mxg[q*128 + o] = mx;
        mng[q*128 + o] = mn;
        atomicAdd(&ssum[o], s);
        atomicAdd(&ssq[o], s2);
      }
    }
  }
  __syncthreads();
  if (tid < 128) { atomicAdd(&sumg[tid], ssum[tid]); atomicAdd(&sqg[tid], ssq[tid]); }
}

// ---------------------------------------------------------------------------
// BN finalize: raw (sum, sumsq) -> (scale, shift) per channel.
// ---------------------------------------------------------------------------
__global__ void finalize_kernel(
    const float* __restrict__ sum, const float* __restrict__ sq,
    const float* __restrict__ g, const float* __restrict__ bt,
    float* __restrict__ sc, float* __restrict__ sh, int C)
{
  int c = threadIdx.x;
  if (c < C) {
    const float inv = 1.0f / (float)P_;
    float mu = sum[c] * inv;
    float var = sq[c] * inv - mu * mu;
    var = fmaxf(var, 0.f);
    float r = 1.0f / sqrtf(var + EPS_);
    float gg = g ? g[c] : 1.0f;
    float bb = bt ? bt[c] : 0.0f;
    float s = gg * r;
    sc[c] = s;
    sh[c] = bb - mu * s;
  }
}

// ---------------------------------------------------------------------------
// Epilogue: BN2 + ReLU + maxpool (affine commutes with max; min covers
// negative scale), write f32 features.
// ---------------------------------------------------------------------------
__global__ __launch_bounds__(256) void out_kernel(
    const float* __restrict__ mxg, const float* __restrict__ mng,
    const float* __restrict__ sc2, const float* __restrict__ sh2,
    float* __restrict__ out)
{
  int i = blockIdx.x * 256 + threadIdx.x;
  int o = i & 127;
  float a = sc2[o];
  float v = (a >= 0.f) ? mxg[i] : mng[i];
  float z = fmaxf(fmaf(a, v, sh2[o]), 0.f);
  out[(size_t)PQ_ * 3 + i] = z;
}

// ---------------------------------------------------------------------------
extern "C" void kernel_launch(void* const* d_in, const int* in_sizes, int n_in,
                              void* d_out, int out_size, void* d_ws, size_t ws_size,
                              hipStream_t stream)
{
  int i_xyz=-1, i_feat=-1, i_fps=-1, i_w0=-1, i_w1=-1, i_w2=-1;
  for (int i = 0; i < n_in; ++i) {
    switch (in_sizes[i]) {
      case 196608:  i_xyz = i; break;
      case 4194304: i_feat = i; break;
      case 16384:   i_fps = i; break;
      case 4288:    i_w0 = i; break;
      case 4096:    i_w1 = i; break;
      case 8192:    i_w2 = i; break;
      default: break;
    }
  }
  if (i_xyz < 0 || i_feat < 0 || i_fps < 0 || i_w0 < 0 || i_w1 < 0 || i_w2 < 0) return;

  const float* xyz  = (const float*)d_in[i_xyz];
  const float* feat = (const float*)d_in[i_feat];
  const int*   fpsr = (const int*)d_in[i_fps];
  const float* W0 = (const float*)d_in[i_w0];
  const float* W1 = (const float*)d_in[i_w1];
  const float* W2 = (const float*)d_in[i_w2];

  bool canon = (n_in >= 15 && i_xyz==0 && i_feat==1 && i_fps==2 && i_w0==3 &&
                i_w1==7 && i_w2==11 &&
                in_sizes[4]==64 && in_sizes[5]==64 && in_sizes[6]==64 &&
                in_sizes[8]==64 && in_sizes[9]==64 && in_sizes[10]==64 &&
                in_sizes[12]==128 && in_sizes[13]==128 && in_sizes[14]==128);
  const float* b0 = canon ? (const float*)d_in[4]  : nullptr;
  const float* g0 = canon ? (const float*)d_in[5]  : nullptr;
  const float* bt0= canon ? (const float*)d_in[6]  : nullptr;
  const float* b1 = canon ? (const float*)d_in[8]  : nullptr;
  const float* g1 = canon ? (const float*)d_in[9]  : nullptr;
  const float* bt1= canon ? (const float*)d_in[10] : nullptr;
  const float* b2 = canon ? (const float*)d_in[12] : nullptr;
  const float* g2 = canon ? (const float*)d_in[13] : nullptr;
  const float* bt2= canon ? (const float*)d_in[14] : nullptr;

  float* out = (float*)d_out;
  char* ws = (char*)d_ws;
  if (ws_size < WS_NEEDED) return;

  int* idxw = (int*)(ws + OFF_IDX);
  uint4* Y0 = (uint4*)(ws + OFF_Y0);
  uint4* Y1 = (uint4*)(ws + OFF_Y1);
  float* mxg = (float*)(ws + OFF_MX);
  float* mng = (float*)(ws + OFF_MN);
  float* st  = (float*)(ws + OFF_STATS);
  float* fin = (float*)(ws + OFF_FIN);
  int* fpsc  = (int*)(ws + OFF_FPSC);

  hipMemsetAsync(st, 0, 2048, stream);

  fps_canon_kernel<<<(PQ_+255)/256, 256, 0, stream>>>(fpsr, fpsc);

  knn_kernel<<<PQ_, 256, 0, stream>>>(xyz, fpsc, idxw, out);

  l0_mfma<<<P_/128, 256, 0, stream>>>(xyz, feat, fpsc, idxw, W0, b0, Y0, st + 0, st + 64);
  finalize_kernel<<<1, 64, 0, stream>>>(st + 0, st + 64, g0, bt0, fin + 0, fin + 64, 64);

  l1_mfma<<<P_/128, 256, 0, stream>>>(Y0, W1, b1, fin + 0, fin + 64, Y1, st + 128, st + 192);
  finalize_kernel<<<1, 64, 0, stream>>>(st + 128, st + 192, g1, bt1, fin + 128, fin + 192, 64);

  l2_mfma<<<P_/128, 256, 0, stream>>>(Y1, W2, b2, fin + 128, fin + 192, mxg, mng, st + 256, st + 384);
  finalize_kernel<<<1, 128, 0, stream>>>(st + 256, st + 384, g2, bt2, fin + 256, fin + 384, 128);

  out_kernel<<<(PQ_*128)/256, 256, 0, stream>>>(mxg, mng, fin + 256, fin + 384, out);
}

// Round 6
// 554.928 us; speedup vs baseline: 1.5913x; 1.1499x over previous
//
#include <hip/hip_runtime.h>
#include <stdint.h>

// Problem constants
#define B_   16
#define N_   4096
#define S_   1024
#define K_   32
#define CIN_ 64
#define P_   524288      // B*S*K points through the MLP
#define PQ_  16384       // B*S queries
#define EPS_ 1e-5f

// Workspace layout (bytes)
#define SZ_IDX    ((size_t)P_ * 4)            // knn indices, int32
#define SZ_Y      ((size_t)P_ * 64 * 2)       // 64ch x P bf16 (subtiled units)
#define SZ_MX     ((size_t)PQ_ * 128 * 4)     // per-(q,ch) f32
#define OFF_IDX   ((size_t)0)
#define OFF_Y0    (OFF_IDX + SZ_IDX)
#define OFF_Y1    (OFF_Y0 + SZ_Y)
#define OFF_MX    (OFF_Y1 + SZ_Y)
#define OFF_MN    (OFF_MX + SZ_MX)
#define OFF_STATS (OFF_MN + SZ_MX)            // 512 f32 raw sums (zeroed per launch)
#define OFF_FIN   (OFF_STATS + 2048)          // 512 f32 finalized scale/shift
#define OFF_FPSC  (OFF_FIN + 2048)            // canonical fps, 16384 int32
#define WS_NEEDED (OFF_FPSC + (size_t)PQ_ * 4)

typedef unsigned short u16;
typedef short bfrag __attribute__((ext_vector_type(8)));   // 8 bf16 (4 VGPRs)
typedef float f32x4 __attribute__((ext_vector_type(4)));

__device__ __forceinline__ float b2f(unsigned v) {
  return __uint_as_float((v & 0xffffu) << 16);
}
__device__ __forceinline__ u16 f2b(float f) {
  unsigned u = __float_as_uint(f);
  unsigned r = (u + 0x7fffu + ((u >> 16) & 1u)) >> 16;  // RNE
  return (u16)r;
}
__device__ __forceinline__ unsigned pk2(float a, float b) {
  return (unsigned)f2b(a) | ((unsigned)f2b(b) << 16);
}

// ---------------------------------------------------------------------------
// fps canonicalization (int64 vs int32 storage) -> int32, clamped.
// ---------------------------------------------------------------------------
__global__ __launch_bounds__(256) void fps_canon_kernel(
    const int* __restrict__ fpsraw, int* __restrict__ fpsc)
{
  __shared__ int is64;
  const int tid = threadIdx.x;
  if (tid == 0) is64 = 1;
  __syncthreads();
  if (tid < 64) {
    if (fpsraw[2 * tid + 1] != 0) atomicAnd(&is64, 0);
  }
  __syncthreads();
  int i = blockIdx.x * 256 + tid;
  if (i < PQ_) {
    int src = is64 ? (2 * i) : i;
    int v = fpsraw[src];
    fpsc[i] = (v & 0xFFF);
  }
}

// ---------------------------------------------------------------------------
// KNN: exact 32 smallest (d, idx) via histogram radix-select.
// 2048 bins of width 1/128 over d^2 in [0,16): bin T holds ~1-6 candidates,
// so the refine loop runs 0-3 iterations, executed by WAVE 0 ONLY (each lane
// owns candidate slots j == lane mod 64 -> no __syncthreads in the loop).
// Distance arithmetic mirrors the reference bit-for-bit (no FMA contraction).
// ---------------------------------------------------------------------------
#define NBIN 2048
#define CAND_CAP 1024

__global__ __launch_bounds__(256) void knn_kernel(
    const float* __restrict__ xyz, const int* __restrict__ fps,
    int* __restrict__ idxout, float* __restrict__ out_xyz)
{
  __shared__ float dar[N_];            // 16 KB
  __shared__ unsigned hist[NBIN];      // 8 KB
  __shared__ float cd[CAND_CAP];       // 4 KB
  __shared__ int   ci_[CAND_CAP];      // 4 KB
  __shared__ int   sel[K_];
  __shared__ int   wtot[4];
  __shared__ int   sCnt, sCand, sT;

  const int q   = blockIdx.x;
  const int b   = q >> 10;
  const int tid = threadIdx.x;
  const float* xb = xyz + (size_t)b * N_ * 3;
  const int ctr = fps[q];
  const float cx = xb[ctr*3+0], cy = xb[ctr*3+1], cz = xb[ctr*3+2];

  if (tid == 0) {
    out_xyz[(size_t)q*3+0] = cx;
    out_xyz[(size_t)q*3+1] = cy;
    out_xyz[(size_t)q*3+2] = cz;
    sCnt = 0; sCand = 0;
  }
  for (int i = tid; i < NBIN; i += 256) hist[i] = 0u;
  const float s1 = __fadd_rn(__fadd_rn(__fmul_rn(cx,cx), __fmul_rn(cy,cy)), __fmul_rn(cz,cz));
  __syncthreads();

  // pass 1: distances + histogram
  for (int n = tid; n < N_; n += 256) {
    float x0 = xb[n*3+0], x1 = xb[n*3+1], x2 = xb[n*3+2];
    float s2 = __fadd_rn(__fadd_rn(__fmul_rn(x0,x0), __fmul_rn(x1,x1)), __fmul_rn(x2,x2));
    float dt = __fadd_rn(__fadd_rn(__fmul_rn(cx,x0), __fmul_rn(cy,x1)), __fmul_rn(cz,x2));
    float d  = __fsub_rn(__fadd_rn(s1, s2), __fmul_rn(2.0f, dt));
    dar[n] = d;
    float dc = fmaxf(d, 0.0f);
    int bin = (int)(dc * 128.0f); bin = bin > (NBIN-1) ? (NBIN-1) : bin;
    atomicAdd(&hist[bin], 1u);
  }
  __syncthreads();

  // scan: find crossing bin T (cumulative count reaches K)
  const int base = tid * 8;
  int h[8]; int lsum = 0;
  #pragma unroll
  for (int j = 0; j < 8; ++j) { h[j] = (int)hist[base + j]; lsum += h[j]; }
  const int lane = tid & 63, wid = tid >> 6;
  int scv = lsum;
  #pragma unroll
  for (int off = 1; off < 64; off <<= 1) {
    int v = __shfl_up(scv, off, 64);
    if (lane >= off) scv += v;
  }
  if (lane == 63) wtot[wid] = scv;
  __syncthreads();
  int woff = 0;
  for (int w = 0; w < wid; ++w) woff += wtot[w];
  int run = woff + scv - lsum;
  #pragma unroll
  for (int j = 0; j < 8; ++j) {
    int c = h[j];
    if (run < K_ && run + c >= K_) { sT = base + j; }
    run += c;
  }
  __syncthreads();
  const int T = sT;

  // pass 2: below-T definitely selected; bin-T members become candidates
  for (int n = tid; n < N_; n += 256) {
    float d  = dar[n];
    float dc = fmaxf(d, 0.0f);
    int bin = (int)(dc * 128.0f); bin = bin > (NBIN-1) ? (NBIN-1) : bin;
    if (bin < T) {
      int s = atomicAdd(&sCnt, 1);
      if (s < K_) sel[s] = n;
    } else if (bin == T) {
      int s = atomicAdd(&sCand, 1);
      if (s < CAND_CAP) { cd[s] = d; ci_[s] = n; }
    }
  }
  __syncthreads();

  // refine: wave 0 only, no block barriers (lane owns j == lane mod 64)
  if (wid == 0) {
    int m = sCnt; m = m > K_ ? K_ : m;
    int cc = sCand; cc = cc > CAND_CAP ? CAND_CAP : cc;
    const int r = K_ - m;
    for (int it = 0; it < r; ++it) {
      float bd = 3.0e38f; int bi = 0x7fffffff;
      for (int j = lane; j < cc; j += 64) {
        float dv = cd[j]; int iv = ci_[j];
        if (dv < bd || (dv == bd && iv < bi)) { bd = dv; bi = iv; }
      }
      #pragma unroll
      for (int off = 32; off > 0; off >>= 1) {
        float od = __shfl_down(bd, off, 64);
        int   oi = __shfl_down(bi, off, 64);
        if (od < bd || (od == bd && oi < bi)) { bd = od; bi = oi; }
      }
      int win = __shfl(bi, 0, 64);
      if (lane == 0) sel[m + it] = win & 0xFFF;
      for (int j = lane; j < cc; j += 64) if (ci_[j] == win) cd[j] = 3.0e38f;
    }
  }
  __syncthreads();
  if (tid < K_) idxout[(size_t)q * K_ + tid] = sel[tid] & 0xFFF;
}

// ===========================================================================
// MFMA MLP layers. Fragment mapping (verified m89/m91, gfx950 16x16x32 bf16):
//   A(M=16,K=32): lane holds A[row=lane&15][k=(lane>>4)*8+i]
//   B(K=32,N=16): lane holds B[k=(lane>>4)*8+i][col=lane&15]
//   D(M=16,N=16): lane holds D[row=(lane>>4)*4+j][col=lane&15]
// Global Y layout: 16B units, unit(kc,p) at index kc*P_+p holding channels
// kc*8..kc*8+7 for point p -> conflict-free ds_read_b128 B-frags.
// ===========================================================================

// ---------------------------------------------------------------------------
// l0: gather (feat c0..63, rel-xyz c64..66, pad->96) -> y0 = W0p*x + b0.
// Block: 256 thr (4 waves), 64o x 128p tile; wave w: p in [w*32, w*32+32).
// ---------------------------------------------------------------------------
__global__ __launch_bounds__(256) void l0_mfma(
    const float* __restrict__ xyz, const float* __restrict__ feat,
    const int* __restrict__ fps, const int* __restrict__ idxin,
    const float* __restrict__ W0, const float* __restrict__ b0,
    uint4* __restrict__ Y0g, float* __restrict__ sumg, float* __restrict__ sqg)
{
  __shared__ uint4 Xl[12*128];     // 24 KB
  __shared__ uint4 Wl[12*64];      // 12 KB
  __shared__ int   idxl[128];
  __shared__ float bl[64];
  __shared__ float ssum[64], ssq[64];

  const int tid = threadIdx.x;
  const int bid = blockIdx.x;
  const int pbase = bid * 128;
  const int q0 = bid * 4;
  const int b = bid >> 8;

  if (tid < 64) { bl[tid] = b0 ? b0[tid] : 0.f; ssum[tid] = 0.f; ssq[tid] = 0.f; }
  if (tid < 128) idxl[tid] = idxin[pbase + tid] & 0xFFF;
  for (int u = tid; u < 12*64; u += 256) {
    int kc = u >> 6, o = u & 63;
    unsigned pk[4];
    #pragma unroll
    for (int h = 0; h < 4; ++h) {
      int c0 = kc*8 + h*2, c1 = c0 + 1;
      float v0 = (c0 < 64) ? W0[o*67 + 3 + c0] : (c0 < 67 ? W0[o*67 + (c0-64)] : 0.f);
      float v1 = (c1 < 64) ? W0[o*67 + 3 + c1] : (c1 < 67 ? W0[o*67 + (c1-64)] : 0.f);
      pk[h] = pk2(v0, v1);
    }
    Wl[u] = make_uint4(pk[0], pk[1], pk[2], pk[3]);
  }
  for (int u = tid; u < 3*128; u += 256) Xl[9*128 + u] = make_uint4(0,0,0,0);
  __syncthreads();

  for (int u = tid; u < 1024; u += 256) {
    int kc = u >> 7, p = u & 127;
    int n = idxl[p];
    const float* fp = feat + ((size_t)b * N_ + n) * 64 + kc*8;
    float4 fa = *(const float4*)fp;
    float4 fb = *(const float4*)(fp + 4);
    Xl[u] = make_uint4(pk2(fa.x, fa.y), pk2(fa.z, fa.w), pk2(fb.x, fb.y), pk2(fb.z, fb.w));
  }
  if (tid < 128) {
    int p = tid;
    int n = idxl[p];
    int ct = fps[q0 + (p >> 5)] & 0xFFF;
    const float* xb = xyz + (size_t)b * N_ * 3;
    float dx = xb[n*3+0] - xb[ct*3+0];
    float dy = xb[n*3+1] - xb[ct*3+1];
    float dz = xb[n*3+2] - xb[ct*3+2];
    Xl[8*128 + p] = make_uint4(pk2(dx, dy), (unsigned)f2b(dz), 0, 0);
  }
  __syncthreads();

  const int lane = tid & 63, w = tid >> 6, g = lane >> 4, fr = lane & 15;
  f32x4 acc[4][2];
  #pragma unroll
  for (int m = 0; m < 4; ++m)
    #pragma unroll
    for (int j = 0; j < 4; ++j) {
      float v = bl[m*16 + g*4 + j];
      acc[m][0][j] = v; acc[m][1][j] = v;
    }
  #pragma unroll
  for (int kk = 0; kk < 3; ++kk) {
    const int kc = kk*4 + g;
    bfrag a[4], xv[2];
    #pragma unroll
    for (int m = 0; m < 4; ++m) { uint4 u = Wl[kc*64 + m*16 + fr]; a[m] = *(bfrag*)&u; }
    #pragma unroll
    for (int n = 0; n < 2; ++n) { uint4 u = Xl[kc*128 + w*32 + n*16 + fr]; xv[n] = *(bfrag*)&u; }
    #pragma unroll
    for (int m = 0; m < 4; ++m)
      #pragma unroll
      for (int n = 0; n < 2; ++n)
        acc[m][n] = __builtin_amdgcn_mfma_f32_16x16x32_bf16(a[m], xv[n], acc[m][n], 0, 0, 0);
  }

  #pragma unroll
  for (int m = 0; m < 4; ++m) {
    #pragma unroll
    for (int j = 0; j < 4; ++j) {
      float v0 = acc[m][0][j], v1 = acc[m][1][j];
      float s = v0 + v1, s2 = v0*v0 + v1*v1;
      #pragma unroll
      for (int d = 1; d < 16; d <<= 1) { s += __shfl_xor(s, d); s2 += __shfl_xor(s2, d); }
      if (fr == 0) {
        atomicAdd(&ssum[m*16 + g*4 + j], s);
        atomicAdd(&ssq[m*16 + g*4 + j], s2);
      }
    }
    #pragma unroll
    for (int n = 0; n < 2; ++n) {
      uint2 vv;
      vv.x = pk2(acc[m][n][0], acc[m][n][1]);
      vv.y = pk2(acc[m][n][2], acc[m][n][3]);
      size_t unit = (size_t)(m*2 + (g>>1)) * P_ + pbase + w*32 + n*16 + fr;
      *(uint2*)((char*)Y0g + unit*16 + (g&1)*8) = vv;
    }
  }
  __syncthreads();
  if (tid < 64) { atomicAdd(&sumg[tid], ssum[tid]); atomicAdd(&sqg[tid], ssq[tid]); }
}

// ---------------------------------------------------------------------------
// l1: x = relu(sc0*y0+sh0) (bf16); y1 = W1*x + b1. 64o x 128p tile.
// ---------------------------------------------------------------------------
__global__ __launch_bounds__(256) void l1_mfma(
    const uint4* __restrict__ Y0g,
    const float* __restrict__ W1, const float* __restrict__ b1,
    const float* __restrict__ sc0, const float* __restrict__ sh0,
    uint4* __restrict__ Y1g, float* __restrict__ sumg, float* __restrict__ sqg)
{
  __shared__ uint4 Xl[8*128];      // 16 KB
  __shared__ uint4 Wl[8*64];       // 8 KB
  __shared__ float scl[64], shl[64], bl[64];
  __shared__ float ssum[64], ssq[64];

  const int tid = threadIdx.x;
  const int pbase = blockIdx.x * 128;

  if (tid < 64) {
    scl[tid] = sc0[tid]; shl[tid] = sh0[tid];
    bl[tid] = b1 ? b1[tid] : 0.f;
    ssum[tid] = 0.f; ssq[tid] = 0.f;
  }
  for (int u = tid; u < 8*64; u += 256) {
    int kc = u >> 6, o = u & 63;
    const float* wp = W1 + o*64 + kc*8;
    float4 wa = *(const float4*)wp;
    float4 wb = *(const float4*)(wp + 4);
    Wl[u] = make_uint4(pk2(wa.x, wa.y), pk2(wa.z, wa.w), pk2(wb.x, wb.y), pk2(wb.z, wb.w));
  }
  __syncthreads();

  for (int u = tid; u < 1024; u += 256) {
    int kc = u >> 7, p = u & 127;
    uint4 yv = Y0g[(size_t)kc * P_ + pbase + p];
    float4 sa = *(const float4*)&scl[kc*8];
    float4 sb = *(const float4*)&scl[kc*8 + 4];
    float4 ha = *(const float4*)&shl[kc*8];
    float4 hb = *(const float4*)&shl[kc*8 + 4];
    float x0 = fmaxf(fmaf(sa.x, b2f(yv.x),       ha.x), 0.f);
    float x1 = fmaxf(fmaf(sa.y, b2f(yv.x >> 16), ha.y), 0.f);
    float x2 = fmaxf(fmaf(sa.z, b2f(yv.y),       ha.z), 0.f);
    float x3 = fmaxf(fmaf(sa.w, b2f(yv.y >> 16), ha.w), 0.f);
    float x4 = fmaxf(fmaf(sb.x, b2f(yv.z),       hb.x), 0.f);
    float x5 = fmaxf(fmaf(sb.y, b2f(yv.z >> 16), hb.y), 0.f);
    float x6 = fmaxf(fmaf(sb.z, b2f(yv.w),       hb.z), 0.f);
    float x7 = fmaxf(fmaf(sb.w, b2f(yv.w >> 16), hb.w), 0.f);
    Xl[u] = make_uint4(pk2(x0, x1), pk2(x2, x3), pk2(x4, x5), pk2(x6, x7));
  }
  __syncthreads();

  const int lane = tid & 63, w = tid >> 6, g = lane >> 4, fr = lane & 15;
  f32x4 acc[4][2];
  #pragma unroll
  for (int m = 0; m < 4; ++m)
    #pragma unroll
    for (int j = 0; j < 4; ++j) {
      float v = bl[m*16 + g*4 + j];
      acc[m][0][j] = v; acc[m][1][j] = v;
    }
  #pragma unroll
  for (int kk = 0; kk < 2; ++kk) {
    const int kc = kk*4 + g;
    bfrag a[4], xv[2];
    #pragma unroll
    for (int m = 0; m < 4; ++m) { uint4 u = Wl[kc*64 + m*16 + fr]; a[m] = *(bfrag*)&u; }
    #pragma unroll
    for (int n = 0; n < 2; ++n) { uint4 u = Xl[kc*128 + w*32 + n*16 + fr]; xv[n] = *(bfrag*)&u; }
    #pragma unroll
    for (int m = 0; m < 4; ++m)
      #pragma unroll
      for (int n = 0; n < 2; ++n)
        acc[m][n] = __builtin_amdgcn_mfma_f32_16x16x32_bf16(a[m], xv[n], acc[m][n], 0, 0, 0);
  }

  #pragma unroll
  for (int m = 0; m < 4; ++m) {
    #pragma unroll
    for (int j = 0; j < 4; ++j) {
      float v0 = acc[m][0][j], v1 = acc[m][1][j];
      float s = v0 + v1, s2 = v0*v0 + v1*v1;
      #pragma unroll
      for (int d = 1; d < 16; d <<= 1) { s += __shfl_xor(s, d); s2 += __shfl_xor(s2, d); }
      if (fr == 0) {
        atomicAdd(&ssum[m*16 + g*4 + j], s);
        atomicAdd(&ssq[m*16 + g*4 + j], s2);
      }
    }
    #pragma unroll
    for (int n = 0; n < 2; ++n) {
      uint2 vv;
      vv.x = pk2(acc[m][n][0], acc[m][n][1]);
      vv.y = pk2(acc[m][n][2], acc[m][n][3]);
      size_t unit = (size_t)(m*2 + (g>>1)) * P_ + pbase + w*32 + n*16 + fr;
      *(uint2*)((char*)Y1g + unit*16 + (g&1)*8) = vv;
    }
  }
  __syncthreads();
  if (tid < 64) { atomicAdd(&sumg[tid], ssum[tid]); atomicAdd(&sqg[tid], ssq[tid]); }
}

// ---------------------------------------------------------------------------
// l2: x = relu(sc1*y1+sh1); y2 = W2*x + b2; per-(q,o) max/min over K=32 via
// shuffle tree (wave == query), + global stats. 128o x 128p tile.
// ---------------------------------------------------------------------------
__global__ __launch_bounds__(256) void l2_mfma(
    const uint4* __restrict__ Y1g,
    const float* __restrict__ W2, const float* __restrict__ b2,
    const float* __restrict__ sc1, const float* __restrict__ sh1,
    float* __restrict__ mxg, float* __restrict__ mng,
    float* __restrict__ sumg, float* __restrict__ sqg)
{
  __shared__ uint4 Xl[8*128];      // 16 KB
  __shared__ uint4 Wl[8*128];      // 16 KB
  __shared__ float scl[64], shl[64], bl[128];
  __shared__ float ssum[128], ssq[128];

  const int tid = threadIdx.x;
  const int pbase = blockIdx.x * 128;
  const int q0 = blockIdx.x * 4;

  if (tid < 64) { scl[tid] = sc1[tid]; shl[tid] = sh1[tid]; }
  if (tid < 128) { bl[tid] = b2 ? b2[tid] : 0.f; ssum[tid] = 0.f; ssq[tid] = 0.f; }
  for (int u = tid; u < 8*128; u += 256) {
    int kc = u >> 7, o = u & 127;
    const float* wp = W2 + o*64 + kc*8;
    float4 wa = *(const float4*)wp;
    float4 wb = *(const float4*)(wp + 4);
    Wl[u] = make_uint4(pk2(wa.x, wa.y), pk2(wa.z, wa.w), pk2(wb.x, wb.y), pk2(wb.z, wb.w));
  }
  __syncthreads();

  for (int u = tid; u < 1024; u += 256) {
    int kc = u >> 7, p = u & 127;
    uint4 yv = Y1g[(size_t)kc * P_ + pbase + p];
    float4 sa = *(const float4*)&scl[kc*8];
    float4 sb = *(const float4*)&scl[kc*8 + 4];
    float4 ha = *(const float4*)&shl[kc*8];
    float4 hb = *(const float4*)&shl[kc*8 + 4];
    float x0 = fmaxf(fmaf(sa.x, b2f(yv.x),       ha.x), 0.f);
    float x1 = fmaxf(fmaf(sa.y, b2f(yv.x >> 16), ha.y), 0.f);
    float x2 = fmaxf(fmaf(sa.z, b2f(yv.y),       ha.z), 0.f);
    float x3 = fmaxf(fmaf(sa.w, b2f(yv.y >> 16), ha.w), 0.f);
    float x4 = fmaxf(fmaf(sb.x, b2f(yv.z),       hb.x), 0.f);
    float x5 = fmaxf(fmaf(sb.y, b2f(yv.z >> 16), hb.y), 0.f);
    float x6 = fmaxf(fmaf(sb.z, b2f(yv.w),       hb.z), 0.f);
    float x7 = fmaxf(fmaf(sb.w, b2f(yv.w >> 16), hb.w), 0.f);
    Xl[u] = make_uint4(pk2(x0, x1), pk2(x2, x3), pk2(x4, x5), pk2(x6, x7));
  }
  __syncthreads();

  const int lane = tid & 63, w = tid >> 6, g = lane >> 4, fr = lane & 15;
  f32x4 acc[8][2];
  #pragma unroll
  for (int m = 0; m < 8; ++m)
    #pragma unroll
    for (int j = 0; j < 4; ++j) {
      float v = bl[m*16 + g*4 + j];
      acc[m][0][j] = v; acc[m][1][j] = v;
    }
  #pragma unroll
  for (int kk = 0; kk < 2; ++kk) {
    const int kc = kk*4 + g;
    bfrag a[8], xv[2];
    #pragma unroll
    for (int m = 0; m < 8; ++m) { uint4 u = Wl[kc*128 + m*16 + fr]; a[m] = *(bfrag*)&u; }
    #pragma unroll
    for (int n = 0; n < 2; ++n) { uint4 u = Xl[kc*128 + w*32 + n*16 + fr]; xv[n] = *(bfrag*)&u; }
    #pragma unroll
    for (int m = 0; m < 8; ++m)
      #pragma unroll
      for (int n = 0; n < 2; ++n)
        acc[m][n] = __builtin_amdgcn_mfma_f32_16x16x32_bf16(a[m], xv[n], acc[m][n], 0, 0, 0);
  }

  #pragma unroll
  for (int m = 0; m < 8; ++m) {
    #pragma unroll
    for (int j = 0; j < 4; ++j) {
      float v0 = acc[m][0][j], v1 = acc[m][1][j];
      float mx = fmaxf(v0, v1), mn = fminf(v0, v1);
      float s = v0 + v1, s2 = v0*v0 + v1*v1;
      #pragma unroll
      for (int d = 1; d < 16; d <<= 1) {
        mx = fmaxf(mx, __shfl_xor(mx, d));
        mn = fminf(mn, __shfl_xor(mn, d));
        s += __shfl_xor(s, d);
        s2 += __shfl_xor(s2, d);
      }
      if (fr == 0) {
        int o = m*16 + g*4 + j;
        size_t q = q0 + w;
        mxg[q*128 + o] = mx;
        mng[q*128 + o] = mn;
        atomicAdd(&ssum[o], s);
        atomicAdd(&ssq[o], s2);
      }
    }
  }
  __syncthreads();
  if (tid < 128) { atomicAdd(&sumg[tid], ssum[tid]); atomicAdd(&sqg[tid], ssq[tid]); }
}

// ---------------------------------------------------------------------------
// BN finalize: raw (sum, sumsq) -> (scale, shift) per channel.
// ---------------------------------------------------------------------------
__global__ void finalize_kernel(
    const float* __restrict__ sum, const float* __restrict__ sq,
    const float* __restrict__ g, const float* __restrict__ bt,
    float* __restrict__ sc, float* __restrict__ sh, int C)
{
  int c = threadIdx.x;
  if (c < C) {
    const float inv = 1.0f / (float)P_;
    float mu = sum[c] * inv;
    float var = sq[c] * inv - mu * mu;
    var = fmaxf(var, 0.f);
    float r = 1.0f / sqrtf(var + EPS_);
    float gg = g ? g[c] : 1.0f;
    float bb = bt ? bt[c] : 0.0f;
    float s = gg * r;
    sc[c] = s;
    sh[c] = bb - mu * s;
  }
}

// ---------------------------------------------------------------------------
// Epilogue: BN2 + ReLU + maxpool (affine commutes with max; min covers
// negative scale), write f32 features.
// ---------------------------------------------------------------------------
__global__ __launch_bounds__(256) void out_kernel(
    const float* __restrict__ mxg, const float* __restrict__ mng,
    const float* __restrict__ sc2, const float* __restrict__ sh2,
    float* __restrict__ out)
{
  int i = blockIdx.x * 256 + threadIdx.x;
  int o = i & 127;
  float a = sc2[o];
  float v = (a >= 0.f) ? mxg[i] : mng[i];
  float z = fmaxf(fmaf(a, v, sh2[o]), 0.f);
  out[(size_t)PQ_ * 3 + i] = z;
}

// ---------------------------------------------------------------------------
extern "C" void kernel_launch(void* const* d_in, const int* in_sizes, int n_in,
                              void* d_out, int out_size, void* d_ws, size_t ws_size,
                              hipStream_t stream)
{
  int i_xyz=-1, i_feat=-1, i_fps=-1, i_w0=-1, i_w1=-1, i_w2=-1;
  for (int i = 0; i < n_in; ++i) {
    switch (in_sizes[i]) {
      case 196608:  i_xyz = i; break;
      case 4194304: i_feat = i; break;
      case 16384:   i_fps = i; break;
      case 4288:    i_w0 = i; break;
      case 4096:    i_w1 = i; break;
      case 8192:    i_w2 = i; break;
      default: break;
    }
  }
  if (i_xyz < 0 || i_feat < 0 || i_fps < 0 || i_w0 < 0 || i_w1 < 0 || i_w2 < 0) return;

  const float* xyz  = (const float*)d_in[i_xyz];
  const float* feat = (const float*)d_in[i_feat];
  const int*   fpsr = (const int*)d_in[i_fps];
  const float* W0 = (const float*)d_in[i_w0];
  const float* W1 = (const float*)d_in[i_w1];
  const float* W2 = (const float*)d_in[i_w2];

  bool canon = (n_in >= 15 && i_xyz==0 && i_feat==1 && i_fps==2 && i_w0==3 &&
                i_w1==7 && i_w2==11 &&
                in_sizes[4]==64 && in_sizes[5]==64 && in_sizes[6]==64 &&
                in_sizes[8]==64 && in_sizes[9]==64 && in_sizes[10]==64 &&
                in_sizes[12]==128 && in_sizes[13]==128 && in_sizes[14]==128);
  const float* b0 = canon ? (const float*)d_in[4]  : nullptr;
  const float* g0 = canon ? (const float*)d_in[5]  : nullptr;
  const float* bt0= canon ? (const float*)d_in[6]  : nullptr;
  const float* b1 = canon ? (const float*)d_in[8]  : nullptr;
  const float* g1 = canon ? (const float*)d_in[9]  : nullptr;
  const float* bt1= canon ? (const float*)d_in[10] : nullptr;
  const float* b2 = canon ? (const float*)d_in[12] : nullptr;
  const float* g2 = canon ? (const float*)d_in[13] : nullptr;
  const float* bt2= canon ? (const float*)d_in[14] : nullptr;

  float* out = (float*)d_out;
  char* ws = (char*)d_ws;
  if (ws_size < WS_NEEDED) return;

  int* idxw = (int*)(ws + OFF_IDX);
  uint4* Y0 = (uint4*)(ws + OFF_Y0);
  uint4* Y1 = (uint4*)(ws + OFF_Y1);
  float* mxg = (float*)(ws + OFF_MX);
  float* mng = (float*)(ws + OFF_MN);
  float* st  = (float*)(ws + OFF_STATS);
  float* fin = (float*)(ws + OFF_FIN);
  int* fpsc  = (int*)(ws + OFF_FPSC);

  hipMemsetAsync(st, 0, 2048, stream);

  fps_canon_kernel<<<(PQ_+255)/256, 256, 0, stream>>>(fpsr, fpsc);

  knn_kernel<<<PQ_, 256, 0, stream>>>(xyz, fpsc, idxw, out);

  l0_mfma<<<P_/128, 256, 0, stream>>>(xyz, feat, fpsc, idxw, W0, b0, Y0, st + 0, st + 64);
  finalize_kernel<<<1, 64, 0, stream>>>(st + 0, st + 64, g0, bt0, fin + 0, fin + 64, 64);

  l1_mfma<<<P_/128, 256, 0, stream>>>(Y0, W1, b1, fin + 0, fin + 64, Y1, st + 128, st + 192);
  finalize_kernel<<<1, 64, 0, stream>>>(st + 128, st + 192, g1, bt1, fin + 128, fin + 192, 64);

  l2_mfma<<<P_/128, 256, 0, stream>>>(Y1, W2, b2, fin + 128, fin + 192, mxg, mng, st + 256, st + 384);
  finalize_kernel<<<1, 128, 0, stream>>>(st + 256, st + 384, g2, bt2, fin + 256, fin + 384, 128);

  out_kernel<<<(PQ_*128)/256, 256, 0, stream>>>(mxg, mng, fin + 256, fin + 384, out);
}

// Round 7
// 504.712 us; speedup vs baseline: 1.7497x; 1.0995x over previous
//
#include <hip/hip_runtime.h>
#include <stdint.h>

// Problem constants
#define B_   16
#define N_   4096
#define S_   1024
#define K_   32
#define CIN_ 64
#define P_   524288      // B*S*K points through the MLP
#define PQ_  16384       // B*S queries
#define EPS_ 1e-5f

// Workspace layout (bytes)
#define SZ_IDX    ((size_t)P_ * 4)            // knn indices, int32
#define SZ_Y      ((size_t)P_ * 64 * 2)       // 64ch x P bf16 (subtiled units)
#define SZ_MX     ((size_t)PQ_ * 128 * 4)     // per-(q,ch) f32
#define OFF_IDX   ((size_t)0)
#define OFF_Y0    (OFF_IDX + SZ_IDX)
#define OFF_Y1    (OFF_Y0 + SZ_Y)
#define OFF_MX    (OFF_Y1 + SZ_Y)
#define OFF_MN    (OFF_MX + SZ_MX)
#define OFF_STATS (OFF_MN + SZ_MX)            // 512 f32 raw sums (zeroed per launch)
#define OFF_FIN   (OFF_STATS + 2048)          // 512 f32 finalized scale/shift
#define OFF_FPSC  (OFF_FIN + 2048)            // canonical fps, 16384 int32
#define WS_NEEDED (OFF_FPSC + (size_t)PQ_ * 4)

typedef unsigned short u16;
typedef short bfrag __attribute__((ext_vector_type(8)));   // 8 bf16 (4 VGPRs)
typedef float f32x4 __attribute__((ext_vector_type(4)));

__device__ __forceinline__ float b2f(unsigned v) {
  return __uint_as_float((v & 0xffffu) << 16);
}
__device__ __forceinline__ u16 f2b(float f) {
  unsigned u = __float_as_uint(f);
  unsigned r = (u + 0x7fffu + ((u >> 16) & 1u)) >> 16;  // RNE
  return (u16)r;
}
__device__ __forceinline__ unsigned pk2(float a, float b) {
  return (unsigned)f2b(a) | ((unsigned)f2b(b) << 16);
}

// ---------------------------------------------------------------------------
// fps canonicalization (int64 vs int32 storage) -> int32, clamped.
// ---------------------------------------------------------------------------
__global__ __launch_bounds__(256) void fps_canon_kernel(
    const int* __restrict__ fpsraw, int* __restrict__ fpsc)
{
  __shared__ int is64;
  const int tid = threadIdx.x;
  if (tid == 0) is64 = 1;
  __syncthreads();
  if (tid < 64) {
    if (fpsraw[2 * tid + 1] != 0) atomicAnd(&is64, 0);
  }
  __syncthreads();
  int i = blockIdx.x * 256 + tid;
  if (i < PQ_) {
    int src = is64 ? (2 * i) : i;
    int v = fpsraw[src];
    fpsc[i] = (v & 0xFFF);
  }
}

// ---------------------------------------------------------------------------
// KNN v3: exact 32 smallest (d, idx) via histogram radix-select.
// - 2048 bins of width 1/128 over d^2 (bin T holds ~1-8 candidates)
// - NO dar cache: distances recomputed in pass 2 (xyz is L1-hot), LDS ~13 KB
//   -> 8 blocks/CU
// - pass 2 uses wave ballot compaction: ONE atomicAdd per wave per 64-chunk
// - refine loop: wave 0 only, register/shuffle only, no block barriers
// Distance arithmetic mirrors the reference bit-for-bit (no FMA contraction).
// ---------------------------------------------------------------------------
#define NBIN 2048
#define CAND_CAP 512

__global__ __launch_bounds__(256) void knn_kernel(
    const float* __restrict__ xyz, const int* __restrict__ fps,
    int* __restrict__ idxout, float* __restrict__ out_xyz)
{
  __shared__ unsigned hist[NBIN];      // 8 KB
  __shared__ float cd[CAND_CAP];       // 2 KB
  __shared__ int   ci_[CAND_CAP];      // 2 KB
  __shared__ int   sel[K_];
  __shared__ int   wtot[4];
  __shared__ int   sCnt, sCand, sT;

  const int q   = blockIdx.x;
  const int b   = q >> 10;
  const int tid = threadIdx.x;
  const float* xb = xyz + (size_t)b * N_ * 3;
  const int ctr = fps[q];
  const float cx = xb[ctr*3+0], cy = xb[ctr*3+1], cz = xb[ctr*3+2];

  if (tid == 0) {
    out_xyz[(size_t)q*3+0] = cx;
    out_xyz[(size_t)q*3+1] = cy;
    out_xyz[(size_t)q*3+2] = cz;
    sCnt = 0; sCand = 0;
  }
  for (int i = tid; i < NBIN; i += 256) hist[i] = 0u;
  const float s1 = __fadd_rn(__fadd_rn(__fmul_rn(cx,cx), __fmul_rn(cy,cy)), __fmul_rn(cz,cz));
  __syncthreads();

  // pass 1: distances -> histogram
  for (int n = tid; n < N_; n += 256) {
    float x0 = xb[n*3+0], x1 = xb[n*3+1], x2 = xb[n*3+2];
    float s2 = __fadd_rn(__fadd_rn(__fmul_rn(x0,x0), __fmul_rn(x1,x1)), __fmul_rn(x2,x2));
    float dt = __fadd_rn(__fadd_rn(__fmul_rn(cx,x0), __fmul_rn(cy,x1)), __fmul_rn(cz,x2));
    float d  = __fsub_rn(__fadd_rn(s1, s2), __fmul_rn(2.0f, dt));
    float dc = fmaxf(d, 0.0f);
    int bin = (int)(dc * 128.0f); bin = bin > (NBIN-1) ? (NBIN-1) : bin;
    atomicAdd(&hist[bin], 1u);
  }
  __syncthreads();

  // scan: find crossing bin T (cumulative count reaches K)
  const int base = tid * 8;
  int h[8]; int lsum = 0;
  #pragma unroll
  for (int j = 0; j < 8; ++j) { h[j] = (int)hist[base + j]; lsum += h[j]; }
  const int lane = tid & 63, wid = tid >> 6;
  int scv = lsum;
  #pragma unroll
  for (int off = 1; off < 64; off <<= 1) {
    int v = __shfl_up(scv, off, 64);
    if (lane >= off) scv += v;
  }
  if (lane == 63) wtot[wid] = scv;
  __syncthreads();
  int woff = 0;
  for (int w = 0; w < wid; ++w) woff += wtot[w];
  int run = woff + scv - lsum;
  #pragma unroll
  for (int j = 0; j < 8; ++j) {
    int c = h[j];
    if (run < K_ && run + c >= K_) { sT = base + j; }
    run += c;
  }
  __syncthreads();
  const int T = sT;

  // pass 2: recompute d; ballot-compact below-T (selected) and bin-T (cand)
  const unsigned long long lmask = (lane == 63) ? 0x7fffffffffffffffull
                                                : ((1ull << lane) - 1ull);
  for (int n = tid; n < N_; n += 256) {
    float x0 = xb[n*3+0], x1 = xb[n*3+1], x2 = xb[n*3+2];
    float s2 = __fadd_rn(__fadd_rn(__fmul_rn(x0,x0), __fmul_rn(x1,x1)), __fmul_rn(x2,x2));
    float dt = __fadd_rn(__fadd_rn(__fmul_rn(cx,x0), __fmul_rn(cy,x1)), __fmul_rn(cz,x2));
    float d  = __fsub_rn(__fadd_rn(s1, s2), __fmul_rn(2.0f, dt));
    float dc = fmaxf(d, 0.0f);
    int bin = (int)(dc * 128.0f); bin = bin > (NBIN-1) ? (NBIN-1) : bin;
    bool isSel  = (bin < T);
    bool isCand = (bin == T);
    unsigned long long mSel  = __ballot(isSel);
    unsigned long long mCand = __ballot(isCand);
    int baseS = 0, baseC = 0;
    if (lane == 0) {
      if (mSel)  baseS = atomicAdd(&sCnt,  __popcll(mSel));
      if (mCand) baseC = atomicAdd(&sCand, __popcll(mCand));
    }
    baseS = __shfl(baseS, 0, 64);
    baseC = __shfl(baseC, 0, 64);
    if (isSel) {
      int s = baseS + __popcll(mSel & lmask);
      if (s < K_) sel[s] = n;
    }
    if (isCand) {
      int s = baseC + __popcll(mCand & lmask);
      if (s < CAND_CAP) { cd[s] = d; ci_[s] = n; }
    }
  }
  __syncthreads();

  // refine: wave 0 only, no block barriers (lane owns j == lane mod 64)
  if (wid == 0) {
    int m = sCnt; m = m > K_ ? K_ : m;
    int cc = sCand; cc = cc > CAND_CAP ? CAND_CAP : cc;
    const int r = K_ - m;
    for (int it = 0; it < r; ++it) {
      float bd = 3.0e38f; int bi = 0x7fffffff;
      for (int j = lane; j < cc; j += 64) {
        float dv = cd[j]; int iv = ci_[j];
        if (dv < bd || (dv == bd && iv < bi)) { bd = dv; bi = iv; }
      }
      #pragma unroll
      for (int off = 32; off > 0; off >>= 1) {
        float od = __shfl_down(bd, off, 64);
        int   oi = __shfl_down(bi, off, 64);
        if (od < bd || (od == bd && oi < bi)) { bd = od; bi = oi; }
      }
      int win = __shfl(bi, 0, 64);
      if (lane == 0) sel[m + it] = win & 0xFFF;
      for (int j = lane; j < cc; j += 64) if (ci_[j] == win) cd[j] = 3.0e38f;
    }
  }
  __syncthreads();
  if (tid < K_) idxout[(size_t)q * K_ + tid] = sel[tid] & 0xFFF;
}

// ===========================================================================
// MFMA MLP layers. Fragment mapping (verified m89/m91, gfx950 16x16x32 bf16):
//   A(M=16,K=32): lane holds A[row=lane&15][k=(lane>>4)*8+i]
//   B(K=32,N=16): lane holds B[k=(lane>>4)*8+i][col=lane&15]
//   D(M=16,N=16): lane holds D[row=(lane>>4)*4+j][col=lane&15]
// Global Y layout: 16B units, unit(kc,p) at index kc*P_+p holding channels
// kc*8..kc*8+7 for point p -> conflict-free ds_read_b128 B-frags.
// ===========================================================================

// ---------------------------------------------------------------------------
// l0: gather (feat c0..63, rel-xyz c64..66, pad->96) -> y0 = W0p*x + b0.
// Block: 256 thr (4 waves), 64o x 128p tile; wave w: p in [w*32, w*32+32).
// ---------------------------------------------------------------------------
__global__ __launch_bounds__(256) void l0_mfma(
    const float* __restrict__ xyz, const float* __restrict__ feat,
    const int* __restrict__ fps, const int* __restrict__ idxin,
    const float* __restrict__ W0, const float* __restrict__ b0,
    uint4* __restrict__ Y0g, float* __restrict__ sumg, float* __restrict__ sqg)
{
  __shared__ uint4 Xl[12*128];     // 24 KB
  __shared__ uint4 Wl[12*64];      // 12 KB
  __shared__ int   idxl[128];
  __shared__ float bl[64];
  __shared__ float ssum[64], ssq[64];

  const int tid = threadIdx.x;
  const int bid = blockIdx.x;
  const int pbase = bid * 128;
  const int q0 = bid * 4;
  const int b = bid >> 8;

  if (tid < 64) { bl[tid] = b0 ? b0[tid] : 0.f; ssum[tid] = 0.f; ssq[tid] = 0.f; }
  if (tid < 128) idxl[tid] = idxin[pbase + tid] & 0xFFF;
  for (int u = tid; u < 12*64; u += 256) {
    int kc = u >> 6, o = u & 63;
    unsigned pk[4];
    #pragma unroll
    for (int h = 0; h < 4; ++h) {
      int c0 = kc*8 + h*2, c1 = c0 + 1;
      float v0 = (c0 < 64) ? W0[o*67 + 3 + c0] : (c0 < 67 ? W0[o*67 + (c0-64)] : 0.f);
      float v1 = (c1 < 64) ? W0[o*67 + 3 + c1] : (c1 < 67 ? W0[o*67 + (c1-64)] : 0.f);
      pk[h] = pk2(v0, v1);
    }
    Wl[u] = make_uint4(pk[0], pk[1], pk[2], pk[3]);
  }
  for (int u = tid; u < 3*128; u += 256) Xl[9*128 + u] = make_uint4(0,0,0,0);
  __syncthreads();

  for (int u = tid; u < 1024; u += 256) {
    int kc = u >> 7, p = u & 127;
    int n = idxl[p];
    const float* fp = feat + ((size_t)b * N_ + n) * 64 + kc*8;
    float4 fa = *(const float4*)fp;
    float4 fb = *(const float4*)(fp + 4);
    Xl[u] = make_uint4(pk2(fa.x, fa.y), pk2(fa.z, fa.w), pk2(fb.x, fb.y), pk2(fb.z, fb.w));
  }
  if (tid < 128) {
    int p = tid;
    int n = idxl[p];
    int ct = fps[q0 + (p >> 5)] & 0xFFF;
    const float* xb = xyz + (size_t)b * N_ * 3;
    float dx = xb[n*3+0] - xb[ct*3+0];
    float dy = xb[n*3+1] - xb[ct*3+1];
    float dz = xb[n*3+2] - xb[ct*3+2];
    Xl[8*128 + p] = make_uint4(pk2(dx, dy), (unsigned)f2b(dz), 0, 0);
  }
  __syncthreads();

  const int lane = tid & 63, w = tid >> 6, g = lane >> 4, fr = lane & 15;
  f32x4 acc[4][2];
  #pragma unroll
  for (int m = 0; m < 4; ++m)
    #pragma unroll
    for (int j = 0; j < 4; ++j) {
      float v = bl[m*16 + g*4 + j];
      acc[m][0][j] = v; acc[m][1][j] = v;
    }
  #pragma unroll
  for (int kk = 0; kk < 3; ++kk) {
    const int kc = kk*4 + g;
    bfrag a[4], xv[2];
    #pragma unroll
    for (int m = 0; m < 4; ++m) { uint4 u = Wl[kc*64 + m*16 + fr]; a[m] = *(bfrag*)&u; }
    #pragma unroll
    for (int n = 0; n < 2; ++n) { uint4 u = Xl[kc*128 + w*32 + n*16 + fr]; xv[n] = *(bfrag*)&u; }
    #pragma unroll
    for (int m = 0; m < 4; ++m)
      #pragma unroll
      for (int n = 0; n < 2; ++n)
        acc[m][n] = __builtin_amdgcn_mfma_f32_16x16x32_bf16(a[m], xv[n], acc[m][n], 0, 0, 0);
  }

  #pragma unroll
  for (int m = 0; m < 4; ++m) {
    #pragma unroll
    for (int j = 0; j < 4; ++j) {
      float v0 = acc[m][0][j], v1 = acc[m][1][j];
      float s = v0 + v1, s2 = v0*v0 + v1*v1;
      #pragma unroll
      for (int d = 1; d < 16; d <<= 1) { s += __shfl_xor(s, d); s2 += __shfl_xor(s2, d); }
      if (fr == 0) {
        atomicAdd(&ssum[m*16 + g*4 + j], s);
        atomicAdd(&ssq[m*16 + g*4 + j], s2);
      }
    }
    #pragma unroll
    for (int n = 0; n < 2; ++n) {
      uint2 vv;
      vv.x = pk2(acc[m][n][0], acc[m][n][1]);
      vv.y = pk2(acc[m][n][2], acc[m][n][3]);
      size_t unit = (size_t)(m*2 + (g>>1)) * P_ + pbase + w*32 + n*16 + fr;
      *(uint2*)((char*)Y0g + unit*16 + (g&1)*8) = vv;
    }
  }
  __syncthreads();
  if (tid < 64) { atomicAdd(&sumg[tid], ssum[tid]); atomicAdd(&sqg[tid], ssq[tid]); }
}

// ---------------------------------------------------------------------------
// l1: x = relu(sc0*y0+sh0) (bf16); y1 = W1*x + b1. 64o x 128p tile.
// ---------------------------------------------------------------------------
__global__ __launch_bounds__(256) void l1_mfma(
    const uint4* __restrict__ Y0g,
    const float* __restrict__ W1, const float* __restrict__ b1,
    const float* __restrict__ sc0, const float* __restrict__ sh0,
    uint4* __restrict__ Y1g, float* __restrict__ sumg, float* __restrict__ sqg)
{
  __shared__ uint4 Xl[8*128];      // 16 KB
  __shared__ uint4 Wl[8*64];       // 8 KB
  __shared__ float scl[64], shl[64], bl[64];
  __shared__ float ssum[64], ssq[64];

  const int tid = threadIdx.x;
  const int pbase = blockIdx.x * 128;

  if (tid < 64) {
    scl[tid] = sc0[tid]; shl[tid] = sh0[tid];
    bl[tid] = b1 ? b1[tid] : 0.f;
    ssum[tid] = 0.f; ssq[tid] = 0.f;
  }
  for (int u = tid; u < 8*64; u += 256) {
    int kc = u >> 6, o = u & 63;
    const float* wp = W1 + o*64 + kc*8;
    float4 wa = *(const float4*)wp;
    float4 wb = *(const float4*)(wp + 4);
    Wl[u] = make_uint4(pk2(wa.x, wa.y), pk2(wa.z, wa.w), pk2(wb.x, wb.y), pk2(wb.z, wb.w));
  }
  __syncthreads();

  for (int u = tid; u < 1024; u += 256) {
    int kc = u >> 7, p = u & 127;
    uint4 yv = Y0g[(size_t)kc * P_ + pbase + p];
    float4 sa = *(const float4*)&scl[kc*8];
    float4 sb = *(const float4*)&scl[kc*8 + 4];
    float4 ha = *(const float4*)&shl[kc*8];
    float4 hb = *(const float4*)&shl[kc*8 + 4];
    float x0 = fmaxf(fmaf(sa.x, b2f(yv.x),       ha.x), 0.f);
    float x1 = fmaxf(fmaf(sa.y, b2f(yv.x >> 16), ha.y), 0.f);
    float x2 = fmaxf(fmaf(sa.z, b2f(yv.y),       ha.z), 0.f);
    float x3 = fmaxf(fmaf(sa.w, b2f(yv.y >> 16), ha.w), 0.f);
    float x4 = fmaxf(fmaf(sb.x, b2f(yv.z),       hb.x), 0.f);
    float x5 = fmaxf(fmaf(sb.y, b2f(yv.z >> 16), hb.y), 0.f);
    float x6 = fmaxf(fmaf(sb.z, b2f(yv.w),       hb.z), 0.f);
    float x7 = fmaxf(fmaf(sb.w, b2f(yv.w >> 16), hb.w), 0.f);
    Xl[u] = make_uint4(pk2(x0, x1), pk2(x2, x3), pk2(x4, x5), pk2(x6, x7));
  }
  __syncthreads();

  const int lane = tid & 63, w = tid >> 6, g = lane >> 4, fr = lane & 15;
  f32x4 acc[4][2];
  #pragma unroll
  for (int m = 0; m < 4; ++m)
    #pragma unroll
    for (int j = 0; j < 4; ++j) {
      float v = bl[m*16 + g*4 + j];
      acc[m][0][j] = v; acc[m][1][j] = v;
    }
  #pragma unroll
  for (int kk = 0; kk < 2; ++kk) {
    const int kc = kk*4 + g;
    bfrag a[4], xv[2];
    #pragma unroll
    for (int m = 0; m < 4; ++m) { uint4 u = Wl[kc*64 + m*16 + fr]; a[m] = *(bfrag*)&u; }
    #pragma unroll
    for (int n = 0; n < 2; ++n) { uint4 u = Xl[kc*128 + w*32 + n*16 + fr]; xv[n] = *(bfrag*)&u; }
    #pragma unroll
    for (int m = 0; m < 4; ++m)
      #pragma unroll
      for (int n = 0; n < 2; ++n)
        acc[m][n] = __builtin_amdgcn_mfma_f32_16x16x32_bf16(a[m], xv[n], acc[m][n], 0, 0, 0);
  }

  #pragma unroll
  for (int m = 0; m < 4; ++m) {
    #pragma unroll
    for (int j = 0; j < 4; ++j) {
      float v0 = acc[m][0][j], v1 = acc[m][1][j];
      float s = v0 + v1, s2 = v0*v0 + v1*v1;
      #pragma unroll
      for (int d = 1; d < 16; d <<= 1) { s += __shfl_xor(s, d); s2 += __shfl_xor(s2, d); }
      if (fr == 0) {
        atomicAdd(&ssum[m*16 + g*4 + j], s);
        atomicAdd(&ssq[m*16 + g*4 + j], s2);
      }
    }
    #pragma unroll
    for (int n = 0; n < 2; ++n) {
      uint2 vv;
      vv.x = pk2(acc[m][n][0], acc[m][n][1]);
      vv.y = pk2(acc[m][n][2], acc[m][n][3]);
      size_t unit = (size_t)(m*2 + (g>>1)) * P_ + pbase + w*32 + n*16 + fr;
      *(uint2*)((char*)Y1g + unit*16 + (g&1)*8) = vv;
    }
  }
  __syncthreads();
  if (tid < 64) { atomicAdd(&sumg[tid], ssum[tid]); atomicAdd(&sqg[tid], ssq[tid]); }
}

// ---------------------------------------------------------------------------
// l2: x = relu(sc1*y1+sh1); y2 = W2*x + b2; per-(q,o) max/min over K=32 via
// shuffle tree (wave == query), + global stats. 128o x 128p tile.
// ---------------------------------------------------------------------------
__global__ __launch_bounds__(256) void l2_mfma(
    const uint4* __restrict__ Y1g,
    const float* __restrict__ W2, const float* __restrict__ b2,
    const float* __restrict__ sc1, const float* __restrict__ sh1,
    float* __restrict__ mxg, float* __restrict__ mng,
    float* __restrict__ sumg, float* __restrict__ sqg)
{
  __shared__ uint4 Xl[8*128];      // 16 KB
  __shared__ uint4 Wl[8*128];      // 16 KB
  __shared__ float scl[64], shl[64], bl[128];
  __shared__ float ssum[128], ssq[128];

  const int tid = threadIdx.x;
  const int pbase = blockIdx.x * 128;
  const int q0 = blockIdx.x * 4;

  if (tid < 64) { scl[tid] = sc1[tid]; shl[tid] = sh1[tid]; }
  if (tid < 128) { bl[tid] = b2 ? b2[tid] : 0.f; ssum[tid] = 0.f; ssq[tid] = 0.f; }
  for (int u = tid; u < 8*128; u += 256) {
    int kc = u >> 7, o = u & 127;
    const float* wp = W2 + o*64 + kc*8;
    float4 wa = *(const float4*)wp;
    float4 wb = *(const float4*)(wp + 4);
    Wl[u] = make_uint4(pk2(wa.x, wa.y), pk2(wa.z, wa.w), pk2(wb.x, wb.y), pk2(wb.z, wb.w));
  }
  __syncthreads();

  for (int u = tid; u < 1024; u += 256) {
    int kc = u >> 7, p = u & 127;
    uint4 yv = Y1g[(size_t)kc * P_ + pbase + p];
    float4 sa = *(const float4*)&scl[kc*8];
    float4 sb = *(const float4*)&scl[kc*8 + 4];
    float4 ha = *(const float4*)&shl[kc*8];
    float4 hb = *(const float4*)&shl[kc*8 + 4];
    float x0 = fmaxf(fmaf(sa.x, b2f(yv.x),       ha.x), 0.f);
    float x1 = fmaxf(fmaf(sa.y, b2f(yv.x >> 16), ha.y), 0.f);
    float x2 = fmaxf(fmaf(sa.z, b2f(yv.y),       ha.z), 0.f);
    float x3 = fmaxf(fmaf(sa.w, b2f(yv.y >> 16), ha.w), 0.f);
    float x4 = fmaxf(fmaf(sb.x, b2f(yv.z),       hb.x), 0.f);
    float x5 = fmaxf(fmaf(sb.y, b2f(yv.z >> 16), hb.y), 0.f);
    float x6 = fmaxf(fmaf(sb.z, b2f(yv.w),       hb.z), 0.f);
    float x7 = fmaxf(fmaf(sb.w, b2f(yv.w >> 16), hb.w), 0.f);
    Xl[u] = make_uint4(pk2(x0, x1), pk2(x2, x3), pk2(x4, x5), pk2(x6, x7));
  }
  __syncthreads();

  const int lane = tid & 63, w = tid >> 6, g = lane >> 4, fr = lane & 15;
  f32x4 acc[8][2];
  #pragma unroll
  for (int m = 0; m < 8; ++m)
    #pragma unroll
    for (int j = 0; j < 4; ++j) {
      float v = bl[m*16 + g*4 + j];
      acc[m][0][j] = v; acc[m][1][j] = v;
    }
  #pragma unroll
  for (int kk = 0; kk < 2; ++kk) {
    const int kc = kk*4 + g;
    bfrag a[8], xv[2];
    #pragma unroll
    for (int m = 0; m < 8; ++m) { uint4 u = Wl[kc*128 + m*16 + fr]; a[m] = *(bfrag*)&u; }
    #pragma unroll
    for (int n = 0; n < 2; ++n) { uint4 u = Xl[kc*128 + w*32 + n*16 + fr]; xv[n] = *(bfrag*)&u; }
    #pragma unroll
    for (int m = 0; m < 8; ++m)
      #pragma unroll
      for (int n = 0; n < 2; ++n)
        acc[m][n] = __builtin_amdgcn_mfma_f32_16x16x32_bf16(a[m], xv[n], acc[m][n], 0, 0, 0);
  }

  #pragma unroll
  for (int m = 0; m < 8; ++m) {
    #pragma unroll
    for (int j = 0; j < 4; ++j) {
      float v0 = acc[m][0][j], v1 = acc[m][1][j];
      float mx = fmaxf(v0, v1), mn = fminf(v0, v1);
      float s = v0 + v1, s2 = v0*v0 + v1*v1;
      #pragma unroll
      for (int d = 1; d < 16; d <<= 1) {
        mx = fmaxf(mx, __shfl_xor(mx, d));
        mn = fminf(mn, __shfl_xor(mn, d));
        s += __shfl_xor(s, d);
        s2 += __shfl_xor(s2, d);
      }
      if (fr == 0) {
        int o = m*16 + g*4 + j;
        size_t q = q0 + w;
        mxg[q*128 + o] = mx;
        mng[q*128 + o] = mn;
        atomicAdd(&ssum[o], s);
        atomicAdd(&ssq[o], s2);
      }
    }
  }
  __syncthreads();
  if (tid < 128) { atomicAdd(&sumg[tid], ssum[tid]); atomicAdd(&sqg[tid], ssq[tid]); }
}

// ---------------------------------------------------------------------------
// BN finalize: raw (sum, sumsq) -> (scale, shift) per channel.
// ---------------------------------------------------------------------------
__global__ void finalize_kernel(
    const float* __restrict__ sum, const float* __restrict__ sq,
    const float* __restrict__ g, const float* __restrict__ bt,
    float* __restrict__ sc, float* __restrict__ sh, int C)
{
  int c = threadIdx.x;
  if (c < C) {
    const float inv = 1.0f / (float)P_;
    float mu = sum[c] * inv;
    float var = sq[c] * inv - mu * mu;
    var = fmaxf(var, 0.f);
    float r = 1.0f / sqrtf(var + EPS_);
    float gg = g ? g[c] : 1.0f;
    float bb = bt ? bt[c] : 0.0f;
    float s = gg * r;
    sc[c] = s;
    sh[c] = bb - mu * s;
  }
}

// ---------------------------------------------------------------------------
// Epilogue: BN2 + ReLU + maxpool (affine commutes with max; min covers
// negative scale), write f32 features.
// ---------------------------------------------------------------------------
__global__ __launch_bounds__(256) void out_kernel(
    const float* __restrict__ mxg, const float* __restrict__ mng,
    const float* __restrict__ sc2, const float* __restrict__ sh2,
    float* __restrict__ out)
{
  int i = blockIdx.x * 256 + threadIdx.x;
  int o = i & 127;
  float a = sc2[o];
  float v = (a >= 0.f) ? mxg[i] : mng[i];
  float z = fmaxf(fmaf(a, v, sh2[o]), 0.f);
  out[(size_t)PQ_ * 3 + i] = z;
}

// ---------------------------------------------------------------------------
extern "C" void kernel_launch(void* const* d_in, const int* in_sizes, int n_in,
                              void* d_out, int out_size, void* d_ws, size_t ws_size,
                              hipStream_t stream)
{
  int i_xyz=-1, i_feat=-1, i_fps=-1, i_w0=-1, i_w1=-1, i_w2=-1;
  for (int i = 0; i < n_in; ++i) {
    switch (in_sizes[i]) {
      case 196608:  i_xyz = i; break;
      case 4194304: i_feat = i; break;
      case 16384:   i_fps = i; break;
      case 4288:    i_w0 = i; break;
      case 4096:    i_w1 = i; break;
      case 8192:    i_w2 = i; break;
      default: break;
    }
  }
  if (i_xyz < 0 || i_feat < 0 || i_fps < 0 || i_w0 < 0 || i_w1 < 0 || i_w2 < 0) return;

  const float* xyz  = (const float*)d_in[i_xyz];
  const float* feat = (const float*)d_in[i_feat];
  const int*   fpsr = (const int*)d_in[i_fps];
  const float* W0 = (const float*)d_in[i_w0];
  const float* W1 = (const float*)d_in[i_w1];
  const float* W2 = (const float*)d_in[i_w2];

  bool canon = (n_in >= 15 && i_xyz==0 && i_feat==1 && i_fps==2 && i_w0==3 &&
                i_w1==7 && i_w2==11 &&
                in_sizes[4]==64 && in_sizes[5]==64 && in_sizes[6]==64 &&
                in_sizes[8]==64 && in_sizes[9]==64 && in_sizes[10]==64 &&
                in_sizes[12]==128 && in_sizes[13]==128 && in_sizes[14]==128);
  const float* b0 = canon ? (const float*)d_in[4]  : nullptr;
  const float* g0 = canon ? (const float*)d_in[5]  : nullptr;
  const float* bt0= canon ? (const float*)d_in[6]  : nullptr;
  const float* b1 = canon ? (const float*)d_in[8]  : nullptr;
  const float* g1 = canon ? (const float*)d_in[9]  : nullptr;
  const float* bt1= canon ? (const float*)d_in[10] : nullptr;
  const float* b2 = canon ? (const float*)d_in[12] : nullptr;
  const float* g2 = canon ? (const float*)d_in[13] : nullptr;
  const float* bt2= canon ? (const float*)d_in[14] : nullptr;

  float* out = (float*)d_out;
  char* ws = (char*)d_ws;
  if (ws_size < WS_NEEDED) return;

  int* idxw = (int*)(ws + OFF_IDX);
  uint4* Y0 = (uint4*)(ws + OFF_Y0);
  uint4* Y1 = (uint4*)(ws + OFF_Y1);
  float* mxg = (float*)(ws + OFF_MX);
  float* mng = (float*)(ws + OFF_MN);
  float* st  = (float*)(ws + OFF_STATS);
  float* fin = (float*)(ws + OFF_FIN);
  int* fpsc  = (int*)(ws + OFF_FPSC);

  hipMemsetAsync(st, 0, 2048, stream);

  fps_canon_kernel<<<(PQ_+255)/256, 256, 0, stream>>>(fpsr, fpsc);

  knn_kernel<<<PQ_, 256, 0, stream>>>(xyz, fpsc, idxw, out);

  l0_mfma<<<P_/128, 256, 0, stream>>>(xyz, feat, fpsc, idxw, W0, b0, Y0, st + 0, st + 64);
  finalize_kernel<<<1, 64, 0, stream>>>(st + 0, st + 64, g0, bt0, fin + 0, fin + 64, 64);

  l1_mfma<<<P_/128, 256, 0, stream>>>(Y0, W1, b1, fin + 0, fin + 64, Y1, st + 128, st + 192);
  finalize_kernel<<<1, 64, 0, stream>>>(st + 128, st + 192, g1, bt1, fin + 128, fin + 192, 64);

  l2_mfma<<<P_/128, 256, 0, stream>>>(Y1, W2, b2, fin + 128, fin + 192, mxg, mng, st + 256, st + 384);
  finalize_kernel<<<1, 128, 0, stream>>>(st + 256, st + 384, g2, bt2, fin + 256, fin + 384, 128);

  out_kernel<<<(PQ_*128)/256, 256, 0, stream>>>(mxg, mng, fin + 256, fin + 384, out);
}

// Round 8
// 466.473 us; speedup vs baseline: 1.8931x; 1.0820x over previous
//
#include <hip/hip_runtime.h>
#include <stdint.h>

// Problem constants
#define B_   16
#define N_   4096
#define S_   1024
#define K_   32
#define CIN_ 64
#define P_   524288      // B*S*K points through the MLP
#define PQ_  16384       // B*S queries
#define EPS_ 1e-5f

// Workspace layout (bytes)
#define SZ_IDX    ((size_t)P_ * 4)            // knn indices, int32
#define SZ_Y      ((size_t)P_ * 64 * 2)       // 64ch x P bf16 (subtiled units)
#define SZ_MX     ((size_t)PQ_ * 128 * 4)     // per-(q,ch) f32
#define OFF_IDX   ((size_t)0)
#define OFF_Y0    (OFF_IDX + SZ_IDX)
#define OFF_Y1    (OFF_Y0 + SZ_Y)
#define OFF_MX    (OFF_Y1 + SZ_Y)
#define OFF_MN    (OFF_MX + SZ_MX)
#define OFF_STATS (OFF_MN + SZ_MX)            // 512 f32 raw sums (zeroed per launch)
#define OFF_FIN   (OFF_STATS + 2048)          // 512 f32 finalized scale/shift
#define OFF_FPSC  (OFF_FIN + 2048)            // canonical fps, 16384 int32
#define WS_NEEDED (OFF_FPSC + (size_t)PQ_ * 4)

typedef unsigned short u16;
typedef short bfrag __attribute__((ext_vector_type(8)));   // 8 bf16 (4 VGPRs)
typedef float f32x4 __attribute__((ext_vector_type(4)));

__device__ __forceinline__ float b2f(unsigned v) {
  return __uint_as_float((v & 0xffffu) << 16);
}
__device__ __forceinline__ u16 f2b(float f) {
  unsigned u = __float_as_uint(f);
  unsigned r = (u + 0x7fffu + ((u >> 16) & 1u)) >> 16;  // RNE
  return (u16)r;
}
__device__ __forceinline__ unsigned pk2(float a, float b) {
  return (unsigned)f2b(a) | ((unsigned)f2b(b) << 16);
}

// ---------------------------------------------------------------------------
// fps canonicalization (int64 vs int32 storage) -> int32, clamped.
// ---------------------------------------------------------------------------
__global__ __launch_bounds__(256) void fps_canon_kernel(
    const int* __restrict__ fpsraw, int* __restrict__ fpsc)
{
  __shared__ int is64;
  const int tid = threadIdx.x;
  if (tid == 0) is64 = 1;
  __syncthreads();
  if (tid < 64) {
    if (fpsraw[2 * tid + 1] != 0) atomicAnd(&is64, 0);
  }
  __syncthreads();
  int i = blockIdx.x * 256 + tid;
  if (i < PQ_) {
    int src = is64 ? (2 * i) : i;
    int v = fpsraw[src];
    fpsc[i] = (v & 0xFFF);
  }
}

// ---------------------------------------------------------------------------
// KNN v4: exact 32 smallest (d, idx) via histogram radix-select.
// - 2048 bins of width 1/128 over d^2 (bin T holds ~1-8 candidates)
// - per-thread REGISTER cache of the 16 distances (pass 2 has no loads and
//   no recompute)
// - pass 2 uses wave ballot compaction: ONE atomicAdd per wave per 64-chunk
// - refine loop: wave 0 only, register/shuffle only, no block barriers
// Distance arithmetic mirrors the reference bit-for-bit (no FMA contraction).
// ---------------------------------------------------------------------------
#define NBIN 2048
#define CAND_CAP 512

__global__ __launch_bounds__(256) void knn_kernel(
    const float* __restrict__ xyz, const int* __restrict__ fps,
    int* __restrict__ idxout, float* __restrict__ out_xyz)
{
  __shared__ unsigned hist[NBIN];      // 8 KB
  __shared__ float cd[CAND_CAP];       // 2 KB
  __shared__ int   ci_[CAND_CAP];      // 2 KB
  __shared__ int   sel[K_];
  __shared__ int   wtot[4];
  __shared__ int   sCnt, sCand, sT;

  const int q   = blockIdx.x;
  const int b   = q >> 10;
  const int tid = threadIdx.x;
  const float* xb = xyz + (size_t)b * N_ * 3;
  const int ctr = fps[q];
  const float cx = xb[ctr*3+0], cy = xb[ctr*3+1], cz = xb[ctr*3+2];

  if (tid == 0) {
    out_xyz[(size_t)q*3+0] = cx;
    out_xyz[(size_t)q*3+1] = cy;
    out_xyz[(size_t)q*3+2] = cz;
    sCnt = 0; sCand = 0;
  }
  for (int i = tid; i < NBIN; i += 256) hist[i] = 0u;
  const float s1 = __fadd_rn(__fadd_rn(__fmul_rn(cx,cx), __fmul_rn(cy,cy)), __fmul_rn(cz,cz));
  __syncthreads();

  // pass 1: distances -> registers + histogram
  float dreg[16];
  #pragma unroll
  for (int it = 0; it < 16; ++it) {
    int n = it * 256 + tid;
    float x0 = xb[n*3+0], x1 = xb[n*3+1], x2 = xb[n*3+2];
    float s2 = __fadd_rn(__fadd_rn(__fmul_rn(x0,x0), __fmul_rn(x1,x1)), __fmul_rn(x2,x2));
    float dt = __fadd_rn(__fadd_rn(__fmul_rn(cx,x0), __fmul_rn(cy,x1)), __fmul_rn(cz,x2));
    float d  = __fsub_rn(__fadd_rn(s1, s2), __fmul_rn(2.0f, dt));
    dreg[it] = d;
    float dc = fmaxf(d, 0.0f);
    int bin = (int)(dc * 128.0f); bin = bin > (NBIN-1) ? (NBIN-1) : bin;
    atomicAdd(&hist[bin], 1u);
  }
  __syncthreads();

  // scan: find crossing bin T (cumulative count reaches K)
  const int base = tid * 8;
  int h[8]; int lsum = 0;
  #pragma unroll
  for (int j = 0; j < 8; ++j) { h[j] = (int)hist[base + j]; lsum += h[j]; }
  const int lane = tid & 63, wid = tid >> 6;
  int scv = lsum;
  #pragma unroll
  for (int off = 1; off < 64; off <<= 1) {
    int v = __shfl_up(scv, off, 64);
    if (lane >= off) scv += v;
  }
  if (lane == 63) wtot[wid] = scv;
  __syncthreads();
  int woff = 0;
  for (int w = 0; w < wid; ++w) woff += wtot[w];
  int run = woff + scv - lsum;
  #pragma unroll
  for (int j = 0; j < 8; ++j) {
    int c = h[j];
    if (run < K_ && run + c >= K_) { sT = base + j; }
    run += c;
  }
  __syncthreads();
  const int T = sT;

  // pass 2: cached d; ballot-compact below-T (selected) and bin-T (cand)
  const unsigned long long lmask = (lane == 63) ? 0x7fffffffffffffffull
                                                : ((1ull << lane) - 1ull);
  #pragma unroll
  for (int it = 0; it < 16; ++it) {
    int n = it * 256 + tid;
    float d = dreg[it];
    float dc = fmaxf(d, 0.0f);
    int bin = (int)(dc * 128.0f); bin = bin > (NBIN-1) ? (NBIN-1) : bin;
    bool isSel  = (bin < T);
    bool isCand = (bin == T);
    unsigned long long mSel  = __ballot(isSel);
    unsigned long long mCand = __ballot(isCand);
    int baseS = 0, baseC = 0;
    if (lane == 0) {
      if (mSel)  baseS = atomicAdd(&sCnt,  __popcll(mSel));
      if (mCand) baseC = atomicAdd(&sCand, __popcll(mCand));
    }
    baseS = __shfl(baseS, 0, 64);
    baseC = __shfl(baseC, 0, 64);
    if (isSel) {
      int s = baseS + __popcll(mSel & lmask);
      if (s < K_) sel[s] = n;
    }
    if (isCand) {
      int s = baseC + __popcll(mCand & lmask);
      if (s < CAND_CAP) { cd[s] = d; ci_[s] = n; }
    }
  }
  __syncthreads();

  // refine: wave 0 only, no block barriers (lane owns j == lane mod 64)
  if (wid == 0) {
    int m = sCnt; m = m > K_ ? K_ : m;
    int cc = sCand; cc = cc > CAND_CAP ? CAND_CAP : cc;
    const int r = K_ - m;
    for (int it = 0; it < r; ++it) {
      float bd = 3.0e38f; int bi = 0x7fffffff;
      for (int j = lane; j < cc; j += 64) {
        float dv = cd[j]; int iv = ci_[j];
        if (dv < bd || (dv == bd && iv < bi)) { bd = dv; bi = iv; }
      }
      #pragma unroll
      for (int off = 32; off > 0; off >>= 1) {
        float od = __shfl_down(bd, off, 64);
        int   oi = __shfl_down(bi, off, 64);
        if (od < bd || (od == bd && oi < bi)) { bd = od; bi = oi; }
      }
      int win = __shfl(bi, 0, 64);
      if (lane == 0) sel[m + it] = win & 0xFFF;
      for (int j = lane; j < cc; j += 64) if (ci_[j] == win) cd[j] = 3.0e38f;
    }
  }
  __syncthreads();
  if (tid < K_) idxout[(size_t)q * K_ + tid] = sel[tid] & 0xFFF;
}

// ===========================================================================
// MFMA MLP layers. Fragment mapping (verified m89/m91, gfx950 16x16x32 bf16):
//   A(M=16,K=32): lane holds A[row=lane&15][k=(lane>>4)*8+i]
//   B(K=32,N=16): lane holds B[k=(lane>>4)*8+i][col=lane&15]
//   D(M=16,N=16): lane holds D[row=(lane>>4)*4+j][col=lane&15]
// A and B share the same lane layout, so the same register bytes serve as
// A[p][k] or B[k][p] -- used by l2's swapped-operand form.
// Global Y layout: 16B units, unit(kc,p) at index kc*P_+p holding channels
// kc*8..kc*8+7 for point p.
// ===========================================================================

// ---------------------------------------------------------------------------
// l0: gather (feat c0..63, rel-xyz c64..66, pad->96) -> y0 = W0p*x + b0.
// Block: 256 thr (4 waves), 64o x 128p tile; wave w: p in [w*32, w*32+32).
// ---------------------------------------------------------------------------
__global__ __launch_bounds__(256) void l0_mfma(
    const float* __restrict__ xyz, const float* __restrict__ feat,
    const int* __restrict__ fps, const int* __restrict__ idxin,
    const float* __restrict__ W0, const float* __restrict__ b0,
    uint4* __restrict__ Y0g, float* __restrict__ sumg, float* __restrict__ sqg)
{
  __shared__ uint4 Xl[12*128];     // 24 KB
  __shared__ uint4 Wl[12*64];      // 12 KB
  __shared__ int   idxl[128];
  __shared__ float bl[64];
  __shared__ float ssum[64], ssq[64];

  const int tid = threadIdx.x;
  const int bid = blockIdx.x;
  const int pbase = bid * 128;
  const int q0 = bid * 4;
  const int b = bid >> 8;

  if (tid < 64) { bl[tid] = b0 ? b0[tid] : 0.f; ssum[tid] = 0.f; ssq[tid] = 0.f; }
  if (tid < 128) idxl[tid] = idxin[pbase + tid] & 0xFFF;
  for (int u = tid; u < 12*64; u += 256) {
    int kc = u >> 6, o = u & 63;
    unsigned pk[4];
    #pragma unroll
    for (int h = 0; h < 4; ++h) {
      int c0 = kc*8 + h*2, c1 = c0 + 1;
      float v0 = (c0 < 64) ? W0[o*67 + 3 + c0] : (c0 < 67 ? W0[o*67 + (c0-64)] : 0.f);
      float v1 = (c1 < 64) ? W0[o*67 + 3 + c1] : (c1 < 67 ? W0[o*67 + (c1-64)] : 0.f);
      pk[h] = pk2(v0, v1);
    }
    Wl[u] = make_uint4(pk[0], pk[1], pk[2], pk[3]);
  }
  for (int u = tid; u < 3*128; u += 256) Xl[9*128 + u] = make_uint4(0,0,0,0);
  __syncthreads();

  for (int u = tid; u < 1024; u += 256) {
    int kc = u >> 7, p = u & 127;
    int n = idxl[p];
    const float* fp = feat + ((size_t)b * N_ + n) * 64 + kc*8;
    float4 fa = *(const float4*)fp;
    float4 fb = *(const float4*)(fp + 4);
    Xl[u] = make_uint4(pk2(fa.x, fa.y), pk2(fa.z, fa.w), pk2(fb.x, fb.y), pk2(fb.z, fb.w));
  }
  if (tid < 128) {
    int p = tid;
    int n = idxl[p];
    int ct = fps[q0 + (p >> 5)] & 0xFFF;
    const float* xb = xyz + (size_t)b * N_ * 3;
    float dx = xb[n*3+0] - xb[ct*3+0];
    float dy = xb[n*3+1] - xb[ct*3+1];
    float dz = xb[n*3+2] - xb[ct*3+2];
    Xl[8*128 + p] = make_uint4(pk2(dx, dy), (unsigned)f2b(dz), 0, 0);
  }
  __syncthreads();

  const int lane = tid & 63, w = tid >> 6, g = lane >> 4, fr = lane & 15;
  f32x4 acc[4][2];
  #pragma unroll
  for (int m = 0; m < 4; ++m)
    #pragma unroll
    for (int j = 0; j < 4; ++j) {
      float v = bl[m*16 + g*4 + j];
      acc[m][0][j] = v; acc[m][1][j] = v;
    }
  #pragma unroll
  for (int kk = 0; kk < 3; ++kk) {
    const int kc = kk*4 + g;
    bfrag a[4], xv[2];
    #pragma unroll
    for (int m = 0; m < 4; ++m) { uint4 u = Wl[kc*64 + m*16 + fr]; a[m] = *(bfrag*)&u; }
    #pragma unroll
    for (int n = 0; n < 2; ++n) { uint4 u = Xl[kc*128 + w*32 + n*16 + fr]; xv[n] = *(bfrag*)&u; }
    #pragma unroll
    for (int m = 0; m < 4; ++m)
      #pragma unroll
      for (int n = 0; n < 2; ++n)
        acc[m][n] = __builtin_amdgcn_mfma_f32_16x16x32_bf16(a[m], xv[n], acc[m][n], 0, 0, 0);
  }

  #pragma unroll
  for (int m = 0; m < 4; ++m) {
    #pragma unroll
    for (int j = 0; j < 4; ++j) {
      float v0 = acc[m][0][j], v1 = acc[m][1][j];
      float s = v0 + v1, s2 = v0*v0 + v1*v1;
      #pragma unroll
      for (int d = 1; d < 16; d <<= 1) { s += __shfl_xor(s, d); s2 += __shfl_xor(s2, d); }
      if (fr == 0) {
        atomicAdd(&ssum[m*16 + g*4 + j], s);
        atomicAdd(&ssq[m*16 + g*4 + j], s2);
      }
    }
    #pragma unroll
    for (int n = 0; n < 2; ++n) {
      uint2 vv;
      vv.x = pk2(acc[m][n][0], acc[m][n][1]);
      vv.y = pk2(acc[m][n][2], acc[m][n][3]);
      size_t unit = (size_t)(m*2 + (g>>1)) * P_ + pbase + w*32 + n*16 + fr;
      *(uint2*)((char*)Y0g + unit*16 + (g&1)*8) = vv;
    }
  }
  __syncthreads();
  if (tid < 64) { atomicAdd(&sumg[tid], ssum[tid]); atomicAdd(&sqg[tid], ssq[tid]); }
}

// ---------------------------------------------------------------------------
// l1: x = relu(sc0*y0+sh0) (bf16); y1 = W1*x + b1. 64o x 128p tile.
// ---------------------------------------------------------------------------
__global__ __launch_bounds__(256) void l1_mfma(
    const uint4* __restrict__ Y0g,
    const float* __restrict__ W1, const float* __restrict__ b1,
    const float* __restrict__ sc0, const float* __restrict__ sh0,
    uint4* __restrict__ Y1g, float* __restrict__ sumg, float* __restrict__ sqg)
{
  __shared__ uint4 Xl[8*128];      // 16 KB
  __shared__ uint4 Wl[8*64];       // 8 KB
  __shared__ float scl[64], shl[64], bl[64];
  __shared__ float ssum[64], ssq[64];

  const int tid = threadIdx.x;
  const int pbase = blockIdx.x * 128;

  if (tid < 64) {
    scl[tid] = sc0[tid]; shl[tid] = sh0[tid];
    bl[tid] = b1 ? b1[tid] : 0.f;
    ssum[tid] = 0.f; ssq[tid] = 0.f;
  }
  for (int u = tid; u < 8*64; u += 256) {
    int kc = u >> 6, o = u & 63;
    const float* wp = W1 + o*64 + kc*8;
    float4 wa = *(const float4*)wp;
    float4 wb = *(const float4*)(wp + 4);
    Wl[u] = make_uint4(pk2(wa.x, wa.y), pk2(wa.z, wa.w), pk2(wb.x, wb.y), pk2(wb.z, wb.w));
  }
  __syncthreads();

  for (int u = tid; u < 1024; u += 256) {
    int kc = u >> 7, p = u & 127;
    uint4 yv = Y0g[(size_t)kc * P_ + pbase + p];
    float4 sa = *(const float4*)&scl[kc*8];
    float4 sb = *(const float4*)&scl[kc*8 + 4];
    float4 ha = *(const float4*)&shl[kc*8];
    float4 hb = *(const float4*)&shl[kc*8 + 4];
    float x0 = fmaxf(fmaf(sa.x, b2f(yv.x),       ha.x), 0.f);
    float x1 = fmaxf(fmaf(sa.y, b2f(yv.x >> 16), ha.y), 0.f);
    float x2 = fmaxf(fmaf(sa.z, b2f(yv.y),       ha.z), 0.f);
    float x3 = fmaxf(fmaf(sa.w, b2f(yv.y >> 16), ha.w), 0.f);
    float x4 = fmaxf(fmaf(sb.x, b2f(yv.z),       hb.x), 0.f);
    float x5 = fmaxf(fmaf(sb.y, b2f(yv.z >> 16), hb.y), 0.f);
    float x6 = fmaxf(fmaf(sb.z, b2f(yv.w),       hb.z), 0.f);
    float x7 = fmaxf(fmaf(sb.w, b2f(yv.w >> 16), hb.w), 0.f);
    Xl[u] = make_uint4(pk2(x0, x1), pk2(x2, x3), pk2(x4, x5), pk2(x6, x7));
  }
  __syncthreads();

  const int lane = tid & 63, w = tid >> 6, g = lane >> 4, fr = lane & 15;
  f32x4 acc[4][2];
  #pragma unroll
  for (int m = 0; m < 4; ++m)
    #pragma unroll
    for (int j = 0; j < 4; ++j) {
      float v = bl[m*16 + g*4 + j];
      acc[m][0][j] = v; acc[m][1][j] = v;
    }
  #pragma unroll
  for (int kk = 0; kk < 2; ++kk) {
    const int kc = kk*4 + g;
    bfrag a[4], xv[2];
    #pragma unroll
    for (int m = 0; m < 4; ++m) { uint4 u = Wl[kc*64 + m*16 + fr]; a[m] = *(bfrag*)&u; }
    #pragma unroll
    for (int n = 0; n < 2; ++n) { uint4 u = Xl[kc*128 + w*32 + n*16 + fr]; xv[n] = *(bfrag*)&u; }
    #pragma unroll
    for (int m = 0; m < 4; ++m)
      #pragma unroll
      for (int n = 0; n < 2; ++n)
        acc[m][n] = __builtin_amdgcn_mfma_f32_16x16x32_bf16(a[m], xv[n], acc[m][n], 0, 0, 0);
  }

  #pragma unroll
  for (int m = 0; m < 4; ++m) {
    #pragma unroll
    for (int j = 0; j < 4; ++j) {
      float v0 = acc[m][0][j], v1 = acc[m][1][j];
      float s = v0 + v1, s2 = v0*v0 + v1*v1;
      #pragma unroll
      for (int d = 1; d < 16; d <<= 1) { s += __shfl_xor(s, d); s2 += __shfl_xor(s2, d); }
      if (fr == 0) {
        atomicAdd(&ssum[m*16 + g*4 + j], s);
        atomicAdd(&ssq[m*16 + g*4 + j], s2);
      }
    }
    #pragma unroll
    for (int n = 0; n < 2; ++n) {
      uint2 vv;
      vv.x = pk2(acc[m][n][0], acc[m][n][1]);
      vv.y = pk2(acc[m][n][2], acc[m][n][3]);
      size_t unit = (size_t)(m*2 + (g>>1)) * P_ + pbase + w*32 + n*16 + fr;
      *(uint2*)((char*)Y1g + unit*16 + (g&1)*8) = vv;
    }
  }
  __syncthreads();
  if (tid < 64) { atomicAdd(&sumg[tid], ssum[tid]); atomicAdd(&sqg[tid], ssq[tid]); }
}

// ---------------------------------------------------------------------------
// l2 v2 (swapped operands): A = X (points as rows), B = W -> D[point][chan].
// X loaded DIRECTLY global->register with BN+ReLU fused (no Xl LDS, one
// barrier fewer, LDS ~18 KB -> 8 blocks/CU). Per-channel pool over points:
// 8 in-register values + 2-step shuffle (xor 16/32). Coalesced mxg/mng writes.
// Wave w == query q0+w (its 32 points).
// ---------------------------------------------------------------------------
__global__ __launch_bounds__(256) void l2_mfma(
    const uint4* __restrict__ Y1g,
    const float* __restrict__ W2, const float* __restrict__ b2,
    const float* __restrict__ sc1, const float* __restrict__ sh1,
    float* __restrict__ mxg, float* __restrict__ mng,
    float* __restrict__ sumg, float* __restrict__ sqg)
{
  __shared__ uint4 Wl[8*128];      // 16 KB
  __shared__ float scl[64], shl[64], bl[128];
  __shared__ float ssum[128], ssq[128];

  const int tid = threadIdx.x;
  const int pbase = blockIdx.x * 128;
  const int q0 = blockIdx.x * 4;

  if (tid < 64) { scl[tid] = sc1[tid]; shl[tid] = sh1[tid]; }
  if (tid < 128) { bl[tid] = b2 ? b2[tid] : 0.f; ssum[tid] = 0.f; ssq[tid] = 0.f; }
  for (int u = tid; u < 8*128; u += 256) {
    int kc = u >> 7, o = u & 127;
    const float* wp = W2 + o*64 + kc*8;
    float4 wa = *(const float4*)wp;
    float4 wb = *(const float4*)(wp + 4);
    Wl[u] = make_uint4(pk2(wa.x, wa.y), pk2(wa.z, wa.w), pk2(wb.x, wb.y), pk2(wb.z, wb.w));
  }
  __syncthreads();

  const int lane = tid & 63, w = tid >> 6, g = lane >> 4, fr = lane & 15;

  // X A-frags: direct global load + BN+ReLU in-register. Thread's k-slice is
  // kc = kk*4+g; point row = w*32 + pm*16 + fr.
  bfrag ax[2][2];
  #pragma unroll
  for (int kk = 0; kk < 2; ++kk) {
    const int kc = kk*4 + g;
    float4 sa = *(const float4*)&scl[kc*8];
    float4 sb = *(const float4*)&scl[kc*8 + 4];
    float4 ha = *(const float4*)&shl[kc*8];
    float4 hb = *(const float4*)&shl[kc*8 + 4];
    #pragma unroll
    for (int pm = 0; pm < 2; ++pm) {
      uint4 yv = Y1g[(size_t)kc * P_ + pbase + w*32 + pm*16 + fr];
      unsigned r0 = pk2(fmaxf(fmaf(sa.x, b2f(yv.x),       ha.x), 0.f),
                        fmaxf(fmaf(sa.y, b2f(yv.x >> 16), ha.y), 0.f));
      unsigned r1 = pk2(fmaxf(fmaf(sa.z, b2f(yv.y),       ha.z), 0.f),
                        fmaxf(fmaf(sa.w, b2f(yv.y >> 16), ha.w), 0.f));
      unsigned r2 = pk2(fmaxf(fmaf(sb.x, b2f(yv.z),       hb.x), 0.f),
                        fmaxf(fmaf(sb.y, b2f(yv.z >> 16), hb.y), 0.f));
      unsigned r3 = pk2(fmaxf(fmaf(sb.z, b2f(yv.w),       hb.z), 0.f),
                        fmaxf(fmaf(sb.w, b2f(yv.w >> 16), hb.w), 0.f));
      uint4 uu = make_uint4(r0, r1, r2, r3);
      ax[kk][pm] = *(bfrag*)&uu;
    }
  }

  // acc[pm][cn]: D[row=point (g*4+j within subtile pm)][col=chan cn*16+fr]
  f32x4 acc[2][8];
  #pragma unroll
  for (int cn = 0; cn < 8; ++cn) {
    float v = bl[cn*16 + fr];
    #pragma unroll
    for (int j = 0; j < 4; ++j) { acc[0][cn][j] = v; acc[1][cn][j] = v; }
  }
  #pragma unroll
  for (int kk = 0; kk < 2; ++kk) {
    const int kc = kk*4 + g;
    #pragma unroll
    for (int cn = 0; cn < 8; ++cn) {
      uint4 u = Wl[kc*128 + cn*16 + fr];
      bfrag bw = *(bfrag*)&u;
      acc[0][cn] = __builtin_amdgcn_mfma_f32_16x16x32_bf16(ax[kk][0], bw, acc[0][cn], 0, 0, 0);
      acc[1][cn] = __builtin_amdgcn_mfma_f32_16x16x32_bf16(ax[kk][1], bw, acc[1][cn], 0, 0, 0);
    }
  }

  // pool + stats: 8 in-register values per (thread, cn), then xor 16/32.
  #pragma unroll
  for (int cn = 0; cn < 8; ++cn) {
    float mx = -3.0e38f, mn = 3.0e38f, s = 0.f, s2 = 0.f;
    #pragma unroll
    for (int pm = 0; pm < 2; ++pm)
      #pragma unroll
      for (int j = 0; j < 4; ++j) {
        float v = acc[pm][cn][j];
        mx = fmaxf(mx, v); mn = fminf(mn, v);
        s += v; s2 += v*v;
      }
    #pragma unroll
    for (int d = 16; d < 64; d <<= 1) {
      mx = fmaxf(mx, __shfl_xor(mx, d));
      mn = fminf(mn, __shfl_xor(mn, d));
      s  += __shfl_xor(s, d);
      s2 += __shfl_xor(s2, d);
    }
    if (g == 0) {
      int o = cn*16 + fr;
      size_t q = q0 + w;
      mxg[q*128 + o] = mx;
      mng[q*128 + o] = mn;
      atomicAdd(&ssum[o], s);
      atomicAdd(&ssq[o], s2);
    }
  }
  __syncthreads();
  if (tid < 128) { atomicAdd(&sumg[tid], ssum[tid]); atomicAdd(&sqg[tid], ssq[tid]); }
}

// ---------------------------------------------------------------------------
// BN finalize: raw (sum, sumsq) -> (scale, shift) per channel.
// ---------------------------------------------------------------------------
__global__ void finalize_kernel(
    const float* __restrict__ sum, const float* __restrict__ sq,
    const float* __restrict__ g, const float* __restrict__ bt,
    float* __restrict__ sc, float* __restrict__ sh, int C)
{
  int c = threadIdx.x;
  if (c < C) {
    const float inv = 1.0f / (float)P_;
    float mu = sum[c] * inv;
    float var = sq[c] * inv - mu * mu;
    var = fmaxf(var, 0.f);
    float r = 1.0f / sqrtf(var + EPS_);
    float gg = g ? g[c] : 1.0f;
    float bb = bt ? bt[c] : 0.0f;
    float s = gg * r;
    sc[c] = s;
    sh[c] = bb - mu * s;
  }
}

// ---------------------------------------------------------------------------
// Epilogue: BN2 + ReLU + maxpool (affine commutes with max; min covers
// negative scale), write f32 features.
// ---------------------------------------------------------------------------
__global__ __launch_bounds__(256) void out_kernel(
    const float* __restrict__ mxg, const float* __restrict__ mng,
    const float* __restrict__ sc2, const float* __restrict__ sh2,
    float* __restrict__ out)
{
  int i = blockIdx.x * 256 + threadIdx.x;
  int o = i & 127;
  float a = sc2[o];
  float v = (a >= 0.f) ? mxg[i] : mng[i];
  float z = fmaxf(fmaf(a, v, sh2[o]), 0.f);
  out[(size_t)PQ_ * 3 + i] = z;
}

// ---------------------------------------------------------------------------
extern "C" void kernel_launch(void* const* d_in, const int* in_sizes, int n_in,
                              void* d_out, int out_size, void* d_ws, size_t ws_size,
                              hipStream_t stream)
{
  int i_xyz=-1, i_feat=-1, i_fps=-1, i_w0=-1, i_w1=-1, i_w2=-1;
  for (int i = 0; i < n_in; ++i) {
    switch (in_sizes[i]) {
      case 196608:  i_xyz = i; break;
      case 4194304: i_feat = i; break;
      case 16384:   i_fps = i; break;
      case 4288:    i_w0 = i; break;
      case 4096:    i_w1 = i; break;
      case 8192:    i_w2 = i; break;
      default: break;
    }
  }
  if (i_xyz < 0 || i_feat < 0 || i_fps < 0 || i_w0 < 0 || i_w1 < 0 || i_w2 < 0) return;

  const float* xyz  = (const float*)d_in[i_xyz];
  const float* feat = (const float*)d_in[i_feat];
  const int*   fpsr = (const int*)d_in[i_fps];
  const float* W0 = (const float*)d_in[i_w0];
  const float* W1 = (const float*)d_in[i_w1];
  const float* W2 = (const float*)d_in[i_w2];

  bool canon = (n_in >= 15 && i_xyz==0 && i_feat==1 && i_fps==2 && i_w0==3 &&
                i_w1==7 && i_w2==11 &&
                in_sizes[4]==64 && in_sizes[5]==64 && in_sizes[6]==64 &&
                in_sizes[8]==64 && in_sizes[9]==64 && in_sizes[10]==64 &&
                in_sizes[12]==128 && in_sizes[13]==128 && in_sizes[14]==128);
  const float* b0 = canon ? (const float*)d_in[4]  : nullptr;
  const float* g0 = canon ? (const float*)d_in[5]  : nullptr;
  const float* bt0= canon ? (const float*)d_in[6]  : nullptr;
  const float* b1 = canon ? (const float*)d_in[8]  : nullptr;
  const float* g1 = canon ? (const float*)d_in[9]  : nullptr;
  const float* bt1= canon ? (const float*)d_in[10] : nullptr;
  const float* b2 = canon ? (const float*)d_in[12] : nullptr;
  const float* g2 = canon ? (const float*)d_in[13] : nullptr;
  const float* bt2= canon ? (const float*)d_in[14] : nullptr;

  float* out = (float*)d_out;
  char* ws = (char*)d_ws;
  if (ws_size < WS_NEEDED) return;

  int* idxw = (int*)(ws + OFF_IDX);
  uint4* Y0 = (uint4*)(ws + OFF_Y0);
  uint4* Y1 = (uint4*)(ws + OFF_Y1);
  float* mxg = (float*)(ws + OFF_MX);
  float* mng = (float*)(ws + OFF_MN);
  float* st  = (float*)(ws + OFF_STATS);
  float* fin = (float*)(ws + OFF_FIN);
  int* fpsc  = (int*)(ws + OFF_FPSC);

  hipMemsetAsync(st, 0, 2048, stream);

  fps_canon_kernel<<<(PQ_+255)/256, 256, 0, stream>>>(fpsr, fpsc);

  knn_kernel<<<PQ_, 256, 0, stream>>>(xyz, fpsc, idxw, out);

  l0_mfma<<<P_/128, 256, 0, stream>>>(xyz, feat, fpsc, idxw, W0, b0, Y0, st + 0, st + 64);
  finalize_kernel<<<1, 64, 0, stream>>>(st + 0, st + 64, g0, bt0, fin + 0, fin + 64, 64);

  l1_mfma<<<P_/128, 256, 0, stream>>>(Y0, W1, b1, fin + 0, fin + 64, Y1, st + 128, st + 192);
  finalize_kernel<<<1, 64, 0, stream>>>(st + 128, st + 192, g1, bt1, fin + 128, fin + 192, 64);

  l2_mfma<<<P_/128, 256, 0, stream>>>(Y1, W2, b2, fin + 128, fin + 192, mxg, mng, st + 256, st + 384);
  finalize_kernel<<<1, 128, 0, stream>>>(st + 256, st + 384, g2, bt2, fin + 256, fin + 384, 128);

  out_kernel<<<(PQ_*128)/256, 256, 0, stream>>>(mxg, mng, fin + 256, fin + 384, out);
}

// Round 9
// 458.314 us; speedup vs baseline: 1.9268x; 1.0178x over previous
//
#include <hip/hip_runtime.h>
#include <stdint.h>

// Problem constants
#define B_   16
#define N_   4096
#define S_   1024
#define K_   32
#define CIN_ 64
#define P_   524288      // B*S*K points through the MLP
#define PQ_  16384       // B*S queries
#define EPS_ 1e-5f

// Workspace layout (bytes)
#define SZ_IDX    ((size_t)P_ * 4)            // knn indices, int32
#define SZ_Y      ((size_t)P_ * 64 * 2)       // 64ch x P bf16 (subtiled units)
#define SZ_MX     ((size_t)PQ_ * 128 * 4)     // per-(q,ch) f32
#define OFF_IDX   ((size_t)0)
#define OFF_Y0    (OFF_IDX + SZ_IDX)
#define OFF_Y1    (OFF_Y0 + SZ_Y)
#define OFF_MX    (OFF_Y1 + SZ_Y)
#define OFF_MN    (OFF_MX + SZ_MX)
#define OFF_STATS (OFF_MN + SZ_MX)            // 512 f32 raw sums (zeroed per launch)
#define OFF_FIN   (OFF_STATS + 2048)          // 512 f32 finalized scale/shift
#define OFF_FPSC  (OFF_FIN + 2048)            // canonical fps, 16384 int32
#define WS_NEEDED (OFF_FPSC + (size_t)PQ_ * 4)

typedef unsigned short u16;
typedef short bfrag __attribute__((ext_vector_type(8)));   // 8 bf16 (4 VGPRs)
typedef float f32x4 __attribute__((ext_vector_type(4)));

__device__ __forceinline__ float b2f(unsigned v) {
  return __uint_as_float((v & 0xffffu) << 16);
}
__device__ __forceinline__ u16 f2b(float f) {
  unsigned u = __float_as_uint(f);
  unsigned r = (u + 0x7fffu + ((u >> 16) & 1u)) >> 16;  // RNE
  return (u16)r;
}
__device__ __forceinline__ unsigned pk2(float a, float b) {
  return (unsigned)f2b(a) | ((unsigned)f2b(b) << 16);
}

// ---------------------------------------------------------------------------
// fps canonicalization (int64 vs int32 storage) -> int32, clamped.
// ---------------------------------------------------------------------------
__global__ __launch_bounds__(256) void fps_canon_kernel(
    const int* __restrict__ fpsraw, int* __restrict__ fpsc)
{
  __shared__ int is64;
  const int tid = threadIdx.x;
  if (tid == 0) is64 = 1;
  __syncthreads();
  if (tid < 64) {
    if (fpsraw[2 * tid + 1] != 0) atomicAnd(&is64, 0);
  }
  __syncthreads();
  int i = blockIdx.x * 256 + tid;
  if (i < PQ_) {
    int src = is64 ? (2 * i) : i;
    int v = fpsraw[src];
    fpsc[i] = (v & 0xFFF);
  }
}

// ---------------------------------------------------------------------------
// KNN v4: exact 32 smallest (d, idx) via histogram radix-select.
// Register distance cache; ballot compaction; wave-0 refine.
// Distance arithmetic mirrors the reference bit-for-bit (no FMA contraction).
// ---------------------------------------------------------------------------
#define NBIN 2048
#define CAND_CAP 512

__global__ __launch_bounds__(256) void knn_kernel(
    const float* __restrict__ xyz, const int* __restrict__ fps,
    int* __restrict__ idxout, float* __restrict__ out_xyz)
{
  __shared__ unsigned hist[NBIN];      // 8 KB
  __shared__ float cd[CAND_CAP];       // 2 KB
  __shared__ int   ci_[CAND_CAP];      // 2 KB
  __shared__ int   sel[K_];
  __shared__ int   wtot[4];
  __shared__ int   sCnt, sCand, sT;

  const int q   = blockIdx.x;
  const int b   = q >> 10;
  const int tid = threadIdx.x;
  const float* xb = xyz + (size_t)b * N_ * 3;
  const int ctr = fps[q];
  const float cx = xb[ctr*3+0], cy = xb[ctr*3+1], cz = xb[ctr*3+2];

  if (tid == 0) {
    out_xyz[(size_t)q*3+0] = cx;
    out_xyz[(size_t)q*3+1] = cy;
    out_xyz[(size_t)q*3+2] = cz;
    sCnt = 0; sCand = 0;
  }
  for (int i = tid; i < NBIN; i += 256) hist[i] = 0u;
  const float s1 = __fadd_rn(__fadd_rn(__fmul_rn(cx,cx), __fmul_rn(cy,cy)), __fmul_rn(cz,cz));
  __syncthreads();

  float dreg[16];
  #pragma unroll
  for (int it = 0; it < 16; ++it) {
    int n = it * 256 + tid;
    float x0 = xb[n*3+0], x1 = xb[n*3+1], x2 = xb[n*3+2];
    float s2 = __fadd_rn(__fadd_rn(__fmul_rn(x0,x0), __fmul_rn(x1,x1)), __fmul_rn(x2,x2));
    float dt = __fadd_rn(__fadd_rn(__fmul_rn(cx,x0), __fmul_rn(cy,x1)), __fmul_rn(cz,x2));
    float d  = __fsub_rn(__fadd_rn(s1, s2), __fmul_rn(2.0f, dt));
    dreg[it] = d;
    float dc = fmaxf(d, 0.0f);
    int bin = (int)(dc * 128.0f); bin = bin > (NBIN-1) ? (NBIN-1) : bin;
    atomicAdd(&hist[bin], 1u);
  }
  __syncthreads();

  const int base = tid * 8;
  int h[8]; int lsum = 0;
  #pragma unroll
  for (int j = 0; j < 8; ++j) { h[j] = (int)hist[base + j]; lsum += h[j]; }
  const int lane = tid & 63, wid = tid >> 6;
  int scv = lsum;
  #pragma unroll
  for (int off = 1; off < 64; off <<= 1) {
    int v = __shfl_up(scv, off, 64);
    if (lane >= off) scv += v;
  }
  if (lane == 63) wtot[wid] = scv;
  __syncthreads();
  int woff = 0;
  for (int w = 0; w < wid; ++w) woff += wtot[w];
  int run = woff + scv - lsum;
  #pragma unroll
  for (int j = 0; j < 8; ++j) {
    int c = h[j];
    if (run < K_ && run + c >= K_) { sT = base + j; }
    run += c;
  }
  __syncthreads();
  const int T = sT;

  const unsigned long long lmask = (lane == 63) ? 0x7fffffffffffffffull
                                                : ((1ull << lane) - 1ull);
  #pragma unroll
  for (int it = 0; it < 16; ++it) {
    int n = it * 256 + tid;
    float d = dreg[it];
    float dc = fmaxf(d, 0.0f);
    int bin = (int)(dc * 128.0f); bin = bin > (NBIN-1) ? (NBIN-1) : bin;
    bool isSel  = (bin < T);
    bool isCand = (bin == T);
    unsigned long long mSel  = __ballot(isSel);
    unsigned long long mCand = __ballot(isCand);
    int baseS = 0, baseC = 0;
    if (lane == 0) {
      if (mSel)  baseS = atomicAdd(&sCnt,  __popcll(mSel));
      if (mCand) baseC = atomicAdd(&sCand, __popcll(mCand));
    }
    baseS = __shfl(baseS, 0, 64);
    baseC = __shfl(baseC, 0, 64);
    if (isSel) {
      int s = baseS + __popcll(mSel & lmask);
      if (s < K_) sel[s] = n;
    }
    if (isCand) {
      int s = baseC + __popcll(mCand & lmask);
      if (s < CAND_CAP) { cd[s] = d; ci_[s] = n; }
    }
  }
  __syncthreads();

  if (wid == 0) {
    int m = sCnt; m = m > K_ ? K_ : m;
    int cc = sCand; cc = cc > CAND_CAP ? CAND_CAP : cc;
    const int r = K_ - m;
    for (int it = 0; it < r; ++it) {
      float bd = 3.0e38f; int bi = 0x7fffffff;
      for (int j = lane; j < cc; j += 64) {
        float dv = cd[j]; int iv = ci_[j];
        if (dv < bd || (dv == bd && iv < bi)) { bd = dv; bi = iv; }
      }
      #pragma unroll
      for (int off = 32; off > 0; off >>= 1) {
        float od = __shfl_down(bd, off, 64);
        int   oi = __shfl_down(bi, off, 64);
        if (od < bd || (od == bd && oi < bi)) { bd = od; bi = oi; }
      }
      int win = __shfl(bi, 0, 64);
      if (lane == 0) sel[m + it] = win & 0xFFF;
      for (int j = lane; j < cc; j += 64) if (ci_[j] == win) cd[j] = 3.0e38f;
    }
  }
  __syncthreads();
  if (tid < K_) idxout[(size_t)q * K_ + tid] = sel[tid] & 0xFFF;
}

// ===========================================================================
// MFMA MLP layers. Fragment mapping (verified m89/m91, gfx950 16x16x32 bf16):
//   A(M=16,K=32): lane holds A[row=lane&15][k=(lane>>4)*8+i]
//   B(K=32,N=16): lane holds B[k=(lane>>4)*8+i][col=lane&15]
//   D(M=16,N=16): lane holds D[row=(lane>>4)*4+j][col=lane&15]
// Global Y layout: 16B units, unit(kc,p) at index kc*P_+p holding channels
// kc*8..kc*8+7 for point p. Each unit is consumed by exactly ONE lane ->
// B/A fragments are loaded DIRECTLY global->register (no LDS staging).
// ===========================================================================

// ---------------------------------------------------------------------------
// l0 v2: direct per-lane gather (no X LDS, 1 barrier), XCD-chunked swizzle.
// y0 = W0p * x + b0, bf16 subtiled out + global stats. 64o x 128p per block.
// ---------------------------------------------------------------------------
__global__ __launch_bounds__(256) void l0_mfma(
    const float* __restrict__ xyz, const float* __restrict__ feat,
    const int* __restrict__ fps, const int* __restrict__ idxin,
    const float* __restrict__ W0, const float* __restrict__ b0,
    uint4* __restrict__ Y0g, float* __restrict__ sumg, float* __restrict__ sqg)
{
  __shared__ uint4 Wl[12*64];      // 12 KB
  __shared__ float bl[64];
  __shared__ float ssum[64], ssq[64];

  const int tid = threadIdx.x;
  // XCD-chunked swizzle (bijective: gridDim.x = 4096 divisible by 8):
  // XCD x (bid0 % 8) gets contiguous logical blocks -> 2 batches -> feat
  // working set 2 MB per XCD L2.
  const int bid0 = blockIdx.x;
  const int bid = (bid0 & 7) * ((int)gridDim.x >> 3) + (bid0 >> 3);
  const int pbase = bid * 128;
  const int q0 = bid * 4;
  const int b = bid >> 8;

  if (tid < 64) { bl[tid] = b0 ? b0[tid] : 0.f; ssum[tid] = 0.f; ssq[tid] = 0.f; }
  for (int u = tid; u < 12*64; u += 256) {
    int kc = u >> 6, o = u & 63;
    unsigned pk[4];
    #pragma unroll
    for (int hh = 0; hh < 4; ++hh) {
      int c0 = kc*8 + hh*2, c1 = c0 + 1;
      float v0 = (c0 < 64) ? W0[o*67 + 3 + c0] : (c0 < 67 ? W0[o*67 + (c0-64)] : 0.f);
      float v1 = (c1 < 64) ? W0[o*67 + 3 + c1] : (c1 < 67 ? W0[o*67 + (c1-64)] : 0.f);
      pk[hh] = pk2(v0, v1);
    }
    Wl[u] = make_uint4(pk[0], pk[1], pk[2], pk[3]);
  }

  const int lane = tid & 63, w = tid >> 6, g = lane >> 4, fr = lane & 15;
  const float* xb = xyz + (size_t)b * N_ * 3;
  const float* fbase = feat + (size_t)b * N_ * 64;

  // direct gather of B-frags: point p = w*32 + pm*16 + fr, k-chunk kc = kk*4+g
  int pidx[2];
  const int ct = fps[q0 + w] & 0xFFF;          // wave-uniform center
  #pragma unroll
  for (int pm = 0; pm < 2; ++pm)
    pidx[pm] = idxin[pbase + w*32 + pm*16 + fr] & 0xFFF;

  bfrag xv[3][2];
  #pragma unroll
  for (int kk = 0; kk < 3; ++kk) {
    const int kc = kk*4 + g;
    #pragma unroll
    for (int pm = 0; pm < 2; ++pm) {
      uint4 uu;
      if (kc < 8) {
        const float* fp = fbase + pidx[pm]*64 + kc*8;
        float4 fa = *(const float4*)fp;
        float4 fb2 = *(const float4*)(fp + 4);
        uu = make_uint4(pk2(fa.x, fa.y), pk2(fa.z, fa.w),
                        pk2(fb2.x, fb2.y), pk2(fb2.z, fb2.w));
      } else if (kc == 8) {
        int n = pidx[pm];
        float dx = xb[n*3+0] - xb[ct*3+0];
        float dy = xb[n*3+1] - xb[ct*3+1];
        float dz = xb[n*3+2] - xb[ct*3+2];
        uu = make_uint4(pk2(dx, dy), (unsigned)f2b(dz), 0u, 0u);
      } else {
        uu = make_uint4(0u, 0u, 0u, 0u);
      }
      xv[kk][pm] = *(bfrag*)&uu;
    }
  }
  __syncthreads();

  f32x4 acc[4][2];
  #pragma unroll
  for (int m = 0; m < 4; ++m)
    #pragma unroll
    for (int j = 0; j < 4; ++j) {
      float v = bl[m*16 + g*4 + j];
      acc[m][0][j] = v; acc[m][1][j] = v;
    }
  #pragma unroll
  for (int kk = 0; kk < 3; ++kk) {
    const int kc = kk*4 + g;
    bfrag a[4];
    #pragma unroll
    for (int m = 0; m < 4; ++m) { uint4 u = Wl[kc*64 + m*16 + fr]; a[m] = *(bfrag*)&u; }
    #pragma unroll
    for (int m = 0; m < 4; ++m)
      #pragma unroll
      for (int pm = 0; pm < 2; ++pm)
        acc[m][pm] = __builtin_amdgcn_mfma_f32_16x16x32_bf16(a[m], xv[kk][pm], acc[m][pm], 0, 0, 0);
  }

  #pragma unroll
  for (int m = 0; m < 4; ++m) {
    #pragma unroll
    for (int j = 0; j < 4; ++j) {
      float v0 = acc[m][0][j], v1 = acc[m][1][j];
      float s = v0 + v1, s2 = v0*v0 + v1*v1;
      #pragma unroll
      for (int d = 1; d < 16; d <<= 1) { s += __shfl_xor(s, d); s2 += __shfl_xor(s2, d); }
      if (fr == 0) {
        atomicAdd(&ssum[m*16 + g*4 + j], s);
        atomicAdd(&ssq[m*16 + g*4 + j], s2);
      }
    }
    #pragma unroll
    for (int pm = 0; pm < 2; ++pm) {
      uint2 vv;
      vv.x = pk2(acc[m][pm][0], acc[m][pm][1]);
      vv.y = pk2(acc[m][pm][2], acc[m][pm][3]);
      size_t unit = (size_t)(m*2 + (g>>1)) * P_ + pbase + w*32 + pm*16 + fr;
      *(uint2*)((char*)Y0g + unit*16 + (g&1)*8) = vv;
    }
  }
  __syncthreads();
  if (tid < 64) { atomicAdd(&sumg[tid], ssum[tid]); atomicAdd(&sqg[tid], ssq[tid]); }
}

// ---------------------------------------------------------------------------
// l1 v2: direct Y0 unit load + fused BN/ReLU (no X LDS); y1 = W1*x + b1.
// ---------------------------------------------------------------------------
__global__ __launch_bounds__(256) void l1_mfma(
    const uint4* __restrict__ Y0g,
    const float* __restrict__ W1, const float* __restrict__ b1,
    const float* __restrict__ sc0, const float* __restrict__ sh0,
    uint4* __restrict__ Y1g, float* __restrict__ sumg, float* __restrict__ sqg)
{
  __shared__ uint4 Wl[8*64];       // 8 KB
  __shared__ float scl[64], shl[64], bl[64];
  __shared__ float ssum[64], ssq[64];

  const int tid = threadIdx.x;
  const int pbase = blockIdx.x * 128;

  if (tid < 64) {
    scl[tid] = sc0[tid]; shl[tid] = sh0[tid];
    bl[tid] = b1 ? b1[tid] : 0.f;
    ssum[tid] = 0.f; ssq[tid] = 0.f;
  }
  for (int u = tid; u < 8*64; u += 256) {
    int kc = u >> 6, o = u & 63;
    const float* wp = W1 + o*64 + kc*8;
    float4 wa = *(const float4*)wp;
    float4 wb = *(const float4*)(wp + 4);
    Wl[u] = make_uint4(pk2(wa.x, wa.y), pk2(wa.z, wa.w), pk2(wb.x, wb.y), pk2(wb.z, wb.w));
  }
  __syncthreads();

  const int lane = tid & 63, w = tid >> 6, g = lane >> 4, fr = lane & 15;

  bfrag xv[2][2];
  #pragma unroll
  for (int kk = 0; kk < 2; ++kk) {
    const int kc = kk*4 + g;
    float4 sa = *(const float4*)&scl[kc*8];
    float4 sb = *(const float4*)&scl[kc*8 + 4];
    float4 ha = *(const float4*)&shl[kc*8];
    float4 hb = *(const float4*)&shl[kc*8 + 4];
    #pragma unroll
    for (int pm = 0; pm < 2; ++pm) {
      uint4 yv = Y0g[(size_t)kc * P_ + pbase + w*32 + pm*16 + fr];
      unsigned r0 = pk2(fmaxf(fmaf(sa.x, b2f(yv.x),       ha.x), 0.f),
                        fmaxf(fmaf(sa.y, b2f(yv.x >> 16), ha.y), 0.f));
      unsigned r1 = pk2(fmaxf(fmaf(sa.z, b2f(yv.y),       ha.z), 0.f),
                        fmaxf(fmaf(sa.w, b2f(yv.y >> 16), ha.w), 0.f));
      unsigned r2 = pk2(fmaxf(fmaf(sb.x, b2f(yv.z),       hb.x), 0.f),
                        fmaxf(fmaf(sb.y, b2f(yv.z >> 16), hb.y), 0.f));
      unsigned r3 = pk2(fmaxf(fmaf(sb.z, b2f(yv.w),       hb.z), 0.f),
                        fmaxf(fmaf(sb.w, b2f(yv.w >> 16), hb.w), 0.f));
      uint4 uu = make_uint4(r0, r1, r2, r3);
      xv[kk][pm] = *(bfrag*)&uu;
    }
  }

  f32x4 acc[4][2];
  #pragma unroll
  for (int m = 0; m < 4; ++m)
    #pragma unroll
    for (int j = 0; j < 4; ++j) {
      float v = bl[m*16 + g*4 + j];
      acc[m][0][j] = v; acc[m][1][j] = v;
    }
  #pragma unroll
  for (int kk = 0; kk < 2; ++kk) {
    const int kc = kk*4 + g;
    bfrag a[4];
    #pragma unroll
    for (int m = 0; m < 4; ++m) { uint4 u = Wl[kc*64 + m*16 + fr]; a[m] = *(bfrag*)&u; }
    #pragma unroll
    for (int m = 0; m < 4; ++m)
      #pragma unroll
      for (int pm = 0; pm < 2; ++pm)
        acc[m][pm] = __builtin_amdgcn_mfma_f32_16x16x32_bf16(a[m], xv[kk][pm], acc[m][pm], 0, 0, 0);
  }

  #pragma unroll
  for (int m = 0; m < 4; ++m) {
    #pragma unroll
    for (int j = 0; j < 4; ++j) {
      float v0 = acc[m][0][j], v1 = acc[m][1][j];
      float s = v0 + v1, s2 = v0*v0 + v1*v1;
      #pragma unroll
      for (int d = 1; d < 16; d <<= 1) { s += __shfl_xor(s, d); s2 += __shfl_xor(s2, d); }
      if (fr == 0) {
        atomicAdd(&ssum[m*16 + g*4 + j], s);
        atomicAdd(&ssq[m*16 + g*4 + j], s2);
      }
    }
    #pragma unroll
    for (int pm = 0; pm < 2; ++pm) {
      uint2 vv;
      vv.x = pk2(acc[m][pm][0], acc[m][pm][1]);
      vv.y = pk2(acc[m][pm][2], acc[m][pm][3]);
      size_t unit = (size_t)(m*2 + (g>>1)) * P_ + pbase + w*32 + pm*16 + fr;
      *(uint2*)((char*)Y1g + unit*16 + (g&1)*8) = vv;
    }
  }
  __syncthreads();
  if (tid < 64) { atomicAdd(&sumg[tid], ssum[tid]); atomicAdd(&sqg[tid], ssq[tid]); }
}

// ---------------------------------------------------------------------------
// l2 (swapped operands): A = X (points as rows), B = W -> D[point][chan].
// Direct global->register X with fused BN/ReLU; in-register pool + 2 shuffles.
// ---------------------------------------------------------------------------
__global__ __launch_bounds__(256) void l2_mfma(
    const uint4* __restrict__ Y1g,
    const float* __restrict__ W2, const float* __restrict__ b2,
    const float* __restrict__ sc1, const float* __restrict__ sh1,
    float* __restrict__ mxg, float* __restrict__ mng,
    float* __restrict__ sumg, float* __restrict__ sqg)
{
  __shared__ uint4 Wl[8*128];      // 16 KB
  __shared__ float scl[64], shl[64], bl[128];
  __shared__ float ssum[128], ssq[128];

  const int tid = threadIdx.x;
  const int pbase = blockIdx.x * 128;
  const int q0 = blockIdx.x * 4;

  if (tid < 64) { scl[tid] = sc1[tid]; shl[tid] = sh1[tid]; }
  if (tid < 128) { bl[tid] = b2 ? b2[tid] : 0.f; ssum[tid] = 0.f; ssq[tid] = 0.f; }
  for (int u = tid; u < 8*128; u += 256) {
    int kc = u >> 7, o = u & 127;
    const float* wp = W2 + o*64 + kc*8;
    float4 wa = *(const float4*)wp;
    float4 wb = *(const float4*)(wp + 4);
    Wl[u] = make_uint4(pk2(wa.x, wa.y), pk2(wa.z, wa.w), pk2(wb.x, wb.y), pk2(wb.z, wb.w));
  }
  __syncthreads();

  const int lane = tid & 63, w = tid >> 6, g = lane >> 4, fr = lane & 15;

  bfrag ax[2][2];
  #pragma unroll
  for (int kk = 0; kk < 2; ++kk) {
    const int kc = kk*4 + g;
    float4 sa = *(const float4*)&scl[kc*8];
    float4 sb = *(const float4*)&scl[kc*8 + 4];
    float4 ha = *(const float4*)&shl[kc*8];
    float4 hb = *(const float4*)&shl[kc*8 + 4];
    #pragma unroll
    for (int pm = 0; pm < 2; ++pm) {
      uint4 yv = Y1g[(size_t)kc * P_ + pbase + w*32 + pm*16 + fr];
      unsigned r0 = pk2(fmaxf(fmaf(sa.x, b2f(yv.x),       ha.x), 0.f),
                        fmaxf(fmaf(sa.y, b2f(yv.x >> 16), ha.y), 0.f));
      unsigned r1 = pk2(fmaxf(fmaf(sa.z, b2f(yv.y),       ha.z), 0.f),
                        fmaxf(fmaf(sa.w, b2f(yv.y >> 16), ha.w), 0.f));
      unsigned r2 = pk2(fmaxf(fmaf(sb.x, b2f(yv.z),       hb.x), 0.f),
                        fmaxf(fmaf(sb.y, b2f(yv.z >> 16), hb.y), 0.f));
      unsigned r3 = pk2(fmaxf(fmaf(sb.z, b2f(yv.w),       hb.z), 0.f),
                        fmaxf(fmaf(sb.w, b2f(yv.w >> 16), hb.w), 0.f));
      uint4 uu = make_uint4(r0, r1, r2, r3);
      ax[kk][pm] = *(bfrag*)&uu;
    }
  }

  f32x4 acc[2][8];
  #pragma unroll
  for (int cn = 0; cn < 8; ++cn) {
    float v = bl[cn*16 + fr];
    #pragma unroll
    for (int j = 0; j < 4; ++j) { acc[0][cn][j] = v; acc[1][cn][j] = v; }
  }
  #pragma unroll
  for (int kk = 0; kk < 2; ++kk) {
    const int kc = kk*4 + g;
    #pragma unroll
    for (int cn = 0; cn < 8; ++cn) {
      uint4 u = Wl[kc*128 + cn*16 + fr];
      bfrag bw = *(bfrag*)&u;
      acc[0][cn] = __builtin_amdgcn_mfma_f32_16x16x32_bf16(ax[kk][0], bw, acc[0][cn], 0, 0, 0);
      acc[1][cn] = __builtin_amdgcn_mfma_f32_16x16x32_bf16(ax[kk][1], bw, acc[1][cn], 0, 0, 0);
    }
  }

  #pragma unroll
  for (int cn = 0; cn < 8; ++cn) {
    float mx = -3.0e38f, mn = 3.0e38f, s = 0.f, s2 = 0.f;
    #pragma unroll
    for (int pm = 0; pm < 2; ++pm)
      #pragma unroll
      for (int j = 0; j < 4; ++j) {
        float v = acc[pm][cn][j];
        mx = fmaxf(mx, v); mn = fminf(mn, v);
        s += v; s2 += v*v;
      }
    #pragma unroll
    for (int d = 16; d < 64; d <<= 1) {
      mx = fmaxf(mx, __shfl_xor(mx, d));
      mn = fminf(mn, __shfl_xor(mn, d));
      s  += __shfl_xor(s, d);
      s2 += __shfl_xor(s2, d);
    }
    if (g == 0) {
      int o = cn*16 + fr;
      size_t q = q0 + w;
      mxg[q*128 + o] = mx;
      mng[q*128 + o] = mn;
      atomicAdd(&ssum[o], s);
      atomicAdd(&ssq[o], s2);
    }
  }
  __syncthreads();
  if (tid < 128) { atomicAdd(&sumg[tid], ssum[tid]); atomicAdd(&sqg[tid], ssq[tid]); }
}

// ---------------------------------------------------------------------------
// BN finalize: raw (sum, sumsq) -> (scale, shift) per channel.
// ---------------------------------------------------------------------------
__global__ void finalize_kernel(
    const float* __restrict__ sum, const float* __restrict__ sq,
    const float* __restrict__ g, const float* __restrict__ bt,
    float* __restrict__ sc, float* __restrict__ sh, int C)
{
  int c = threadIdx.x;
  if (c < C) {
    const float inv = 1.0f / (float)P_;
    float mu = sum[c] * inv;
    float var = sq[c] * inv - mu * mu;
    var = fmaxf(var, 0.f);
    float r = 1.0f / sqrtf(var + EPS_);
    float gg = g ? g[c] : 1.0f;
    float bb = bt ? bt[c] : 0.0f;
    float s = gg * r;
    sc[c] = s;
    sh[c] = bb - mu * s;
  }
}

// ---------------------------------------------------------------------------
// Epilogue: BN2 + ReLU + maxpool (affine commutes with max; min covers
// negative scale), write f32 features.
// ---------------------------------------------------------------------------
__global__ __launch_bounds__(256) void out_kernel(
    const float* __restrict__ mxg, const float* __restrict__ mng,
    const float* __restrict__ sc2, const float* __restrict__ sh2,
    float* __restrict__ out)
{
  int i = blockIdx.x * 256 + threadIdx.x;
  int o = i & 127;
  float a = sc2[o];
  float v = (a >= 0.f) ? mxg[i] : mng[i];
  float z = fmaxf(fmaf(a, v, sh2[o]), 0.f);
  out[(size_t)PQ_ * 3 + i] = z;
}

// ---------------------------------------------------------------------------
extern "C" void kernel_launch(void* const* d_in, const int* in_sizes, int n_in,
                              void* d_out, int out_size, void* d_ws, size_t ws_size,
                              hipStream_t stream)
{
  int i_xyz=-1, i_feat=-1, i_fps=-1, i_w0=-1, i_w1=-1, i_w2=-1;
  for (int i = 0; i < n_in; ++i) {
    switch (in_sizes[i]) {
      case 196608:  i_xyz = i; break;
      case 4194304: i_feat = i; break;
      case 16384:   i_fps = i; break;
      case 4288:    i_w0 = i; break;
      case 4096:    i_w1 = i; break;
      case 8192:    i_w2 = i; break;
      default: break;
    }
  }
  if (i_xyz < 0 || i_feat < 0 || i_fps < 0 || i_w0 < 0 || i_w1 < 0 || i_w2 < 0) return;

  const float* xyz  = (const float*)d_in[i_xyz];
  const float* feat = (const float*)d_in[i_feat];
  const int*   fpsr = (const int*)d_in[i_fps];
  const float* W0 = (const float*)d_in[i_w0];
  const float* W1 = (const float*)d_in[i_w1];
  const float* W2 = (const float*)d_in[i_w2];

  bool canon = (n_in >= 15 && i_xyz==0 && i_feat==1 && i_fps==2 && i_w0==3 &&
                i_w1==7 && i_w2==11 &&
                in_sizes[4]==64 && in_sizes[5]==64 && in_sizes[6]==64 &&
                in_sizes[8]==64 && in_sizes[9]==64 && in_sizes[10]==64 &&
                in_sizes[12]==128 && in_sizes[13]==128 && in_sizes[14]==128);
  const float* b0 = canon ? (const float*)d_in[4]  : nullptr;
  const float* g0 = canon ? (const float*)d_in[5]  : nullptr;
  const float* bt0= canon ? (const float*)d_in[6]  : nullptr;
  const float* b1 = canon ? (const float*)d_in[8]  : nullptr;
  const float* g1 = canon ? (const float*)d_in[9]  : nullptr;
  const float* bt1= canon ? (const float*)d_in[10] : nullptr;
  const float* b2 = canon ? (const float*)d_in[12] : nullptr;
  const float* g2 = canon ? (const float*)d_in[13] : nullptr;
  const float* bt2= canon ? (const float*)d_in[14] : nullptr;

  float* out = (float*)d_out;
  char* ws = (char*)d_ws;
  if (ws_size < WS_NEEDED) return;

  int* idxw = (int*)(ws + OFF_IDX);
  uint4* Y0 = (uint4*)(ws + OFF_Y0);
  uint4* Y1 = (uint4*)(ws + OFF_Y1);
  float* mxg = (float*)(ws + OFF_MX);
  float* mng = (float*)(ws + OFF_MN);
  float* st  = (float*)(ws + OFF_STATS);
  float* fin = (float*)(ws + OFF_FIN);
  int* fpsc  = (int*)(ws + OFF_FPSC);

  hipMemsetAsync(st, 0, 2048, stream);

  fps_canon_kernel<<<(PQ_+255)/256, 256, 0, stream>>>(fpsr, fpsc);

  knn_kernel<<<PQ_, 256, 0, stream>>>(xyz, fpsc, idxw, out);

  l0_mfma<<<P_/128, 256, 0, stream>>>(xyz, feat, fpsc, idxw, W0, b0, Y0, st + 0, st + 64);
  finalize_kernel<<<1, 64, 0, stream>>>(st + 0, st + 64, g0, bt0, fin + 0, fin + 64, 64);

  l1_mfma<<<P_/128, 256, 0, stream>>>(Y0, W1, b1, fin + 0, fin + 64, Y1, st + 128, st + 192);
  finalize_kernel<<<1, 64, 0, stream>>>(st + 128, st + 192, g1, bt1, fin + 128, fin + 192, 64);

  l2_mfma<<<P_/128, 256, 0, stream>>>(Y1, W2, b2, fin + 128, fin + 192, mxg, mng, st + 256, st + 384);
  finalize_kernel<<<1, 128, 0, stream>>>(st + 256, st + 384, g2, bt2, fin + 256, fin + 384, 128);

  out_kernel<<<(PQ_*128)/256, 256, 0, stream>>>(mxg, mng, fin + 256, fin + 384, out);
}

// Round 10
// 251.178 us; speedup vs baseline: 3.5158x; 1.8247x over previous
//
#include <hip/hip_runtime.h>
#include <stdint.h>

// Problem constants
#define B_   16
#define N_   4096
#define S_   1024
#define K_   32
#define CIN_ 64
#define P_   524288      // B*S*K points through the MLP
#define PQ_  16384       // B*S queries
#define EPS_ 1e-5f

// Workspace layout (bytes)
#define SZ_IDX    ((size_t)P_ * 4)            // knn indices, int32
#define SZ_Y      ((size_t)P_ * 64 * 2)       // 64ch x P bf16 (subtiled units)
#define SZ_MX     ((size_t)PQ_ * 128 * 4)     // per-(q,ch) f32
#define OFF_IDX   ((size_t)0)
#define OFF_Y0    (OFF_IDX + SZ_IDX)
#define OFF_Y1    (OFF_Y0 + SZ_Y)
#define OFF_MX    (OFF_Y1 + SZ_Y)
#define OFF_MN    (OFF_MX + SZ_MX)
#define OFF_STATS (OFF_MN + SZ_MX)            // 8 replicas x 512 f32 (16 KB, zeroed)
#define OFF_FIN   (OFF_STATS + 16384)         // 512 f32 finalized scale/shift
#define OFF_FPSC  (OFF_FIN + 2048)            // canonical fps, 16384 int32
#define WS_NEEDED (OFF_FPSC + (size_t)PQ_ * 4)

typedef unsigned short u16;
typedef short bfrag __attribute__((ext_vector_type(8)));   // 8 bf16 (4 VGPRs)
typedef float f32x4 __attribute__((ext_vector_type(4)));

__device__ __forceinline__ float b2f(unsigned v) {
  return __uint_as_float((v & 0xffffu) << 16);
}
__device__ __forceinline__ u16 f2b(float f) {
  unsigned u = __float_as_uint(f);
  unsigned r = (u + 0x7fffu + ((u >> 16) & 1u)) >> 16;  // RNE
  return (u16)r;
}
__device__ __forceinline__ unsigned pk2(float a, float b) {
  return (unsigned)f2b(a) | ((unsigned)f2b(b) << 16);
}

// ---------------------------------------------------------------------------
// fps canonicalization (int64 vs int32 storage) -> int32, clamped.
// ---------------------------------------------------------------------------
__global__ __launch_bounds__(256) void fps_canon_kernel(
    const int* __restrict__ fpsraw, int* __restrict__ fpsc)
{
  __shared__ int is64;
  const int tid = threadIdx.x;
  if (tid == 0) is64 = 1;
  __syncthreads();
  if (tid < 64) {
    if (fpsraw[2 * tid + 1] != 0) atomicAnd(&is64, 0);
  }
  __syncthreads();
  int i = blockIdx.x * 256 + tid;
  if (i < PQ_) {
    int src = is64 ? (2 * i) : i;
    int v = fpsraw[src];
    fpsc[i] = (v & 0xFFF);
  }
}

// ---------------------------------------------------------------------------
// KNN v4: exact 32 smallest (d, idx) via histogram radix-select.
// Register distance cache; ballot compaction; wave-0 refine.
// Distance arithmetic mirrors the reference bit-for-bit (no FMA contraction).
// ---------------------------------------------------------------------------
#define NBIN 2048
#define CAND_CAP 512

__global__ __launch_bounds__(256) void knn_kernel(
    const float* __restrict__ xyz, const int* __restrict__ fps,
    int* __restrict__ idxout, float* __restrict__ out_xyz)
{
  __shared__ unsigned hist[NBIN];      // 8 KB
  __shared__ float cd[CAND_CAP];       // 2 KB
  __shared__ int   ci_[CAND_CAP];      // 2 KB
  __shared__ int   sel[K_];
  __shared__ int   wtot[4];
  __shared__ int   sCnt, sCand, sT;

  const int q   = blockIdx.x;
  const int b   = q >> 10;
  const int tid = threadIdx.x;
  const float* xb = xyz + (size_t)b * N_ * 3;
  const int ctr = fps[q];
  const float cx = xb[ctr*3+0], cy = xb[ctr*3+1], cz = xb[ctr*3+2];

  if (tid == 0) {
    out_xyz[(size_t)q*3+0] = cx;
    out_xyz[(size_t)q*3+1] = cy;
    out_xyz[(size_t)q*3+2] = cz;
    sCnt = 0; sCand = 0;
  }
  for (int i = tid; i < NBIN; i += 256) hist[i] = 0u;
  const float s1 = __fadd_rn(__fadd_rn(__fmul_rn(cx,cx), __fmul_rn(cy,cy)), __fmul_rn(cz,cz));
  __syncthreads();

  float dreg[16];
  #pragma unroll
  for (int it = 0; it < 16; ++it) {
    int n = it * 256 + tid;
    float x0 = xb[n*3+0], x1 = xb[n*3+1], x2 = xb[n*3+2];
    float s2 = __fadd_rn(__fadd_rn(__fmul_rn(x0,x0), __fmul_rn(x1,x1)), __fmul_rn(x2,x2));
    float dt = __fadd_rn(__fadd_rn(__fmul_rn(cx,x0), __fmul_rn(cy,x1)), __fmul_rn(cz,x2));
    float d  = __fsub_rn(__fadd_rn(s1, s2), __fmul_rn(2.0f, dt));
    dreg[it] = d;
    float dc = fmaxf(d, 0.0f);
    int bin = (int)(dc * 128.0f); bin = bin > (NBIN-1) ? (NBIN-1) : bin;
    atomicAdd(&hist[bin], 1u);
  }
  __syncthreads();

  const int base = tid * 8;
  int h[8]; int lsum = 0;
  #pragma unroll
  for (int j = 0; j < 8; ++j) { h[j] = (int)hist[base + j]; lsum += h[j]; }
  const int lane = tid & 63, wid = tid >> 6;
  int scv = lsum;
  #pragma unroll
  for (int off = 1; off < 64; off <<= 1) {
    int v = __shfl_up(scv, off, 64);
    if (lane >= off) scv += v;
  }
  if (lane == 63) wtot[wid] = scv;
  __syncthreads();
  int woff = 0;
  for (int w = 0; w < wid; ++w) woff += wtot[w];
  int run = woff + scv - lsum;
  #pragma unroll
  for (int j = 0; j < 8; ++j) {
    int c = h[j];
    if (run < K_ && run + c >= K_) { sT = base + j; }
    run += c;
  }
  __syncthreads();
  const int T = sT;

  const unsigned long long lmask = (lane == 63) ? 0x7fffffffffffffffull
                                                : ((1ull << lane) - 1ull);
  #pragma unroll
  for (int it = 0; it < 16; ++it) {
    int n = it * 256 + tid;
    float d = dreg[it];
    float dc = fmaxf(d, 0.0f);
    int bin = (int)(dc * 128.0f); bin = bin > (NBIN-1) ? (NBIN-1) : bin;
    bool isSel  = (bin < T);
    bool isCand = (bin == T);
    unsigned long long mSel  = __ballot(isSel);
    unsigned long long mCand = __ballot(isCand);
    int baseS = 0, baseC = 0;
    if (lane == 0) {
      if (mSel)  baseS = atomicAdd(&sCnt,  __popcll(mSel));
      if (mCand) baseC = atomicAdd(&sCand, __popcll(mCand));
    }
    baseS = __shfl(baseS, 0, 64);
    baseC = __shfl(baseC, 0, 64);
    if (isSel) {
      int s = baseS + __popcll(mSel & lmask);
      if (s < K_) sel[s] = n;
    }
    if (isCand) {
      int s = baseC + __popcll(mCand & lmask);
      if (s < CAND_CAP) { cd[s] = d; ci_[s] = n; }
    }
  }
  __syncthreads();

  if (wid == 0) {
    int m = sCnt; m = m > K_ ? K_ : m;
    int cc = sCand; cc = cc > CAND_CAP ? CAND_CAP : cc;
    const int r = K_ - m;
    for (int it = 0; it < r; ++it) {
      float bd = 3.0e38f; int bi = 0x7fffffff;
      for (int j = lane; j < cc; j += 64) {
        float dv = cd[j]; int iv = ci_[j];
        if (dv < bd || (dv == bd && iv < bi)) { bd = dv; bi = iv; }
      }
      #pragma unroll
      for (int off = 32; off > 0; off >>= 1) {
        float od = __shfl_down(bd, off, 64);
        int   oi = __shfl_down(bi, off, 64);
        if (od < bd || (od == bd && oi < bi)) { bd = od; bi = oi; }
      }
      int win = __shfl(bi, 0, 64);
      if (lane == 0) sel[m + it] = win & 0xFFF;
      for (int j = lane; j < cc; j += 64) if (ci_[j] == win) cd[j] = 3.0e38f;
    }
  }
  __syncthreads();
  if (tid < K_) idxout[(size_t)q * K_ + tid] = sel[tid] & 0xFFF;
}

// ===========================================================================
// MFMA MLP layers. Fragment mapping (verified m89/m91, gfx950 16x16x32 bf16):
//   A(M=16,K=32): lane holds A[row=lane&15][k=(lane>>4)*8+i]
//   B(K=32,N=16): lane holds B[k=(lane>>4)*8+i][col=lane&15]
//   D(M=16,N=16): lane holds D[row=(lane>>4)*4+j][col=lane&15]
// Y stores: the two 8B halves of one 16B unit live in partner lanes (g, g^1);
// a shfl_xor(16) pairs them so even-g lanes emit full 16B stores (clean
// write-granule coverage). Stats: 8 per-XCD replica regions (stride 512 f32)
// to de-hotspot the global atomic tails; finalize sums replicas.
// ===========================================================================

// ---------------------------------------------------------------------------
// l0 v3: direct per-lane gather, XCD-chunked swizzle, paired 16B stores.
// ---------------------------------------------------------------------------
__global__ __launch_bounds__(256) void l0_mfma(
    const float* __restrict__ xyz, const float* __restrict__ feat,
    const int* __restrict__ fps, const int* __restrict__ idxin,
    const float* __restrict__ W0, const float* __restrict__ b0,
    uint4* __restrict__ Y0g, float* __restrict__ sumg, float* __restrict__ sqg)
{
  __shared__ uint4 Wl[12*64];      // 12 KB
  __shared__ float bl[64];
  __shared__ float ssum[64], ssq[64];

  const int tid = threadIdx.x;
  const int bid0 = blockIdx.x;
  const int rep = (bid0 & 7) << 9;             // per-XCD stats replica offset
  const int bid = (bid0 & 7) * ((int)gridDim.x >> 3) + (bid0 >> 3);
  const int pbase = bid * 128;
  const int q0 = bid * 4;
  const int b = bid >> 8;

  if (tid < 64) { bl[tid] = b0 ? b0[tid] : 0.f; ssum[tid] = 0.f; ssq[tid] = 0.f; }
  for (int u = tid; u < 12*64; u += 256) {
    int kc = u >> 6, o = u & 63;
    unsigned pk[4];
    #pragma unroll
    for (int hh = 0; hh < 4; ++hh) {
      int c0 = kc*8 + hh*2, c1 = c0 + 1;
      float v0 = (c0 < 64) ? W0[o*67 + 3 + c0] : (c0 < 67 ? W0[o*67 + (c0-64)] : 0.f);
      float v1 = (c1 < 64) ? W0[o*67 + 3 + c1] : (c1 < 67 ? W0[o*67 + (c1-64)] : 0.f);
      pk[hh] = pk2(v0, v1);
    }
    Wl[u] = make_uint4(pk[0], pk[1], pk[2], pk[3]);
  }

  const int lane = tid & 63, w = tid >> 6, g = lane >> 4, fr = lane & 15;
  const float* xb = xyz + (size_t)b * N_ * 3;
  const float* fbase = feat + (size_t)b * N_ * 64;

  int pidx[2];
  const int ct = fps[q0 + w] & 0xFFF;
  #pragma unroll
  for (int pm = 0; pm < 2; ++pm)
    pidx[pm] = idxin[pbase + w*32 + pm*16 + fr] & 0xFFF;

  bfrag xv[3][2];
  #pragma unroll
  for (int kk = 0; kk < 3; ++kk) {
    const int kc = kk*4 + g;
    #pragma unroll
    for (int pm = 0; pm < 2; ++pm) {
      uint4 uu;
      if (kc < 8) {
        const float* fp = fbase + pidx[pm]*64 + kc*8;
        float4 fa = *(const float4*)fp;
        float4 fb2 = *(const float4*)(fp + 4);
        uu = make_uint4(pk2(fa.x, fa.y), pk2(fa.z, fa.w),
                        pk2(fb2.x, fb2.y), pk2(fb2.z, fb2.w));
      } else if (kc == 8) {
        int n = pidx[pm];
        float dx = xb[n*3+0] - xb[ct*3+0];
        float dy = xb[n*3+1] - xb[ct*3+1];
        float dz = xb[n*3+2] - xb[ct*3+2];
        uu = make_uint4(pk2(dx, dy), (unsigned)f2b(dz), 0u, 0u);
      } else {
        uu = make_uint4(0u, 0u, 0u, 0u);
      }
      xv[kk][pm] = *(bfrag*)&uu;
    }
  }
  __syncthreads();

  f32x4 acc[4][2];
  #pragma unroll
  for (int m = 0; m < 4; ++m)
    #pragma unroll
    for (int j = 0; j < 4; ++j) {
      float v = bl[m*16 + g*4 + j];
      acc[m][0][j] = v; acc[m][1][j] = v;
    }
  #pragma unroll
  for (int kk = 0; kk < 3; ++kk) {
    const int kc = kk*4 + g;
    bfrag a[4];
    #pragma unroll
    for (int m = 0; m < 4; ++m) { uint4 u = Wl[kc*64 + m*16 + fr]; a[m] = *(bfrag*)&u; }
    #pragma unroll
    for (int m = 0; m < 4; ++m)
      #pragma unroll
      for (int pm = 0; pm < 2; ++pm)
        acc[m][pm] = __builtin_amdgcn_mfma_f32_16x16x32_bf16(a[m], xv[kk][pm], acc[m][pm], 0, 0, 0);
  }

  #pragma unroll
  for (int m = 0; m < 4; ++m) {
    #pragma unroll
    for (int j = 0; j < 4; ++j) {
      float v0 = acc[m][0][j], v1 = acc[m][1][j];
      float s = v0 + v1, s2 = v0*v0 + v1*v1;
      #pragma unroll
      for (int d = 1; d < 16; d <<= 1) { s += __shfl_xor(s, d); s2 += __shfl_xor(s2, d); }
      if (fr == 0) {
        atomicAdd(&ssum[m*16 + g*4 + j], s);
        atomicAdd(&ssq[m*16 + g*4 + j], s2);
      }
    }
    #pragma unroll
    for (int pm = 0; pm < 2; ++pm) {
      unsigned lo = pk2(acc[m][pm][0], acc[m][pm][1]);
      unsigned hi = pk2(acc[m][pm][2], acc[m][pm][3]);
      unsigned plo = (unsigned)__shfl_xor((int)lo, 16, 64);
      unsigned phi = (unsigned)__shfl_xor((int)hi, 16, 64);
      if ((g & 1) == 0) {
        size_t unit = (size_t)(m*2 + (g>>1)) * P_ + pbase + w*32 + pm*16 + fr;
        Y0g[unit] = make_uint4(lo, hi, plo, phi);
      }
    }
  }
  __syncthreads();
  if (tid < 64) { atomicAdd(&sumg[rep + tid], ssum[tid]); atomicAdd(&sqg[rep + tid], ssq[tid]); }
}

// ---------------------------------------------------------------------------
// l1 v3: direct Y0 unit load + fused BN/ReLU; paired 16B stores; swizzled.
// ---------------------------------------------------------------------------
__global__ __launch_bounds__(256) void l1_mfma(
    const uint4* __restrict__ Y0g,
    const float* __restrict__ W1, const float* __restrict__ b1,
    const float* __restrict__ sc0, const float* __restrict__ sh0,
    uint4* __restrict__ Y1g, float* __restrict__ sumg, float* __restrict__ sqg)
{
  __shared__ uint4 Wl[8*64];       // 8 KB
  __shared__ float scl[64], shl[64], bl[64];
  __shared__ float ssum[64], ssq[64];

  const int tid = threadIdx.x;
  const int bid0 = blockIdx.x;
  const int rep = (bid0 & 7) << 9;
  const int bid = (bid0 & 7) * ((int)gridDim.x >> 3) + (bid0 >> 3);
  const int pbase = bid * 128;

  if (tid < 64) {
    scl[tid] = sc0[tid]; shl[tid] = sh0[tid];
    bl[tid] = b1 ? b1[tid] : 0.f;
    ssum[tid] = 0.f; ssq[tid] = 0.f;
  }
  for (int u = tid; u < 8*64; u += 256) {
    int kc = u >> 6, o = u & 63;
    const float* wp = W1 + o*64 + kc*8;
    float4 wa = *(const float4*)wp;
    float4 wb = *(const float4*)(wp + 4);
    Wl[u] = make_uint4(pk2(wa.x, wa.y), pk2(wa.z, wa.w), pk2(wb.x, wb.y), pk2(wb.z, wb.w));
  }
  __syncthreads();

  const int lane = tid & 63, w = tid >> 6, g = lane >> 4, fr = lane & 15;

  bfrag xv[2][2];
  #pragma unroll
  for (int kk = 0; kk < 2; ++kk) {
    const int kc = kk*4 + g;
    float4 sa = *(const float4*)&scl[kc*8];
    float4 sb = *(const float4*)&scl[kc*8 + 4];
    float4 ha = *(const float4*)&shl[kc*8];
    float4 hb = *(const float4*)&shl[kc*8 + 4];
    #pragma unroll
    for (int pm = 0; pm < 2; ++pm) {
      uint4 yv = Y0g[(size_t)kc * P_ + pbase + w*32 + pm*16 + fr];
      unsigned r0 = pk2(fmaxf(fmaf(sa.x, b2f(yv.x),       ha.x), 0.f),
                        fmaxf(fmaf(sa.y, b2f(yv.x >> 16), ha.y), 0.f));
      unsigned r1 = pk2(fmaxf(fmaf(sa.z, b2f(yv.y),       ha.z), 0.f),
                        fmaxf(fmaf(sa.w, b2f(yv.y >> 16), ha.w), 0.f));
      unsigned r2 = pk2(fmaxf(fmaf(sb.x, b2f(yv.z),       hb.x), 0.f),
                        fmaxf(fmaf(sb.y, b2f(yv.z >> 16), hb.y), 0.f));
      unsigned r3 = pk2(fmaxf(fmaf(sb.z, b2f(yv.w),       hb.z), 0.f),
                        fmaxf(fmaf(sb.w, b2f(yv.w >> 16), hb.w), 0.f));
      uint4 uu = make_uint4(r0, r1, r2, r3);
      xv[kk][pm] = *(bfrag*)&uu;
    }
  }

  f32x4 acc[4][2];
  #pragma unroll
  for (int m = 0; m < 4; ++m)
    #pragma unroll
    for (int j = 0; j < 4; ++j) {
      float v = bl[m*16 + g*4 + j];
      acc[m][0][j] = v; acc[m][1][j] = v;
    }
  #pragma unroll
  for (int kk = 0; kk < 2; ++kk) {
    const int kc = kk*4 + g;
    bfrag a[4];
    #pragma unroll
    for (int m = 0; m < 4; ++m) { uint4 u = Wl[kc*64 + m*16 + fr]; a[m] = *(bfrag*)&u; }
    #pragma unroll
    for (int m = 0; m < 4; ++m)
      #pragma unroll
      for (int pm = 0; pm < 2; ++pm)
        acc[m][pm] = __builtin_amdgcn_mfma_f32_16x16x32_bf16(a[m], xv[kk][pm], acc[m][pm], 0, 0, 0);
  }

  #pragma unroll
  for (int m = 0; m < 4; ++m) {
    #pragma unroll
    for (int j = 0; j < 4; ++j) {
      float v0 = acc[m][0][j], v1 = acc[m][1][j];
      float s = v0 + v1, s2 = v0*v0 + v1*v1;
      #pragma unroll
      for (int d = 1; d < 16; d <<= 1) { s += __shfl_xor(s, d); s2 += __shfl_xor(s2, d); }
      if (fr == 0) {
        atomicAdd(&ssum[m*16 + g*4 + j], s);
        atomicAdd(&ssq[m*16 + g*4 + j], s2);
      }
    }
    #pragma unroll
    for (int pm = 0; pm < 2; ++pm) {
      unsigned lo = pk2(acc[m][pm][0], acc[m][pm][1]);
      unsigned hi = pk2(acc[m][pm][2], acc[m][pm][3]);
      unsigned plo = (unsigned)__shfl_xor((int)lo, 16, 64);
      unsigned phi = (unsigned)__shfl_xor((int)hi, 16, 64);
      if ((g & 1) == 0) {
        size_t unit = (size_t)(m*2 + (g>>1)) * P_ + pbase + w*32 + pm*16 + fr;
        Y1g[unit] = make_uint4(lo, hi, plo, phi);
      }
    }
  }
  __syncthreads();
  if (tid < 64) { atomicAdd(&sumg[rep + tid], ssum[tid]); atomicAdd(&sqg[rep + tid], ssq[tid]); }
}

// ---------------------------------------------------------------------------
// l2 (swapped operands): A = X (points as rows), B = W -> D[point][chan].
// Direct global->register X with fused BN/ReLU; in-register pool + 2 shuffles.
// Swizzled grid (align with l1's Y1 placement) + stats replicas.
// ---------------------------------------------------------------------------
__global__ __launch_bounds__(256) void l2_mfma(
    const uint4* __restrict__ Y1g,
    const float* __restrict__ W2, const float* __restrict__ b2,
    const float* __restrict__ sc1, const float* __restrict__ sh1,
    float* __restrict__ mxg, float* __restrict__ mng,
    float* __restrict__ sumg, float* __restrict__ sqg)
{
  __shared__ uint4 Wl[8*128];      // 16 KB
  __shared__ float scl[64], shl[64], bl[128];
  __shared__ float ssum[128], ssq[128];

  const int tid = threadIdx.x;
  const int bid0 = blockIdx.x;
  const int rep = (bid0 & 7) << 9;
  const int bid = (bid0 & 7) * ((int)gridDim.x >> 3) + (bid0 >> 3);
  const int pbase = bid * 128;
  const int q0 = bid * 4;

  if (tid < 64) { scl[tid] = sc1[tid]; shl[tid] = sh1[tid]; }
  if (tid < 128) { bl[tid] = b2 ? b2[tid] : 0.f; ssum[tid] = 0.f; ssq[tid] = 0.f; }
  for (int u = tid; u < 8*128; u += 256) {
    int kc = u >> 7, o = u & 127;
    const float* wp = W2 + o*64 + kc*8;
    float4 wa = *(const float4*)wp;
    float4 wb = *(const float4*)(wp + 4);
    Wl[u] = make_uint4(pk2(wa.x, wa.y), pk2(wa.z, wa.w), pk2(wb.x, wb.y), pk2(wb.z, wb.w));
  }
  __syncthreads();

  const int lane = tid & 63, w = tid >> 6, g = lane >> 4, fr = lane & 15;

  bfrag ax[2][2];
  #pragma unroll
  for (int kk = 0; kk < 2; ++kk) {
    const int kc = kk*4 + g;
    float4 sa = *(const float4*)&scl[kc*8];
    float4 sb = *(const float4*)&scl[kc*8 + 4];
    float4 ha = *(const float4*)&shl[kc*8];
    float4 hb = *(const float4*)&shl[kc*8 + 4];
    #pragma unroll
    for (int pm = 0; pm < 2; ++pm) {
      uint4 yv = Y1g[(size_t)kc * P_ + pbase + w*32 + pm*16 + fr];
      unsigned r0 = pk2(fmaxf(fmaf(sa.x, b2f(yv.x),       ha.x), 0.f),
                        fmaxf(fmaf(sa.y, b2f(yv.x >> 16), ha.y), 0.f));
      unsigned r1 = pk2(fmaxf(fmaf(sa.z, b2f(yv.y),       ha.z), 0.f),
                        fmaxf(fmaf(sa.w, b2f(yv.y >> 16), ha.w), 0.f));
      unsigned r2 = pk2(fmaxf(fmaf(sb.x, b2f(yv.z),       hb.x), 0.f),
                        fmaxf(fmaf(sb.y, b2f(yv.z >> 16), hb.y), 0.f));
      unsigned r3 = pk2(fmaxf(fmaf(sb.z, b2f(yv.w),       hb.z), 0.f),
                        fmaxf(fmaf(sb.w, b2f(yv.w >> 16), hb.w), 0.f));
      uint4 uu = make_uint4(r0, r1, r2, r3);
      ax[kk][pm] = *(bfrag*)&uu;
    }
  }

  f32x4 acc[2][8];
  #pragma unroll
  for (int cn = 0; cn < 8; ++cn) {
    float v = bl[cn*16 + fr];
    #pragma unroll
    for (int j = 0; j < 4; ++j) { acc[0][cn][j] = v; acc[1][cn][j] = v; }
  }
  #pragma unroll
  for (int kk = 0; kk < 2; ++kk) {
    const int kc = kk*4 + g;
    #pragma unroll
    for (int cn = 0; cn < 8; ++cn) {
      uint4 u = Wl[kc*128 + cn*16 + fr];
      bfrag bw = *(bfrag*)&u;
      acc[0][cn] = __builtin_amdgcn_mfma_f32_16x16x32_bf16(ax[kk][0], bw, acc[0][cn], 0, 0, 0);
      acc[1][cn] = __builtin_amdgcn_mfma_f32_16x16x32_bf16(ax[kk][1], bw, acc[1][cn], 0, 0, 0);
    }
  }

  #pragma unroll
  for (int cn = 0; cn < 8; ++cn) {
    float mx = -3.0e38f, mn = 3.0e38f, s = 0.f, s2 = 0.f;
    #pragma unroll
    for (int pm = 0; pm < 2; ++pm)
      #pragma unroll
      for (int j = 0; j < 4; ++j) {
        float v = acc[pm][cn][j];
        mx = fmaxf(mx, v); mn = fminf(mn, v);
        s += v; s2 += v*v;
      }
    #pragma unroll
    for (int d = 16; d < 64; d <<= 1) {
      mx = fmaxf(mx, __shfl_xor(mx, d));
      mn = fminf(mn, __shfl_xor(mn, d));
      s  += __shfl_xor(s, d);
      s2 += __shfl_xor(s2, d);
    }
    if (g == 0) {
      int o = cn*16 + fr;
      size_t q = q0 + w;
      mxg[q*128 + o] = mx;
      mng[q*128 + o] = mn;
      atomicAdd(&ssum[o], s);
      atomicAdd(&ssq[o], s2);
    }
  }
  __syncthreads();
  if (tid < 128) { atomicAdd(&sumg[rep + tid], ssum[tid]); atomicAdd(&sqg[rep + tid], ssq[tid]); }
}

// ---------------------------------------------------------------------------
// BN finalize: sum 8 per-XCD replicas of (sum, sumsq) -> (scale, shift).
// ---------------------------------------------------------------------------
__global__ void finalize_kernel(
    const float* __restrict__ sum, const float* __restrict__ sq,
    const float* __restrict__ g, const float* __restrict__ bt,
    float* __restrict__ sc, float* __restrict__ sh, int C)
{
  int c = threadIdx.x;
  if (c < C) {
    float s = 0.f, s2 = 0.f;
    #pragma unroll
    for (int r = 0; r < 8; ++r) { s += sum[r*512 + c]; s2 += sq[r*512 + c]; }
    const float inv = 1.0f / (float)P_;
    float mu = s * inv;
    float var = s2 * inv - mu * mu;
    var = fmaxf(var, 0.f);
    float rr = 1.0f / sqrtf(var + EPS_);
    float gg = g ? g[c] : 1.0f;
    float bb = bt ? bt[c] : 0.0f;
    float sv = gg * rr;
    sc[c] = sv;
    sh[c] = bb - mu * sv;
  }
}

// ---------------------------------------------------------------------------
// Epilogue: BN2 + ReLU + maxpool (affine commutes with max; min covers
// negative scale), write f32 features.
// ---------------------------------------------------------------------------
__global__ __launch_bounds__(256) void out_kernel(
    const float* __restrict__ mxg, const float* __restrict__ mng,
    const float* __restrict__ sc2, const float* __restrict__ sh2,
    float* __restrict__ out)
{
  int i = blockIdx.x * 256 + threadIdx.x;
  int o = i & 127;
  float a = sc2[o];
  float v = (a >= 0.f) ? mxg[i] : mng[i];
  float z = fmaxf(fmaf(a, v, sh2[o]), 0.f);
  out[(size_t)PQ_ * 3 + i] = z;
}

// ---------------------------------------------------------------------------
extern "C" void kernel_launch(void* const* d_in, const int* in_sizes, int n_in,
                              void* d_out, int out_size, void* d_ws, size_t ws_size,
                              hipStream_t stream)
{
  int i_xyz=-1, i_feat=-1, i_fps=-1, i_w0=-1, i_w1=-1, i_w2=-1;
  for (int i = 0; i < n_in; ++i) {
    switch (in_sizes[i]) {
      case 196608:  i_xyz = i; break;
      case 4194304: i_feat = i; break;
      case 16384:   i_fps = i; break;
      case 4288:    i_w0 = i; break;
      case 4096:    i_w1 = i; break;
      case 8192:    i_w2 = i; break;
      default: break;
    }
  }
  if (i_xyz < 0 || i_feat < 0 || i_fps < 0 || i_w0 < 0 || i_w1 < 0 || i_w2 < 0) return;

  const float* xyz  = (const float*)d_in[i_xyz];
  const float* feat = (const float*)d_in[i_feat];
  const int*   fpsr = (const int*)d_in[i_fps];
  const float* W0 = (const float*)d_in[i_w0];
  const float* W1 = (const float*)d_in[i_w1];
  const float* W2 = (const float*)d_in[i_w2];

  bool canon = (n_in >= 15 && i_xyz==0 && i_feat==1 && i_fps==2 && i_w0==3 &&
                i_w1==7 && i_w2==11 &&
                in_sizes[4]==64 && in_sizes[5]==64 && in_sizes[6]==64 &&
                in_sizes[8]==64 && in_sizes[9]==64 && in_sizes[10]==64 &&
                in_sizes[12]==128 && in_sizes[13]==128 && in_sizes[14]==128);
  const float* b0 = canon ? (const float*)d_in[4]  : nullptr;
  const float* g0 = canon ? (const float*)d_in[5]  : nullptr;
  const float* bt0= canon ? (const float*)d_in[6]  : nullptr;
  const float* b1 = canon ? (const float*)d_in[8]  : nullptr;
  const float* g1 = canon ? (const float*)d_in[9]  : nullptr;
  const float* bt1= canon ? (const float*)d_in[10] : nullptr;
  const float* b2 = canon ? (const float*)d_in[12] : nullptr;
  const float* g2 = canon ? (const float*)d_in[13] : nullptr;
  const float* bt2= canon ? (const float*)d_in[14] : nullptr;

  float* out = (float*)d_out;
  char* ws = (char*)d_ws;
  if (ws_size < WS_NEEDED) return;

  int* idxw = (int*)(ws + OFF_IDX);
  uint4* Y0 = (uint4*)(ws + OFF_Y0);
  uint4* Y1 = (uint4*)(ws + OFF_Y1);
  float* mxg = (float*)(ws + OFF_MX);
  float* mng = (float*)(ws + OFF_MN);
  float* st  = (float*)(ws + OFF_STATS);   // 8 replicas x 512 f32
  float* fin = (float*)(ws + OFF_FIN);
  int* fpsc  = (int*)(ws + OFF_FPSC);

  hipMemsetAsync(st, 0, 16384, stream);

  fps_canon_kernel<<<(PQ_+255)/256, 256, 0, stream>>>(fpsr, fpsc);

  knn_kernel<<<PQ_, 256, 0, stream>>>(xyz, fpsc, idxw, out);

  l0_mfma<<<P_/128, 256, 0, stream>>>(xyz, feat, fpsc, idxw, W0, b0, Y0, st + 0, st + 64);
  finalize_kernel<<<1, 64, 0, stream>>>(st + 0, st + 64, g0, bt0, fin + 0, fin + 64, 64);

  l1_mfma<<<P_/128, 256, 0, stream>>>(Y0, W1, b1, fin + 0, fin + 64, Y1, st + 128, st + 192);
  finalize_kernel<<<1, 64, 0, stream>>>(st + 128, st + 192, g1, bt1, fin + 128, fin + 192, 64);

  l2_mfma<<<P_/128, 256, 0, stream>>>(Y1, W2, b2, fin + 128, fin + 192, mxg, mng, st + 256, st + 384);
  finalize_kernel<<<1, 128, 0, stream>>>(st + 256, st + 384, g2, bt2, fin + 256, fin + 384, 128);

  out_kernel<<<(PQ_*128)/256, 256, 0, stream>>>(mxg, mng, fin + 256, fin + 384, out);
}

// Round 11
// 242.498 us; speedup vs baseline: 3.6416x; 1.0358x over previous
//
#include <hip/hip_runtime.h>
#include <stdint.h>

// Problem constants
#define B_   16
#define N_   4096
#define S_   1024
#define K_   32
#define CIN_ 64
#define P_   524288      // B*S*K points through the MLP
#define PQ_  16384       // B*S queries
#define EPS_ 1e-5f

// Workspace layout (bytes)
#define SZ_IDX    ((size_t)P_ * 4)            // knn indices, int32
#define SZ_Y      ((size_t)P_ * 64 * 2)       // 64ch x P bf16 (subtiled units)
#define SZ_MX     ((size_t)PQ_ * 128 * 4)     // per-(q,ch) f32
#define OFF_IDX   ((size_t)0)
#define OFF_Y0    (OFF_IDX + SZ_IDX)
#define OFF_Y1    (OFF_Y0 + SZ_Y)
#define OFF_MX    (OFF_Y1 + SZ_Y)
#define OFF_MN    (OFF_MX + SZ_MX)
#define OFF_STATS (OFF_MN + SZ_MX)            // 8 replicas x 512 f32 (16 KB, zeroed)
#define OFF_FIN   (OFF_STATS + 16384)         // 512 f32 finalized scale/shift
#define OFF_FPSC  (OFF_FIN + 2048)            // canonical fps, 16384 int32
#define OFF_PXYZW (OFF_FPSC + (size_t)PQ_ * 4)  // B*N float4 (x,y,z,|x|^2)
#define WS_NEEDED (OFF_PXYZW + (size_t)B_ * N_ * 16)

typedef unsigned short u16;
typedef short bfrag __attribute__((ext_vector_type(8)));   // 8 bf16 (4 VGPRs)
typedef float f32x4 __attribute__((ext_vector_type(4)));

__device__ __forceinline__ float b2f(unsigned v) {
  return __uint_as_float((v & 0xffffu) << 16);
}
__device__ __forceinline__ u16 f2b(float f) {
  unsigned u = __float_as_uint(f);
  unsigned r = (u + 0x7fffu + ((u >> 16) & 1u)) >> 16;  // RNE
  return (u16)r;
}
__device__ __forceinline__ unsigned pk2(float a, float b) {
  return (unsigned)f2b(a) | ((unsigned)f2b(b) << 16);
}

// ---------------------------------------------------------------------------
// fps canonicalization (int64 vs int32 storage) -> int32, clamped.
// ---------------------------------------------------------------------------
__global__ __launch_bounds__(256) void fps_canon_kernel(
    const int* __restrict__ fpsraw, int* __restrict__ fpsc)
{
  __shared__ int is64;
  const int tid = threadIdx.x;
  if (tid == 0) is64 = 1;
  __syncthreads();
  if (tid < 64) {
    if (fpsraw[2 * tid + 1] != 0) atomicAnd(&is64, 0);
  }
  __syncthreads();
  int i = blockIdx.x * 256 + tid;
  if (i < PQ_) {
    int src = is64 ? (2 * i) : i;
    int v = fpsraw[src];
    fpsc[i] = (v & 0xFFF);
  }
}

// ---------------------------------------------------------------------------
// prep: pack (x, y, z, |x|^2) per point. |x|^2 uses the EXACT reference
// op ordering ((x0*x0 + x1*x1) + x2*x2), f32, no FMA.
// ---------------------------------------------------------------------------
__global__ __launch_bounds__(256) void prep_kernel(
    const float* __restrict__ xyz, float4* __restrict__ pxyzw)
{
  int i = blockIdx.x * 256 + threadIdx.x;   // 0 .. B*N-1
  float x0 = xyz[i*3+0], x1 = xyz[i*3+1], x2 = xyz[i*3+2];
  float s2 = __fadd_rn(__fadd_rn(__fmul_rn(x0,x0), __fmul_rn(x1,x1)), __fmul_rn(x2,x2));
  pxyzw[i] = make_float4(x0, x1, x2, s2);
}

// ---------------------------------------------------------------------------
// KNN v5: exact 32 smallest (d, idx) via histogram radix-select.
// - float4 (x,y,z,|x|^2) input: coalesced dwordx4 loads, 6-op distances
// - register distance cache; wave-0 serial 64-bin-chunk scan for T
// - pass 2 float-threshold compares (bin<T <=> dc < T/128, exact)
// - ballot compaction, guarded on nonzero masks; wave-0 refine loop
// ---------------------------------------------------------------------------
#define NBIN 2048
#define CAND_CAP 512

__global__ __launch_bounds__(256) void knn_kernel(
    const float4* __restrict__ pxyzw, const int* __restrict__ fps,
    int* __restrict__ idxout, float* __restrict__ out_xyz)
{
  __shared__ unsigned hist[NBIN];      // 8 KB
  __shared__ float cd[CAND_CAP];       // 2 KB
  __shared__ int   ci_[CAND_CAP];      // 2 KB
  __shared__ int   sel[K_];
  __shared__ int   sCnt, sCand, sT;

  const int q   = blockIdx.x;
  const int b   = q >> 10;
  const int tid = threadIdx.x;
  const float4* xb4 = pxyzw + (size_t)b * N_;
  const int ctr = fps[q];
  const float4 cv = xb4[ctr];
  const float cx = cv.x, cy = cv.y, cz = cv.z, s1 = cv.w;

  if (tid == 0) {
    out_xyz[(size_t)q*3+0] = cx;
    out_xyz[(size_t)q*3+1] = cy;
    out_xyz[(size_t)q*3+2] = cz;
    sCnt = 0; sCand = 0;
  }
  {
    uint4* hz = (uint4*)hist;
    hz[tid]       = make_uint4(0,0,0,0);
    hz[tid + 256] = make_uint4(0,0,0,0);
  }
  __syncthreads();

  // pass 1: distances -> registers + histogram
  float dreg[16];
  #pragma unroll
  for (int it = 0; it < 16; ++it) {
    int n = it * 256 + tid;
    float4 v = xb4[n];
    float dt = __fadd_rn(__fadd_rn(__fmul_rn(cx,v.x), __fmul_rn(cy,v.y)), __fmul_rn(cz,v.z));
    float d  = __fsub_rn(__fadd_rn(s1, v.w), __fmul_rn(2.0f, dt));
    dreg[it] = d;
    float dc = fmaxf(d, 0.0f);
    int bin = (int)(dc * 128.0f); bin = bin > (NBIN-1) ? (NBIN-1) : bin;
    atomicAdd(&hist[bin], 1u);
  }
  __syncthreads();

  // scan: wave 0 walks 64 bins at a time until cumulative reaches K (T small)
  const int lane = tid & 63, wid = tid >> 6;
  if (wid == 0) {
    int cum = 0, base = 0, found = 0;
    while (!found && base < NBIN) {
      int h = (int)hist[base + lane];
      int pre = h;
      #pragma unroll
      for (int off = 1; off < 64; off <<= 1) {
        int v = __shfl_up(pre, off, 64);
        if (lane >= off) pre += v;
      }
      int tot = __shfl(pre, 63, 64);
      bool cross = (cum + pre >= K_) && (cum + pre - h < K_);
      unsigned long long mm = __ballot(cross);
      if (mm) {
        if (lane == 0) sT = base + (int)(__ffsll((long long)mm) - 1);
        found = 1;
      }
      cum += tot;
      base += 64;
    }
  }
  __syncthreads();
  const int T = sT;
  const float fT  = (float)T * 0.0078125f;                       // exact
  const float fT1 = (T >= NBIN-1) ? 3.0e38f : (float)(T+1) * 0.0078125f;

  // pass 2: cached d; float-threshold classify; ballot-compact
  const unsigned long long lmask = (lane == 63) ? 0x7fffffffffffffffull
                                                : ((1ull << lane) - 1ull);
  #pragma unroll
  for (int it = 0; it < 16; ++it) {
    int n = it * 256 + tid;
    float dc = fmaxf(dreg[it], 0.0f);
    bool isSel  = dc < fT;                   // <=> bin < T (exact)
    bool isCand = !isSel && (dc < fT1);      // <=> bin == T (exact)
    unsigned long long mSel  = __ballot(isSel);
    unsigned long long mCand = __ballot(isCand);
    if (mSel) {
      int baseS = 0;
      if (lane == 0) baseS = atomicAdd(&sCnt, __popcll(mSel));
      baseS = __shfl(baseS, 0, 64);
      if (isSel) {
        int s = baseS + __popcll(mSel & lmask);
        if (s < K_) sel[s] = n;
      }
    }
    if (mCand) {
      int baseC = 0;
      if (lane == 0) baseC = atomicAdd(&sCand, __popcll(mCand));
      baseC = __shfl(baseC, 0, 64);
      if (isCand) {
        int s = baseC + __popcll(mCand & lmask);
        if (s < CAND_CAP) { cd[s] = dreg[it]; ci_[s] = n; }
      }
    }
  }
  __syncthreads();

  // refine: wave 0 only (lane owns j == lane mod 64), (d, idx) tie-break
  if (wid == 0) {
    int m = sCnt; m = m > K_ ? K_ : m;
    int cc = sCand; cc = cc > CAND_CAP ? CAND_CAP : cc;
    const int r = K_ - m;
    for (int it = 0; it < r; ++it) {
      float bd = 3.0e38f; int bi = 0x7fffffff;
      for (int j = lane; j < cc; j += 64) {
        float dv = cd[j]; int iv = ci_[j];
        if (dv < bd || (dv == bd && iv < bi)) { bd = dv; bi = iv; }
      }
      #pragma unroll
      for (int off = 32; off > 0; off >>= 1) {
        float od = __shfl_down(bd, off, 64);
        int   oi = __shfl_down(bi, off, 64);
        if (od < bd || (od == bd && oi < bi)) { bd = od; bi = oi; }
      }
      int win = __shfl(bi, 0, 64);
      if (lane == 0) sel[m + it] = win & 0xFFF;
      for (int j = lane; j < cc; j += 64) if (ci_[j] == win) cd[j] = 3.0e38f;
    }
  }
  __syncthreads();
  if (tid < K_) idxout[(size_t)q * K_ + tid] = sel[tid] & 0xFFF;
}

// ===========================================================================
// MFMA MLP layers (unchanged from round 10). Fragment mapping (m89/m91):
//   A(M=16,K=32): lane holds A[row=lane&15][k=(lane>>4)*8+i]
//   B(K=32,N=16): lane holds B[k=(lane>>4)*8+i][col=lane&15]
//   D(M=16,N=16): lane holds D[row=(lane>>4)*4+j][col=lane&15]
// Paired 16B Y stores via shfl_xor(16); 8 per-XCD stats replicas.
// ===========================================================================

__global__ __launch_bounds__(256) void l0_mfma(
    const float* __restrict__ xyz, const float* __restrict__ feat,
    const int* __restrict__ fps, const int* __restrict__ idxin,
    const float* __restrict__ W0, const float* __restrict__ b0,
    uint4* __restrict__ Y0g, float* __restrict__ sumg, float* __restrict__ sqg)
{
  __shared__ uint4 Wl[12*64];      // 12 KB
  __shared__ float bl[64];
  __shared__ float ssum[64], ssq[64];

  const int tid = threadIdx.x;
  const int bid0 = blockIdx.x;
  const int rep = (bid0 & 7) << 9;
  const int bid = (bid0 & 7) * ((int)gridDim.x >> 3) + (bid0 >> 3);
  const int pbase = bid * 128;
  const int q0 = bid * 4;
  const int b = bid >> 8;

  if (tid < 64) { bl[tid] = b0 ? b0[tid] : 0.f; ssum[tid] = 0.f; ssq[tid] = 0.f; }
  for (int u = tid; u < 12*64; u += 256) {
    int kc = u >> 6, o = u & 63;
    unsigned pk[4];
    #pragma unroll
    for (int hh = 0; hh < 4; ++hh) {
      int c0 = kc*8 + hh*2, c1 = c0 + 1;
      float v0 = (c0 < 64) ? W0[o*67 + 3 + c0] : (c0 < 67 ? W0[o*67 + (c0-64)] : 0.f);
      float v1 = (c1 < 64) ? W0[o*67 + 3 + c1] : (c1 < 67 ? W0[o*67 + (c1-64)] : 0.f);
      pk[hh] = pk2(v0, v1);
    }
    Wl[u] = make_uint4(pk[0], pk[1], pk[2], pk[3]);
  }

  const int lane = tid & 63, w = tid >> 6, g = lane >> 4, fr = lane & 15;
  const float* xb = xyz + (size_t)b * N_ * 3;
  const float* fbase = feat + (size_t)b * N_ * 64;

  int pidx[2];
  const int ct = fps[q0 + w] & 0xFFF;
  #pragma unroll
  for (int pm = 0; pm < 2; ++pm)
    pidx[pm] = idxin[pbase + w*32 + pm*16 + fr] & 0xFFF;

  bfrag xv[3][2];
  #pragma unroll
  for (int kk = 0; kk < 3; ++kk) {
    const int kc = kk*4 + g;
    #pragma unroll
    for (int pm = 0; pm < 2; ++pm) {
      uint4 uu;
      if (kc < 8) {
        const float* fp = fbase + pidx[pm]*64 + kc*8;
        float4 fa = *(const float4*)fp;
        float4 fb2 = *(const float4*)(fp + 4);
        uu = make_uint4(pk2(fa.x, fa.y), pk2(fa.z, fa.w),
                        pk2(fb2.x, fb2.y), pk2(fb2.z, fb2.w));
      } else if (kc == 8) {
        int n = pidx[pm];
        float dx = xb[n*3+0] - xb[ct*3+0];
        float dy = xb[n*3+1] - xb[ct*3+1];
        float dz = xb[n*3+2] - xb[ct*3+2];
        uu = make_uint4(pk2(dx, dy), (unsigned)f2b(dz), 0u, 0u);
      } else {
        uu = make_uint4(0u, 0u, 0u, 0u);
      }
      xv[kk][pm] = *(bfrag*)&uu;
    }
  }
  __syncthreads();

  f32x4 acc[4][2];
  #pragma unroll
  for (int m = 0; m < 4; ++m)
    #pragma unroll
    for (int j = 0; j < 4; ++j) {
      float v = bl[m*16 + g*4 + j];
      acc[m][0][j] = v; acc[m][1][j] = v;
    }
  #pragma unroll
  for (int kk = 0; kk < 3; ++kk) {
    const int kc = kk*4 + g;
    bfrag a[4];
    #pragma unroll
    for (int m = 0; m < 4; ++m) { uint4 u = Wl[kc*64 + m*16 + fr]; a[m] = *(bfrag*)&u; }
    #pragma unroll
    for (int m = 0; m < 4; ++m)
      #pragma unroll
      for (int pm = 0; pm < 2; ++pm)
        acc[m][pm] = __builtin_amdgcn_mfma_f32_16x16x32_bf16(a[m], xv[kk][pm], acc[m][pm], 0, 0, 0);
  }

  #pragma unroll
  for (int m = 0; m < 4; ++m) {
    #pragma unroll
    for (int j = 0; j < 4; ++j) {
      float v0 = acc[m][0][j], v1 = acc[m][1][j];
      float s = v0 + v1, s2 = v0*v0 + v1*v1;
      #pragma unroll
      for (int d = 1; d < 16; d <<= 1) { s += __shfl_xor(s, d); s2 += __shfl_xor(s2, d); }
      if (fr == 0) {
        atomicAdd(&ssum[m*16 + g*4 + j], s);
        atomicAdd(&ssq[m*16 + g*4 + j], s2);
      }
    }
    #pragma unroll
    for (int pm = 0; pm < 2; ++pm) {
      unsigned lo = pk2(acc[m][pm][0], acc[m][pm][1]);
      unsigned hi = pk2(acc[m][pm][2], acc[m][pm][3]);
      unsigned plo = (unsigned)__shfl_xor((int)lo, 16, 64);
      unsigned phi = (unsigned)__shfl_xor((int)hi, 16, 64);
      if ((g & 1) == 0) {
        size_t unit = (size_t)(m*2 + (g>>1)) * P_ + pbase + w*32 + pm*16 + fr;
        Y0g[unit] = make_uint4(lo, hi, plo, phi);
      }
    }
  }
  __syncthreads();
  if (tid < 64) { atomicAdd(&sumg[rep + tid], ssum[tid]); atomicAdd(&sqg[rep + tid], ssq[tid]); }
}

__global__ __launch_bounds__(256) void l1_mfma(
    const uint4* __restrict__ Y0g,
    const float* __restrict__ W1, const float* __restrict__ b1,
    const float* __restrict__ sc0, const float* __restrict__ sh0,
    uint4* __restrict__ Y1g, float* __restrict__ sumg, float* __restrict__ sqg)
{
  __shared__ uint4 Wl[8*64];       // 8 KB
  __shared__ float scl[64], shl[64], bl[64];
  __shared__ float ssum[64], ssq[64];

  const int tid = threadIdx.x;
  const int bid0 = blockIdx.x;
  const int rep = (bid0 & 7) << 9;
  const int bid = (bid0 & 7) * ((int)gridDim.x >> 3) + (bid0 >> 3);
  const int pbase = bid * 128;

  if (tid < 64) {
    scl[tid] = sc0[tid]; shl[tid] = sh0[tid];
    bl[tid] = b1 ? b1[tid] : 0.f;
    ssum[tid] = 0.f; ssq[tid] = 0.f;
  }
  for (int u = tid; u < 8*64; u += 256) {
    int kc = u >> 6, o = u & 63;
    const float* wp = W1 + o*64 + kc*8;
    float4 wa = *(const float4*)wp;
    float4 wb = *(const float4*)(wp + 4);
    Wl[u] = make_uint4(pk2(wa.x, wa.y), pk2(wa.z, wa.w), pk2(wb.x, wb.y), pk2(wb.z, wb.w));
  }
  __syncthreads();

  const int lane = tid & 63, w = tid >> 6, g = lane >> 4, fr = lane & 15;

  bfrag xv[2][2];
  #pragma unroll
  for (int kk = 0; kk < 2; ++kk) {
    const int kc = kk*4 + g;
    float4 sa = *(const float4*)&scl[kc*8];
    float4 sb = *(const float4*)&scl[kc*8 + 4];
    float4 ha = *(const float4*)&shl[kc*8];
    float4 hb = *(const float4*)&shl[kc*8 + 4];
    #pragma unroll
    for (int pm = 0; pm < 2; ++pm) {
      uint4 yv = Y0g[(size_t)kc * P_ + pbase + w*32 + pm*16 + fr];
      unsigned r0 = pk2(fmaxf(fmaf(sa.x, b2f(yv.x),       ha.x), 0.f),
                        fmaxf(fmaf(sa.y, b2f(yv.x >> 16), ha.y), 0.f));
      unsigned r1 = pk2(fmaxf(fmaf(sa.z, b2f(yv.y),       ha.z), 0.f),
                        fmaxf(fmaf(sa.w, b2f(yv.y >> 16), ha.w), 0.f));
      unsigned r2 = pk2(fmaxf(fmaf(sb.x, b2f(yv.z),       hb.x), 0.f),
                        fmaxf(fmaf(sb.y, b2f(yv.z >> 16), hb.y), 0.f));
      unsigned r3 = pk2(fmaxf(fmaf(sb.z, b2f(yv.w),       hb.z), 0.f),
                        fmaxf(fmaf(sb.w, b2f(yv.w >> 16), hb.w), 0.f));
      uint4 uu = make_uint4(r0, r1, r2, r3);
      xv[kk][pm] = *(bfrag*)&uu;
    }
  }

  f32x4 acc[4][2];
  #pragma unroll
  for (int m = 0; m < 4; ++m)
    #pragma unroll
    for (int j = 0; j < 4; ++j) {
      float v = bl[m*16 + g*4 + j];
      acc[m][0][j] = v; acc[m][1][j] = v;
    }
  #pragma unroll
  for (int kk = 0; kk < 2; ++kk) {
    const int kc = kk*4 + g;
    bfrag a[4];
    #pragma unroll
    for (int m = 0; m < 4; ++m) { uint4 u = Wl[kc*64 + m*16 + fr]; a[m] = *(bfrag*)&u; }
    #pragma unroll
    for (int m = 0; m < 4; ++m)
      #pragma unroll
      for (int pm = 0; pm < 2; ++pm)
        acc[m][pm] = __builtin_amdgcn_mfma_f32_16x16x32_bf16(a[m], xv[kk][pm], acc[m][pm], 0, 0, 0);
  }

  #pragma unroll
  for (int m = 0; m < 4; ++m) {
    #pragma unroll
    for (int j = 0; j < 4; ++j) {
      float v0 = acc[m][0][j], v1 = acc[m][1][j];
      float s = v0 + v1, s2 = v0*v0 + v1*v1;
      #pragma unroll
      for (int d = 1; d < 16; d <<= 1) { s += __shfl_xor(s, d); s2 += __shfl_xor(s2, d); }
      if (fr == 0) {
        atomicAdd(&ssum[m*16 + g*4 + j], s);
        atomicAdd(&ssq[m*16 + g*4 + j], s2);
      }
    }
    #pragma unroll
    for (int pm = 0; pm < 2; ++pm) {
      unsigned lo = pk2(acc[m][pm][0], acc[m][pm][1]);
      unsigned hi = pk2(acc[m][pm][2], acc[m][pm][3]);
      unsigned plo = (unsigned)__shfl_xor((int)lo, 16, 64);
      unsigned phi = (unsigned)__shfl_xor((int)hi, 16, 64);
      if ((g & 1) == 0) {
        size_t unit = (size_t)(m*2 + (g>>1)) * P_ + pbase + w*32 + pm*16 + fr;
        Y1g[unit] = make_uint4(lo, hi, plo, phi);
      }
    }
  }
  __syncthreads();
  if (tid < 64) { atomicAdd(&sumg[rep + tid], ssum[tid]); atomicAdd(&sqg[rep + tid], ssq[tid]); }
}

__global__ __launch_bounds__(256) void l2_mfma(
    const uint4* __restrict__ Y1g,
    const float* __restrict__ W2, const float* __restrict__ b2,
    const float* __restrict__ sc1, const float* __restrict__ sh1,
    float* __restrict__ mxg, float* __restrict__ mng,
    float* __restrict__ sumg, float* __restrict__ sqg)
{
  __shared__ uint4 Wl[8*128];      // 16 KB
  __shared__ float scl[64], shl[64], bl[128];
  __shared__ float ssum[128], ssq[128];

  const int tid = threadIdx.x;
  const int bid0 = blockIdx.x;
  const int rep = (bid0 & 7) << 9;
  const int bid = (bid0 & 7) * ((int)gridDim.x >> 3) + (bid0 >> 3);
  const int pbase = bid * 128;
  const int q0 = bid * 4;

  if (tid < 64) { scl[tid] = sc1[tid]; shl[tid] = sh1[tid]; }
  if (tid < 128) { bl[tid] = b2 ? b2[tid] : 0.f; ssum[tid] = 0.f; ssq[tid] = 0.f; }
  for (int u = tid; u < 8*128; u += 256) {
    int kc = u >> 7, o = u & 127;
    const float* wp = W2 + o*64 + kc*8;
    float4 wa = *(const float4*)wp;
    float4 wb = *(const float4*)(wp + 4);
    Wl[u] = make_uint4(pk2(wa.x, wa.y), pk2(wa.z, wa.w), pk2(wb.x, wb.y), pk2(wb.z, wb.w));
  }
  __syncthreads();

  const int lane = tid & 63, w = tid >> 6, g = lane >> 4, fr = lane & 15;

  bfrag ax[2][2];
  #pragma unroll
  for (int kk = 0; kk < 2; ++kk) {
    const int kc = kk*4 + g;
    float4 sa = *(const float4*)&scl[kc*8];
    float4 sb = *(const float4*)&scl[kc*8 + 4];
    float4 ha = *(const float4*)&shl[kc*8];
    float4 hb = *(const float4*)&shl[kc*8 + 4];
    #pragma unroll
    for (int pm = 0; pm < 2; ++pm) {
      uint4 yv = Y1g[(size_t)kc * P_ + pbase + w*32 + pm*16 + fr];
      unsigned r0 = pk2(fmaxf(fmaf(sa.x, b2f(yv.x),       ha.x), 0.f),
                        fmaxf(fmaf(sa.y, b2f(yv.x >> 16), ha.y), 0.f));
      unsigned r1 = pk2(fmaxf(fmaf(sa.z, b2f(yv.y),       ha.z), 0.f),
                        fmaxf(fmaf(sa.w, b2f(yv.y >> 16), ha.w), 0.f));
      unsigned r2 = pk2(fmaxf(fmaf(sb.x, b2f(yv.z),       hb.x), 0.f),
                        fmaxf(fmaf(sb.y, b2f(yv.z >> 16), hb.y), 0.f));
      unsigned r3 = pk2(fmaxf(fmaf(sb.z, b2f(yv.w),       hb.z), 0.f),
                        fmaxf(fmaf(sb.w, b2f(yv.w >> 16), hb.w), 0.f));
      uint4 uu = make_uint4(r0, r1, r2, r3);
      ax[kk][pm] = *(bfrag*)&uu;
    }
  }

  f32x4 acc[2][8];
  #pragma unroll
  for (int cn = 0; cn < 8; ++cn) {
    float v = bl[cn*16 + fr];
    #pragma unroll
    for (int j = 0; j < 4; ++j) { acc[0][cn][j] = v; acc[1][cn][j] = v; }
  }
  #pragma unroll
  for (int kk = 0; kk < 2; ++kk) {
    const int kc = kk*4 + g;
    #pragma unroll
    for (int cn = 0; cn < 8; ++cn) {
      uint4 u = Wl[kc*128 + cn*16 + fr];
      bfrag bw = *(bfrag*)&u;
      acc[0][cn] = __builtin_amdgcn_mfma_f32_16x16x32_bf16(ax[kk][0], bw, acc[0][cn], 0, 0, 0);
      acc[1][cn] = __builtin_amdgcn_mfma_f32_16x16x32_bf16(ax[kk][1], bw, acc[1][cn], 0, 0, 0);
    }
  }

  #pragma unroll
  for (int cn = 0; cn < 8; ++cn) {
    float mx = -3.0e38f, mn = 3.0e38f, s = 0.f, s2 = 0.f;
    #pragma unroll
    for (int pm = 0; pm < 2; ++pm)
      #pragma unroll
      for (int j = 0; j < 4; ++j) {
        float v = acc[pm][cn][j];
        mx = fmaxf(mx, v); mn = fminf(mn, v);
        s += v; s2 += v*v;
      }
    #pragma unroll
    for (int d = 16; d < 64; d <<= 1) {
      mx = fmaxf(mx, __shfl_xor(mx, d));
      mn = fminf(mn, __shfl_xor(mn, d));
      s  += __shfl_xor(s, d);
      s2 += __shfl_xor(s2, d);
    }
    if (g == 0) {
      int o = cn*16 + fr;
      size_t q = q0 + w;
      mxg[q*128 + o] = mx;
      mng[q*128 + o] = mn;
      atomicAdd(&ssum[o], s);
      atomicAdd(&ssq[o], s2);
    }
  }
  __syncthreads();
  if (tid < 128) { atomicAdd(&sumg[rep + tid], ssum[tid]); atomicAdd(&sqg[rep + tid], ssq[tid]); }
}

// ---------------------------------------------------------------------------
// BN finalize: sum 8 per-XCD replicas of (sum, sumsq) -> (scale, shift).
// ---------------------------------------------------------------------------
__global__ void finalize_kernel(
    const float* __restrict__ sum, const float* __restrict__ sq,
    const float* __restrict__ g, const float* __restrict__ bt,
    float* __restrict__ sc, float* __restrict__ sh, int C)
{
  int c = threadIdx.x;
  if (c < C) {
    float s = 0.f, s2 = 0.f;
    #pragma unroll
    for (int r = 0; r < 8; ++r) { s += sum[r*512 + c]; s2 += sq[r*512 + c]; }
    const float inv = 1.0f / (float)P_;
    float mu = s * inv;
    float var = s2 * inv - mu * mu;
    var = fmaxf(var, 0.f);
    float rr = 1.0f / sqrtf(var + EPS_);
    float gg = g ? g[c] : 1.0f;
    float bb = bt ? bt[c] : 0.0f;
    float sv = gg * rr;
    sc[c] = sv;
    sh[c] = bb - mu * sv;
  }
}

// ---------------------------------------------------------------------------
// Epilogue: BN2 + ReLU + maxpool (affine commutes with max; min covers
// negative scale), write f32 features.
// ---------------------------------------------------------------------------
__global__ __launch_bounds__(256) void out_kernel(
    const float* __restrict__ mxg, const float* __restrict__ mng,
    const float* __restrict__ sc2, const float* __restrict__ sh2,
    float* __restrict__ out)
{
  int i = blockIdx.x * 256 + threadIdx.x;
  int o = i & 127;
  float a = sc2[o];
  float v = (a >= 0.f) ? mxg[i] : mng[i];
  float z = fmaxf(fmaf(a, v, sh2[o]), 0.f);
  out[(size_t)PQ_ * 3 + i] = z;
}

// ---------------------------------------------------------------------------
extern "C" void kernel_launch(void* const* d_in, const int* in_sizes, int n_in,
                              void* d_out, int out_size, void* d_ws, size_t ws_size,
                              hipStream_t stream)
{
  int i_xyz=-1, i_feat=-1, i_fps=-1, i_w0=-1, i_w1=-1, i_w2=-1;
  for (int i = 0; i < n_in; ++i) {
    switch (in_sizes[i]) {
      case 196608:  i_xyz = i; break;
      case 4194304: i_feat = i; break;
      case 16384:   i_fps = i; break;
      case 4288:    i_w0 = i; break;
      case 4096:    i_w1 = i; break;
      case 8192:    i_w2 = i; break;
      default: break;
    }
  }
  if (i_xyz < 0 || i_feat < 0 || i_fps < 0 || i_w0 < 0 || i_w1 < 0 || i_w2 < 0) return;

  const float* xyz  = (const float*)d_in[i_xyz];
  const float* feat = (const float*)d_in[i_feat];
  const int*   fpsr = (const int*)d_in[i_fps];
  const float* W0 = (const float*)d_in[i_w0];
  const float* W1 = (const float*)d_in[i_w1];
  const float* W2 = (const float*)d_in[i_w2];

  bool canon = (n_in >= 15 && i_xyz==0 && i_feat==1 && i_fps==2 && i_w0==3 &&
                i_w1==7 && i_w2==11 &&
                in_sizes[4]==64 && in_sizes[5]==64 && in_sizes[6]==64 &&
                in_sizes[8]==64 && in_sizes[9]==64 && in_sizes[10]==64 &&
                in_sizes[12]==128 && in_sizes[13]==128 && in_sizes[14]==128);
  const float* b0 = canon ? (const float*)d_in[4]  : nullptr;
  const float* g0 = canon ? (const float*)d_in[5]  : nullptr;
  const float* bt0= canon ? (const float*)d_in[6]  : nullptr;
  const float* b1 = canon ? (const float*)d_in[8]  : nullptr;
  const float* g1 = canon ? (const float*)d_in[9]  : nullptr;
  const float* bt1= canon ? (const float*)d_in[10] : nullptr;
  const float* b2 = canon ? (const float*)d_in[12] : nullptr;
  const float* g2 = canon ? (const float*)d_in[13] : nullptr;
  const float* bt2= canon ? (const float*)d_in[14] : nullptr;

  float* out = (float*)d_out;
  char* ws = (char*)d_ws;
  if (ws_size < WS_NEEDED) return;

  int* idxw = (int*)(ws + OFF_IDX);
  uint4* Y0 = (uint4*)(ws + OFF_Y0);
  uint4* Y1 = (uint4*)(ws + OFF_Y1);
  float* mxg = (float*)(ws + OFF_MX);
  float* mng = (float*)(ws + OFF_MN);
  float* st  = (float*)(ws + OFF_STATS);   // 8 replicas x 512 f32
  float* fin = (float*)(ws + OFF_FIN);
  int* fpsc  = (int*)(ws + OFF_FPSC);
  float4* pxyzw = (float4*)(ws + OFF_PXYZW);

  hipMemsetAsync(st, 0, 16384, stream);

  fps_canon_kernel<<<(PQ_+255)/256, 256, 0, stream>>>(fpsr, fpsc);
  prep_kernel<<<(B_*N_)/256, 256, 0, stream>>>(xyz, pxyzw);

  knn_kernel<<<PQ_, 256, 0, stream>>>(pxyzw, fpsc, idxw, out);

  l0_mfma<<<P_/128, 256, 0, stream>>>(xyz, feat, fpsc, idxw, W0, b0, Y0, st + 0, st + 64);
  finalize_kernel<<<1, 64, 0, stream>>>(st + 0, st + 64, g0, bt0, fin + 0, fin + 64, 64);

  l1_mfma<<<P_/128, 256, 0, stream>>>(Y0, W1, b1, fin + 0, fin + 64, Y1, st + 128, st + 192);
  finalize_kernel<<<1, 64, 0, stream>>>(st + 128, st + 192, g1, bt1, fin + 128, fin + 192, 64);

  l2_mfma<<<P_/128, 256, 0, stream>>>(Y1, W2, b2, fin + 128, fin + 192, mxg, mng, st + 256, st + 384);
  finalize_kernel<<<1, 128, 0, stream>>>(st + 256, st + 384, g2, bt2, fin + 256, fin + 384, 128);

  out_kernel<<<(PQ_*128)/256, 256, 0, stream>>>(mxg, mng, fin + 256, fin + 384, out);
}

// Round 12
// 238.353 us; speedup vs baseline: 3.7049x; 1.0174x over previous
//
#include <hip/hip_runtime.h>
#include <stdint.h>

// Problem constants
#define B_   16
#define N_   4096
#define S_   1024
#define K_   32
#define CIN_ 64
#define P_   524288      // B*S*K points through the MLP
#define PQ_  16384       // B*S queries
#define EPS_ 1e-5f

// Workspace layout (bytes)
#define SZ_IDX    ((size_t)P_ * 4)            // knn indices, int32
#define SZ_Y      ((size_t)P_ * 64 * 2)       // 64ch x P bf16 (subtiled units)
#define SZ_MX     ((size_t)PQ_ * 128 * 4)     // per-(q,ch) f32
#define OFF_IDX   ((size_t)0)
#define OFF_Y0    (OFF_IDX + SZ_IDX)
#define OFF_Y1    (OFF_Y0 + SZ_Y)
#define OFF_MX    (OFF_Y1 + SZ_Y)
#define OFF_MN    (OFF_MX + SZ_MX)
#define OFF_STATS (OFF_MN + SZ_MX)            // 8 replicas x 512 f32 (16 KB, zeroed)
#define OFF_FIN   (OFF_STATS + 16384)         // 512 f32 finalized scale/shift
#define OFF_FPSC  (OFF_FIN + 2048)            // canonical fps, 16384 int32
#define OFF_PXYZW (OFF_FPSC + (size_t)PQ_ * 4)  // B*N float4 (x,y,z,|x|^2)
#define WS_NEEDED (OFF_PXYZW + (size_t)B_ * N_ * 16)

typedef unsigned short u16;
typedef short bfrag __attribute__((ext_vector_type(8)));   // 8 bf16 (4 VGPRs)
typedef float f32x4 __attribute__((ext_vector_type(4)));

__device__ __forceinline__ float b2f(unsigned v) {
  return __uint_as_float((v & 0xffffu) << 16);
}
__device__ __forceinline__ u16 f2b(float f) {
  unsigned u = __float_as_uint(f);
  unsigned r = (u + 0x7fffu + ((u >> 16) & 1u)) >> 16;  // RNE
  return (u16)r;
}
__device__ __forceinline__ unsigned pk2(float a, float b) {
  return (unsigned)f2b(a) | ((unsigned)f2b(b) << 16);
}

// ---------------------------------------------------------------------------
// fps canonicalization (int64 vs int32 storage) -> int32, clamped.
// ---------------------------------------------------------------------------
__global__ __launch_bounds__(256) void fps_canon_kernel(
    const int* __restrict__ fpsraw, int* __restrict__ fpsc)
{
  __shared__ int is64;
  const int tid = threadIdx.x;
  if (tid == 0) is64 = 1;
  __syncthreads();
  if (tid < 64) {
    if (fpsraw[2 * tid + 1] != 0) atomicAnd(&is64, 0);
  }
  __syncthreads();
  int i = blockIdx.x * 256 + tid;
  if (i < PQ_) {
    int src = is64 ? (2 * i) : i;
    int v = fpsraw[src];
    fpsc[i] = (v & 0xFFF);
  }
}

// ---------------------------------------------------------------------------
// prep: pack (x, y, z, |x|^2) per point. |x|^2 uses the EXACT reference
// op ordering ((x0*x0 + x1*x1) + x2*x2), f32, no FMA.
// ---------------------------------------------------------------------------
__global__ __launch_bounds__(256) void prep_kernel(
    const float* __restrict__ xyz, float4* __restrict__ pxyzw)
{
  int i = blockIdx.x * 256 + threadIdx.x;   // 0 .. B*N-1
  float x0 = xyz[i*3+0], x1 = xyz[i*3+1], x2 = xyz[i*3+2];
  float s2 = __fadd_rn(__fadd_rn(__fmul_rn(x0,x0), __fmul_rn(x1,x1)), __fmul_rn(x2,x2));
  pxyzw[i] = make_float4(x0, x1, x2, s2);
}

// ---------------------------------------------------------------------------
// KNN v6: exact 32 smallest (d, idx) via histogram radix-select.
// - float4 (x,y,z,|x|^2) input: coalesced dwordx4 loads, 6-op distances
// - register cache of distance AND bin (u16-packed); wave-0 serial scan for T
// - pass 2: rare plain LDS atomics (hits ~35/4096) -- no ballot machinery
// - wave-0 refine loop with (d, idx) lexicographic tie-break
// ---------------------------------------------------------------------------
#define NBIN 2048
#define CAND_CAP 512

__global__ __launch_bounds__(256) void knn_kernel(
    const float4* __restrict__ pxyzw, const int* __restrict__ fps,
    int* __restrict__ idxout, float* __restrict__ out_xyz)
{
  __shared__ unsigned hist[NBIN];      // 8 KB
  __shared__ float cd[CAND_CAP];       // 2 KB
  __shared__ int   ci_[CAND_CAP];      // 2 KB
  __shared__ int   sel[K_];
  __shared__ int   sCnt, sCand, sT;

  const int q   = blockIdx.x;
  const int b   = q >> 10;
  const int tid = threadIdx.x;
  const float4* xb4 = pxyzw + (size_t)b * N_;
  const int ctr = fps[q];
  const float4 cv = xb4[ctr];
  const float cx = cv.x, cy = cv.y, cz = cv.z, s1 = cv.w;

  if (tid == 0) {
    out_xyz[(size_t)q*3+0] = cx;
    out_xyz[(size_t)q*3+1] = cy;
    out_xyz[(size_t)q*3+2] = cz;
    sCnt = 0; sCand = 0;
  }
  {
    uint4* hz = (uint4*)hist;
    hz[tid]       = make_uint4(0,0,0,0);
    hz[tid + 256] = make_uint4(0,0,0,0);
  }
  __syncthreads();

  // pass 1: distances -> registers; bins -> packed registers + histogram.
  // (int) truncation sends tiny-negative d to bin 0, same as the reference's
  // fmax clamp; only the upper clamp is needed.
  float dreg[16];
  unsigned bpk[8];
  #pragma unroll
  for (int it = 0; it < 16; ++it) {
    int n = it * 256 + tid;
    float4 v = xb4[n];
    float dt = __fadd_rn(__fadd_rn(__fmul_rn(cx,v.x), __fmul_rn(cy,v.y)), __fmul_rn(cz,v.z));
    float d  = __fsub_rn(__fadd_rn(s1, v.w), __fmul_rn(2.0f, dt));
    dreg[it] = d;
    int bin = (int)(d * 128.0f);
    bin = bin > (NBIN-1) ? (NBIN-1) : bin;
    bin = bin < 0 ? 0 : bin;
    if (it & 1) bpk[it >> 1] |= (unsigned)bin << 16;
    else        bpk[it >> 1]  = (unsigned)bin;
    atomicAdd(&hist[bin], 1u);
  }
  __syncthreads();

  // scan: wave 0 walks 64 bins at a time until cumulative reaches K (T small)
  const int lane = tid & 63, wid = tid >> 6;
  if (wid == 0) {
    int cum = 0, base = 0, found = 0;
    while (!found && base < NBIN) {
      int h = (int)hist[base + lane];
      int pre = h;
      #pragma unroll
      for (int off = 1; off < 64; off <<= 1) {
        int v = __shfl_up(pre, off, 64);
        if (lane >= off) pre += v;
      }
      int tot = __shfl(pre, 63, 64);
      bool cross = (cum + pre >= K_) && (cum + pre - h < K_);
      unsigned long long mm = __ballot(cross);
      if (mm) {
        if (lane == 0) sT = base + (int)(__ffsll((long long)mm) - 1);
        found = 1;
      }
      cum += tot;
      base += 64;
    }
  }
  __syncthreads();
  const int T = sT;

  // pass 2: rare hits -> plain LDS atomics (no per-iteration wave machinery)
  #pragma unroll
  for (int it = 0; it < 16; ++it) {
    int bin = (int)((bpk[it >> 1] >> ((it & 1) * 16)) & 0xFFFFu);
    if (bin <= T) {
      int n = it * 256 + tid;
      if (bin < T) {
        int s = atomicAdd(&sCnt, 1);
        if (s < K_) sel[s] = n;
      } else {
        int s = atomicAdd(&sCand, 1);
        if (s < CAND_CAP) { cd[s] = dreg[it]; ci_[s] = n; }
      }
    }
  }
  __syncthreads();

  // refine: wave 0 only (lane owns j == lane mod 64), (d, idx) tie-break
  if (wid == 0) {
    int m = sCnt; m = m > K_ ? K_ : m;
    int cc = sCand; cc = cc > CAND_CAP ? CAND_CAP : cc;
    const int r = K_ - m;
    for (int it = 0; it < r; ++it) {
      float bd = 3.0e38f; int bi = 0x7fffffff;
      for (int j = lane; j < cc; j += 64) {
        float dv = cd[j]; int iv = ci_[j];
        if (dv < bd || (dv == bd && iv < bi)) { bd = dv; bi = iv; }
      }
      #pragma unroll
      for (int off = 32; off > 0; off >>= 1) {
        float od = __shfl_down(bd, off, 64);
        int   oi = __shfl_down(bi, off, 64);
        if (od < bd || (od == bd && oi < bi)) { bd = od; bi = oi; }
      }
      int win = __shfl(bi, 0, 64);
      if (lane == 0) sel[m + it] = win & 0xFFF;
      for (int j = lane; j < cc; j += 64) if (ci_[j] == win) cd[j] = 3.0e38f;
    }
  }
  __syncthreads();
  if (tid < K_) idxout[(size_t)q * K_ + tid] = sel[tid] & 0xFFF;
}

// ===========================================================================
// MFMA MLP layers (unchanged from round 10). Fragment mapping (m89/m91):
//   A(M=16,K=32): lane holds A[row=lane&15][k=(lane>>4)*8+i]
//   B(K=32,N=16): lane holds B[k=(lane>>4)*8+i][col=lane&15]
//   D(M=16,N=16): lane holds D[row=(lane>>4)*4+j][col=lane&15]
// Paired 16B Y stores via shfl_xor(16); 8 per-XCD stats replicas.
// ===========================================================================

__global__ __launch_bounds__(256) void l0_mfma(
    const float* __restrict__ xyz, const float* __restrict__ feat,
    const int* __restrict__ fps, const int* __restrict__ idxin,
    const float* __restrict__ W0, const float* __restrict__ b0,
    uint4* __restrict__ Y0g, float* __restrict__ sumg, float* __restrict__ sqg)
{
  __shared__ uint4 Wl[12*64];      // 12 KB
  __shared__ float bl[64];
  __shared__ float ssum[64], ssq[64];

  const int tid = threadIdx.x;
  const int bid0 = blockIdx.x;
  const int rep = (bid0 & 7) << 9;
  const int bid = (bid0 & 7) * ((int)gridDim.x >> 3) + (bid0 >> 3);
  const int pbase = bid * 128;
  const int q0 = bid * 4;
  const int b = bid >> 8;

  if (tid < 64) { bl[tid] = b0 ? b0[tid] : 0.f; ssum[tid] = 0.f; ssq[tid] = 0.f; }
  for (int u = tid; u < 12*64; u += 256) {
    int kc = u >> 6, o = u & 63;
    unsigned pk[4];
    #pragma unroll
    for (int hh = 0; hh < 4; ++hh) {
      int c0 = kc*8 + hh*2, c1 = c0 + 1;
      float v0 = (c0 < 64) ? W0[o*67 + 3 + c0] : (c0 < 67 ? W0[o*67 + (c0-64)] : 0.f);
      float v1 = (c1 < 64) ? W0[o*67 + 3 + c1] : (c1 < 67 ? W0[o*67 + (c1-64)] : 0.f);
      pk[hh] = pk2(v0, v1);
    }
    Wl[u] = make_uint4(pk[0], pk[1], pk[2], pk[3]);
  }

  const int lane = tid & 63, w = tid >> 6, g = lane >> 4, fr = lane & 15;
  const float* xb = xyz + (size_t)b * N_ * 3;
  const float* fbase = feat + (size_t)b * N_ * 64;

  int pidx[2];
  const int ct = fps[q0 + w] & 0xFFF;
  #pragma unroll
  for (int pm = 0; pm < 2; ++pm)
    pidx[pm] = idxin[pbase + w*32 + pm*16 + fr] & 0xFFF;

  bfrag xv[3][2];
  #pragma unroll
  for (int kk = 0; kk < 3; ++kk) {
    const int kc = kk*4 + g;
    #pragma unroll
    for (int pm = 0; pm < 2; ++pm) {
      uint4 uu;
      if (kc < 8) {
        const float* fp = fbase + pidx[pm]*64 + kc*8;
        float4 fa = *(const float4*)fp;
        float4 fb2 = *(const float4*)(fp + 4);
        uu = make_uint4(pk2(fa.x, fa.y), pk2(fa.z, fa.w),
                        pk2(fb2.x, fb2.y), pk2(fb2.z, fb2.w));
      } else if (kc == 8) {
        int n = pidx[pm];
        float dx = xb[n*3+0] - xb[ct*3+0];
        float dy = xb[n*3+1] - xb[ct*3+1];
        float dz = xb[n*3+2] - xb[ct*3+2];
        uu = make_uint4(pk2(dx, dy), (unsigned)f2b(dz), 0u, 0u);
      } else {
        uu = make_uint4(0u, 0u, 0u, 0u);
      }
      xv[kk][pm] = *(bfrag*)&uu;
    }
  }
  __syncthreads();

  f32x4 acc[4][2];
  #pragma unroll
  for (int m = 0; m < 4; ++m)
    #pragma unroll
    for (int j = 0; j < 4; ++j) {
      float v = bl[m*16 + g*4 + j];
      acc[m][0][j] = v; acc[m][1][j] = v;
    }
  #pragma unroll
  for (int kk = 0; kk < 3; ++kk) {
    const int kc = kk*4 + g;
    bfrag a[4];
    #pragma unroll
    for (int m = 0; m < 4; ++m) { uint4 u = Wl[kc*64 + m*16 + fr]; a[m] = *(bfrag*)&u; }
    #pragma unroll
    for (int m = 0; m < 4; ++m)
      #pragma unroll
      for (int pm = 0; pm < 2; ++pm)
        acc[m][pm] = __builtin_amdgcn_mfma_f32_16x16x32_bf16(a[m], xv[kk][pm], acc[m][pm], 0, 0, 0);
  }

  #pragma unroll
  for (int m = 0; m < 4; ++m) {
    #pragma unroll
    for (int j = 0; j < 4; ++j) {
      float v0 = acc[m][0][j], v1 = acc[m][1][j];
      float s = v0 + v1, s2 = v0*v0 + v1*v1;
      #pragma unroll
      for (int d = 1; d < 16; d <<= 1) { s += __shfl_xor(s, d); s2 += __shfl_xor(s2, d); }
      if (fr == 0) {
        atomicAdd(&ssum[m*16 + g*4 + j], s);
        atomicAdd(&ssq[m*16 + g*4 + j], s2);
      }
    }
    #pragma unroll
    for (int pm = 0; pm < 2; ++pm) {
      unsigned lo = pk2(acc[m][pm][0], acc[m][pm][1]);
      unsigned hi = pk2(acc[m][pm][2], acc[m][pm][3]);
      unsigned plo = (unsigned)__shfl_xor((int)lo, 16, 64);
      unsigned phi = (unsigned)__shfl_xor((int)hi, 16, 64);
      if ((g & 1) == 0) {
        size_t unit = (size_t)(m*2 + (g>>1)) * P_ + pbase + w*32 + pm*16 + fr;
        Y0g[unit] = make_uint4(lo, hi, plo, phi);
      }
    }
  }
  __syncthreads();
  if (tid < 64) { atomicAdd(&sumg[rep + tid], ssum[tid]); atomicAdd(&sqg[rep + tid], ssq[tid]); }
}

__global__ __launch_bounds__(256) void l1_mfma(
    const uint4* __restrict__ Y0g,
    const float* __restrict__ W1, const float* __restrict__ b1,
    const float* __restrict__ sc0, const float* __restrict__ sh0,
    uint4* __restrict__ Y1g, float* __restrict__ sumg, float* __restrict__ sqg)
{
  __shared__ uint4 Wl[8*64];       // 8 KB
  __shared__ float scl[64], shl[64], bl[64];
  __shared__ float ssum[64], ssq[64];

  const int tid = threadIdx.x;
  const int bid0 = blockIdx.x;
  const int rep = (bid0 & 7) << 9;
  const int bid = (bid0 & 7) * ((int)gridDim.x >> 3) + (bid0 >> 3);
  const int pbase = bid * 128;

  if (tid < 64) {
    scl[tid] = sc0[tid]; shl[tid] = sh0[tid];
    bl[tid] = b1 ? b1[tid] : 0.f;
    ssum[tid] = 0.f; ssq[tid] = 0.f;
  }
  for (int u = tid; u < 8*64; u += 256) {
    int kc = u >> 6, o = u & 63;
    const float* wp = W1 + o*64 + kc*8;
    float4 wa = *(const float4*)wp;
    float4 wb = *(const float4*)(wp + 4);
    Wl[u] = make_uint4(pk2(wa.x, wa.y), pk2(wa.z, wa.w), pk2(wb.x, wb.y), pk2(wb.z, wb.w));
  }
  __syncthreads();

  const int lane = tid & 63, w = tid >> 6, g = lane >> 4, fr = lane & 15;

  bfrag xv[2][2];
  #pragma unroll
  for (int kk = 0; kk < 2; ++kk) {
    const int kc = kk*4 + g;
    float4 sa = *(const float4*)&scl[kc*8];
    float4 sb = *(const float4*)&scl[kc*8 + 4];
    float4 ha = *(const float4*)&shl[kc*8];
    float4 hb = *(const float4*)&shl[kc*8 + 4];
    #pragma unroll
    for (int pm = 0; pm < 2; ++pm) {
      uint4 yv = Y0g[(size_t)kc * P_ + pbase + w*32 + pm*16 + fr];
      unsigned r0 = pk2(fmaxf(fmaf(sa.x, b2f(yv.x),       ha.x), 0.f),
                        fmaxf(fmaf(sa.y, b2f(yv.x >> 16), ha.y), 0.f));
      unsigned r1 = pk2(fmaxf(fmaf(sa.z, b2f(yv.y),       ha.z), 0.f),
                        fmaxf(fmaf(sa.w, b2f(yv.y >> 16), ha.w), 0.f));
      unsigned r2 = pk2(fmaxf(fmaf(sb.x, b2f(yv.z),       hb.x), 0.f),
                        fmaxf(fmaf(sb.y, b2f(yv.z >> 16), hb.y), 0.f));
      unsigned r3 = pk2(fmaxf(fmaf(sb.z, b2f(yv.w),       hb.z), 0.f),
                        fmaxf(fmaf(sb.w, b2f(yv.w >> 16), hb.w), 0.f));
      uint4 uu = make_uint4(r0, r1, r2, r3);
      xv[kk][pm] = *(bfrag*)&uu;
    }
  }

  f32x4 acc[4][2];
  #pragma unroll
  for (int m = 0; m < 4; ++m)
    #pragma unroll
    for (int j = 0; j < 4; ++j) {
      float v = bl[m*16 + g*4 + j];
      acc[m][0][j] = v; acc[m][1][j] = v;
    }
  #pragma unroll
  for (int kk = 0; kk < 2; ++kk) {
    const int kc = kk*4 + g;
    bfrag a[4];
    #pragma unroll
    for (int m = 0; m < 4; ++m) { uint4 u = Wl[kc*64 + m*16 + fr]; a[m] = *(bfrag*)&u; }
    #pragma unroll
    for (int m = 0; m < 4; ++m)
      #pragma unroll
      for (int pm = 0; pm < 2; ++pm)
        acc[m][pm] = __builtin_amdgcn_mfma_f32_16x16x32_bf16(a[m], xv[kk][pm], acc[m][pm], 0, 0, 0);
  }

  #pragma unroll
  for (int m = 0; m < 4; ++m) {
    #pragma unroll
    for (int j = 0; j < 4; ++j) {
      float v0 = acc[m][0][j], v1 = acc[m][1][j];
      float s = v0 + v1, s2 = v0*v0 + v1*v1;
      #pragma unroll
      for (int d = 1; d < 16; d <<= 1) { s += __shfl_xor(s, d); s2 += __shfl_xor(s2, d); }
      if (fr == 0) {
        atomicAdd(&ssum[m*16 + g*4 + j], s);
        atomicAdd(&ssq[m*16 + g*4 + j], s2);
      }
    }
    #pragma unroll
    for (int pm = 0; pm < 2; ++pm) {
      unsigned lo = pk2(acc[m][pm][0], acc[m][pm][1]);
      unsigned hi = pk2(acc[m][pm][2], acc[m][pm][3]);
      unsigned plo = (unsigned)__shfl_xor((int)lo, 16, 64);
      unsigned phi = (unsigned)__shfl_xor((int)hi, 16, 64);
      if ((g & 1) == 0) {
        size_t unit = (size_t)(m*2 + (g>>1)) * P_ + pbase + w*32 + pm*16 + fr;
        Y1g[unit] = make_uint4(lo, hi, plo, phi);
      }
    }
  }
  __syncthreads();
  if (tid < 64) { atomicAdd(&sumg[rep + tid], ssum[tid]); atomicAdd(&sqg[rep + tid], ssq[tid]); }
}

__global__ __launch_bounds__(256) void l2_mfma(
    const uint4* __restrict__ Y1g,
    const float* __restrict__ W2, const float* __restrict__ b2,
    const float* __restrict__ sc1, const float* __restrict__ sh1,
    float* __restrict__ mxg, float* __restrict__ mng,
    float* __restrict__ sumg, float* __restrict__ sqg)
{
  __shared__ uint4 Wl[8*128];      // 16 KB
  __shared__ float scl[64], shl[64], bl[128];
  __shared__ float ssum[128], ssq[128];

  const int tid = threadIdx.x;
  const int bid0 = blockIdx.x;
  const int rep = (bid0 & 7) << 9;
  const int bid = (bid0 & 7) * ((int)gridDim.x >> 3) + (bid0 >> 3);
  const int pbase = bid * 128;
  const int q0 = bid * 4;

  if (tid < 64) { scl[tid] = sc1[tid]; shl[tid] = sh1[tid]; }
  if (tid < 128) { bl[tid] = b2 ? b2[tid] : 0.f; ssum[tid] = 0.f; ssq[tid] = 0.f; }
  for (int u = tid; u < 8*128; u += 256) {
    int kc = u >> 7, o = u & 127;
    const float* wp = W2 + o*64 + kc*8;
    float4 wa = *(const float4*)wp;
    float4 wb = *(const float4*)(wp + 4);
    Wl[u] = make_uint4(pk2(wa.x, wa.y), pk2(wa.z, wa.w), pk2(wb.x, wb.y), pk2(wb.z, wb.w));
  }
  __syncthreads();

  const int lane = tid & 63, w = tid >> 6, g = lane >> 4, fr = lane & 15;

  bfrag ax[2][2];
  #pragma unroll
  for (int kk = 0; kk < 2; ++kk) {
    const int kc = kk*4 + g;
    float4 sa = *(const float4*)&scl[kc*8];
    float4 sb = *(const float4*)&scl[kc*8 + 4];
    float4 ha = *(const float4*)&shl[kc*8];
    float4 hb = *(const float4*)&shl[kc*8 + 4];
    #pragma unroll
    for (int pm = 0; pm < 2; ++pm) {
      uint4 yv = Y1g[(size_t)kc * P_ + pbase + w*32 + pm*16 + fr];
      unsigned r0 = pk2(fmaxf(fmaf(sa.x, b2f(yv.x),       ha.x), 0.f),
                        fmaxf(fmaf(sa.y, b2f(yv.x >> 16), ha.y), 0.f));
      unsigned r1 = pk2(fmaxf(fmaf(sa.z, b2f(yv.y),       ha.z), 0.f),
                        fmaxf(fmaf(sa.w, b2f(yv.y >> 16), ha.w), 0.f));
      unsigned r2 = pk2(fmaxf(fmaf(sb.x, b2f(yv.z),       hb.x), 0.f),
                        fmaxf(fmaf(sb.y, b2f(yv.z >> 16), hb.y), 0.f));
      unsigned r3 = pk2(fmaxf(fmaf(sb.z, b2f(yv.w),       hb.z), 0.f),
                        fmaxf(fmaf(sb.w, b2f(yv.w >> 16), hb.w), 0.f));
      uint4 uu = make_uint4(r0, r1, r2, r3);
      ax[kk][pm] = *(bfrag*)&uu;
    }
  }

  f32x4 acc[2][8];
  #pragma unroll
  for (int cn = 0; cn < 8; ++cn) {
    float v = bl[cn*16 + fr];
    #pragma unroll
    for (int j = 0; j < 4; ++j) { acc[0][cn][j] = v; acc[1][cn][j] = v; }
  }
  #pragma unroll
  for (int kk = 0; kk < 2; ++kk) {
    const int kc = kk*4 + g;
    #pragma unroll
    for (int cn = 0; cn < 8; ++cn) {
      uint4 u = Wl[kc*128 + cn*16 + fr];
      bfrag bw = *(bfrag*)&u;
      acc[0][cn] = __builtin_amdgcn_mfma_f32_16x16x32_bf16(ax[kk][0], bw, acc[0][cn], 0, 0, 0);
      acc[1][cn] = __builtin_amdgcn_mfma_f32_16x16x32_bf16(ax[kk][1], bw, acc[1][cn], 0, 0, 0);
    }
  }

  #pragma unroll
  for (int cn = 0; cn < 8; ++cn) {
    float mx = -3.0e38f, mn = 3.0e38f, s = 0.f, s2 = 0.f;
    #pragma unroll
    for (int pm = 0; pm < 2; ++pm)
      #pragma unroll
      for (int j = 0; j < 4; ++j) {
        float v = acc[pm][cn][j];
        mx = fmaxf(mx, v); mn = fminf(mn, v);
        s += v; s2 += v*v;
      }
    #pragma unroll
    for (int d = 16; d < 64; d <<= 1) {
      mx = fmaxf(mx, __shfl_xor(mx, d));
      mn = fminf(mn, __shfl_xor(mn, d));
      s  += __shfl_xor(s, d);
      s2 += __shfl_xor(s2, d);
    }
    if (g == 0) {
      int o = cn*16 + fr;
      size_t q = q0 + w;
      mxg[q*128 + o] = mx;
      mng[q*128 + o] = mn;
      atomicAdd(&ssum[o], s);
      atomicAdd(&ssq[o], s2);
    }
  }
  __syncthreads();
  if (tid < 128) { atomicAdd(&sumg[rep + tid], ssum[tid]); atomicAdd(&sqg[rep + tid], ssq[tid]); }
}

// ---------------------------------------------------------------------------
// BN finalize: sum 8 per-XCD replicas of (sum, sumsq) -> (scale, shift).
// ---------------------------------------------------------------------------
__global__ void finalize_kernel(
    const float* __restrict__ sum, const float* __restrict__ sq,
    const float* __restrict__ g, const float* __restrict__ bt,
    float* __restrict__ sc, float* __restrict__ sh, int C)
{
  int c = threadIdx.x;
  if (c < C) {
    float s = 0.f, s2 = 0.f;
    #pragma unroll
    for (int r = 0; r < 8; ++r) { s += sum[r*512 + c]; s2 += sq[r*512 + c]; }
    const float inv = 1.0f / (float)P_;
    float mu = s * inv;
    float var = s2 * inv - mu * mu;
    var = fmaxf(var, 0.f);
    float rr = 1.0f / sqrtf(var + EPS_);
    float gg = g ? g[c] : 1.0f;
    float bb = bt ? bt[c] : 0.0f;
    float sv = gg * rr;
    sc[c] = sv;
    sh[c] = bb - mu * sv;
  }
}

// ---------------------------------------------------------------------------
// Epilogue: BN2 + ReLU + maxpool (affine commutes with max; min covers
// negative scale), write f32 features.
// ---------------------------------------------------------------------------
__global__ __launch_bounds__(256) void out_kernel(
    const float* __restrict__ mxg, const float* __restrict__ mng,
    const float* __restrict__ sc2, const float* __restrict__ sh2,
    float* __restrict__ out)
{
  int i = blockIdx.x * 256 + threadIdx.x;
  int o = i & 127;
  float a = sc2[o];
  float v = (a >= 0.f) ? mxg[i] : mng[i];
  float z = fmaxf(fmaf(a, v, sh2[o]), 0.f);
  out[(size_t)PQ_ * 3 + i] = z;
}

// ---------------------------------------------------------------------------
extern "C" void kernel_launch(void* const* d_in, const int* in_sizes, int n_in,
                              void* d_out, int out_size, void* d_ws, size_t ws_size,
                              hipStream_t stream)
{
  int i_xyz=-1, i_feat=-1, i_fps=-1, i_w0=-1, i_w1=-1, i_w2=-1;
  for (int i = 0; i < n_in; ++i) {
    switch (in_sizes[i]) {
      case 196608:  i_xyz = i; break;
      case 4194304: i_feat = i; break;
      case 16384:   i_fps = i; break;
      case 4288:    i_w0 = i; break;
      case 4096:    i_w1 = i; break;
      case 8192:    i_w2 = i; break;
      default: break;
    }
  }
  if (i_xyz < 0 || i_feat < 0 || i_fps < 0 || i_w0 < 0 || i_w1 < 0 || i_w2 < 0) return;

  const float* xyz  = (const float*)d_in[i_xyz];
  const float* feat = (const float*)d_in[i_feat];
  const int*   fpsr = (const int*)d_in[i_fps];
  const float* W0 = (const float*)d_in[i_w0];
  const float* W1 = (const float*)d_in[i_w1];
  const float* W2 = (const float*)d_in[i_w2];

  bool canon = (n_in >= 15 && i_xyz==0 && i_feat==1 && i_fps==2 && i_w0==3 &&
                i_w1==7 && i_w2==11 &&
                in_sizes[4]==64 && in_sizes[5]==64 && in_sizes[6]==64 &&
                in_sizes[8]==64 && in_sizes[9]==64 && in_sizes[10]==64 &&
                in_sizes[12]==128 && in_sizes[13]==128 && in_sizes[14]==128);
  const float* b0 = canon ? (const float*)d_in[4]  : nullptr;
  const float* g0 = canon ? (const float*)d_in[5]  : nullptr;
  const float* bt0= canon ? (const float*)d_in[6]  : nullptr;
  const float* b1 = canon ? (const float*)d_in[8]  : nullptr;
  const float* g1 = canon ? (const float*)d_in[9]  : nullptr;
  const float* bt1= canon ? (const float*)d_in[10] : nullptr;
  const float* b2 = canon ? (const float*)d_in[12] : nullptr;
  const float* g2 = canon ? (const float*)d_in[13] : nullptr;
  const float* bt2= canon ? (const float*)d_in[14] : nullptr;

  float* out = (float*)d_out;
  char* ws = (char*)d_ws;
  if (ws_size < WS_NEEDED) return;

  int* idxw = (int*)(ws + OFF_IDX);
  uint4* Y0 = (uint4*)(ws + OFF_Y0);
  uint4* Y1 = (uint4*)(ws + OFF_Y1);
  float* mxg = (float*)(ws + OFF_MX);
  float* mng = (float*)(ws + OFF_MN);
  float* st  = (float*)(ws + OFF_STATS);   // 8 replicas x 512 f32
  float* fin = (float*)(ws + OFF_FIN);
  int* fpsc  = (int*)(ws + OFF_FPSC);
  float4* pxyzw = (float4*)(ws + OFF_PXYZW);

  hipMemsetAsync(st, 0, 16384, stream);

  fps_canon_kernel<<<(PQ_+255)/256, 256, 0, stream>>>(fpsr, fpsc);
  prep_kernel<<<(B_*N_)/256, 256, 0, stream>>>(xyz, pxyzw);

  knn_kernel<<<PQ_, 256, 0, stream>>>(pxyzw, fpsc, idxw, out);

  l0_mfma<<<P_/128, 256, 0, stream>>>(xyz, feat, fpsc, idxw, W0, b0, Y0, st + 0, st + 64);
  finalize_kernel<<<1, 64, 0, stream>>>(st + 0, st + 64, g0, bt0, fin + 0, fin + 64, 64);

  l1_mfma<<<P_/128, 256, 0, stream>>>(Y0, W1, b1, fin + 0, fin + 64, Y1, st + 128, st + 192);
  finalize_kernel<<<1, 64, 0, stream>>>(st + 128, st + 192, g1, bt1, fin + 128, fin + 192, 64);

  l2_mfma<<<P_/128, 256, 0, stream>>>(Y1, W2, b2, fin + 128, fin + 192, mxg, mng, st + 256, st + 384);
  finalize_kernel<<<1, 128, 0, stream>>>(st + 256, st + 384, g2, bt2, fin + 256, fin + 384, 128);

  out_kernel<<<(PQ_*128)/256, 256, 0, stream>>>(mxg, mng, fin + 256, fin + 384, out);
}